// Round 1
// baseline (1806.662 us; speedup 1.0000x reference)
//
#include <hip/hip_runtime.h>
#include <math.h>

#ifndef M_PI
#define M_PI 3.14159265358979323846
#endif

namespace {

constexpr int kDim = 768;
constexpr int kNKW = 33;           // W/2+1
constexpr int kB = 8;
constexpr float kLambd = 0.01f;
constexpr size_t kXFElems = (size_t)kB * kNKW * 64 * kDim;  // 12,976,128

// ---------------- 1. bias GEMM: out[m,d] = sum_c x[m,c]*Wb[d,c] + bb[d] ----
__global__ __launch_bounds__(256) void bias_gemm_kernel(
    const float* __restrict__ x, const float* __restrict__ Wb,
    const float* __restrict__ bb, float* __restrict__ out) {
  __shared__ float As[16][129];
  __shared__ float Bs[16][65];
  const int t = threadIdx.x;
  const int m0 = blockIdx.x * 128;
  const int n0 = blockIdx.y * 64;
  const int tx = t & 15;
  const int ty = t >> 4;
  const int tm = ty * 8;
  const int tn = tx * 4;
  float acc[8][4];
#pragma unroll
  for (int i = 0; i < 8; ++i)
#pragma unroll
    for (int j = 0; j < 4; ++j) acc[i][j] = 0.f;

  const int am = t >> 1;
  const int ak = (t & 1) * 8;
  const int bn = t >> 2;
  const int bk = (t & 3) * 4;

  for (int k0 = 0; k0 < 768; k0 += 16) {
    const float4* ap =
        reinterpret_cast<const float4*>(x + (size_t)(m0 + am) * 768 + k0 + ak);
    float4 a0 = ap[0];
    float4 a1 = ap[1];
    float4 bv = *reinterpret_cast<const float4*>(Wb + (size_t)(n0 + bn) * 768 +
                                                 k0 + bk);
    As[ak + 0][am] = a0.x; As[ak + 1][am] = a0.y;
    As[ak + 2][am] = a0.z; As[ak + 3][am] = a0.w;
    As[ak + 4][am] = a1.x; As[ak + 5][am] = a1.y;
    As[ak + 6][am] = a1.z; As[ak + 7][am] = a1.w;
    Bs[bk + 0][bn] = bv.x; Bs[bk + 1][bn] = bv.y;
    Bs[bk + 2][bn] = bv.z; Bs[bk + 3][bn] = bv.w;
    __syncthreads();
#pragma unroll
    for (int kk = 0; kk < 16; ++kk) {
      float a[8], b[4];
#pragma unroll
      for (int i = 0; i < 8; ++i) a[i] = As[kk][tm + i];
#pragma unroll
      for (int j = 0; j < 4; ++j) b[j] = Bs[kk][tn + j];
#pragma unroll
      for (int i = 0; i < 8; ++i)
#pragma unroll
        for (int j = 0; j < 4; ++j) acc[i][j] = fmaf(a[i], b[j], acc[i][j]);
    }
    __syncthreads();
  }
#pragma unroll
  for (int j = 0; j < 4; ++j) {
    const float bias = bb[n0 + tn + j];
#pragma unroll
    for (int i = 0; i < 8; ++i) {
      out[(size_t)(m0 + tm + i) * 768 + n0 + tn + j] = acc[i][j] + bias;
    }
  }
}

// ---------------- 2. forward row rFFT along w -----------------------------
// XFr/XFi layout: [b][kw][h][c], scale 1/8, e^{-i 2pi kw w / 64}
__global__ __launch_bounds__(256) void rfft_row_kernel(
    const float* __restrict__ x, float* __restrict__ XFr,
    float* __restrict__ XFi) {
  __shared__ float xs[64][256];
  __shared__ float ct[64];
  __shared__ float st[64];
  const int t = threadIdx.x;
  const int bh = blockIdx.x;  // b*64 + h
  const int c0 = blockIdx.y * 256;
  if (t < 64) {
    float ang = (float)(2.0 * M_PI / 64.0) * (float)t;
    ct[t] = cosf(ang);
    st[t] = sinf(ang);
  }
  const float* xrow = x + (size_t)bh * (64 * 768) + c0 + t;
#pragma unroll 4
  for (int w = 0; w < 64; ++w) xs[w][t] = xrow[(size_t)w * 768];
  __syncthreads();
  const int b = bh >> 6;
  const int h = bh & 63;
  for (int kw = 0; kw <= 32; ++kw) {
    float sr = 0.f, si = 0.f;
    int idx = 0;
#pragma unroll 8
    for (int w = 0; w < 64; ++w) {
      const float v = xs[w][t];
      sr = fmaf(v, ct[idx], sr);
      si = fmaf(v, st[idx], si);
      idx = (idx + kw) & 63;
    }
    const size_t off = (((size_t)b * kNKW + kw) * 64 + h) * 768 + c0 + t;
    XFr[off] = 0.125f * sr;
    XFi[off] = -0.125f * si;
  }
}

// ---------------- 3/5. column FFT along h (in place), SIGN=-1 fwd, +1 inv --
template <int SIGN>
__global__ __launch_bounds__(256) void fft_col_kernel(float* __restrict__ Xr,
                                                      float* __restrict__ Xi) {
  __shared__ float sr[64][64];
  __shared__ float si[64][64];
  __shared__ float ct[64];
  __shared__ float st[64];
  const int t = threadIdx.x;
  if (t < 64) {
    float ang = (float)(2.0 * M_PI / 64.0) * (float)t;
    ct[t] = cosf(ang);
    st[t] = sinf(ang);
  }
  const int c = t & 63;
  const int g = t >> 6;  // 0..3
  const size_t base = (size_t)blockIdx.x * (64 * 768) + blockIdx.y * 64 + c;
  for (int h = g; h < 64; h += 4) {
    sr[h][c] = Xr[base + (size_t)h * 768];
    si[h][c] = Xi[base + (size_t)h * 768];
  }
  __syncthreads();
  float outr[16], outi[16];
#pragma unroll
  for (int j = 0; j < 16; ++j) {
    const int kh = g + j * 4;
    float ar = 0.f, ai = 0.f;
    int idx = 0;
#pragma unroll 8
    for (int h = 0; h < 64; ++h) {
      const float xr = sr[h][c];
      const float xi = si[h][c];
      const float cv = ct[idx];
      const float sv = st[idx];
      ar += xr * cv - (float)SIGN * xi * sv;
      ai += xi * cv + (float)SIGN * xr * sv;
      idx = (idx + kh) & 63;
    }
    outr[j] = 0.125f * ar;
    outi[j] = 0.125f * ai;
  }
  __syncthreads();
#pragma unroll
  for (int j = 0; j < 16; ++j) {
    const int kh = g + j * 4;
    Xr[base + (size_t)kh * 768] = outr[j];
    Xi[base + (size_t)kh * 768] = outi[j];
  }
}

// ---------------- 4. block-diagonal complex MLP (in place) ----------------
__global__ __launch_bounds__(256) void mlp_kernel(
    float* __restrict__ Xr, float* __restrict__ Xi,
    const float* __restrict__ w1, const float* __restrict__ b1,
    const float* __restrict__ w2, const float* __restrict__ b2) {
  __shared__ float sR[8][768];
  __shared__ float sI[8][768];
  const int t = threadIdx.x;
  const size_t p0 = (size_t)blockIdx.x * 8;
  for (int p = 0; p < 8; ++p) {
    const size_t rbase = (p0 + p) * 768;
    for (int c = t; c < 768; c += 256) {
      sR[p][c] = Xr[rbase + c];
      sI[p][c] = Xi[rbase + c];
    }
  }
  __syncthreads();

  float r1v[3][8], i1v[3][8];
#pragma unroll
  for (int oo = 0; oo < 3; ++oo) {
    const int o = t + oo * 256;
    const int nb = o / 96;
    const int k = o % 96;
    const float* wr = w1 + (size_t)nb * 96 * 96 + k;
    const float* wi = w1 + (size_t)(8 + nb) * 96 * 96 + k;
    float accr[8], acci[8];
#pragma unroll
    for (int p = 0; p < 8; ++p) { accr[p] = 0.f; acci[p] = 0.f; }
    const int cb = nb * 96;
    for (int d = 0; d < 96; ++d) {
      const float wrv = wr[(size_t)d * 96];
      const float wiv = wi[(size_t)d * 96];
#pragma unroll
      for (int p = 0; p < 8; ++p) {
        const float xr = sR[p][cb + d];
        const float xi = sI[p][cb + d];
        accr[p] = fmaf(xr, wrv, fmaf(-xi, wiv, accr[p]));
        acci[p] = fmaf(xr, wiv, fmaf(xi, wrv, acci[p]));
      }
    }
    const float br = b1[nb * 96 + k];
    const float bi = b1[768 + nb * 96 + k];
#pragma unroll
    for (int p = 0; p < 8; ++p) {
      r1v[oo][p] = fmaxf(accr[p] + br, 0.f);
      i1v[oo][p] = fmaxf(acci[p] + bi, 0.f);
    }
  }
  __syncthreads();
#pragma unroll
  for (int oo = 0; oo < 3; ++oo) {
    const int o = t + oo * 256;
#pragma unroll
    for (int p = 0; p < 8; ++p) {
      sR[p][o] = r1v[oo][p];
      sI[p][o] = i1v[oo][p];
    }
  }
  __syncthreads();

#pragma unroll
  for (int oo = 0; oo < 3; ++oo) {
    const int o = t + oo * 256;
    const int nb = o / 96;
    const int k = o % 96;
    const float* wr = w2 + (size_t)nb * 96 * 96 + k;
    const float* wi = w2 + (size_t)(8 + nb) * 96 * 96 + k;
    float accr[8], acci[8];
#pragma unroll
    for (int p = 0; p < 8; ++p) { accr[p] = 0.f; acci[p] = 0.f; }
    const int cb = nb * 96;
    for (int d = 0; d < 96; ++d) {
      const float wrv = wr[(size_t)d * 96];
      const float wiv = wi[(size_t)d * 96];
#pragma unroll
      for (int p = 0; p < 8; ++p) {
        const float xr = sR[p][cb + d];
        const float xi = sI[p][cb + d];
        accr[p] = fmaf(xr, wrv, fmaf(-xi, wiv, accr[p]));
        acci[p] = fmaf(xr, wiv, fmaf(xi, wrv, acci[p]));
      }
    }
    const float br = b2[nb * 96 + k];
    const float bi = b2[768 + nb * 96 + k];
#pragma unroll
    for (int p = 0; p < 8; ++p) {
      float r = accr[p] + br;
      float iv = acci[p] + bi;
      // softshrink
      r = (r > kLambd) ? (r - kLambd) : ((r < -kLambd) ? (r + kLambd) : 0.f);
      iv = (iv > kLambd) ? (iv - kLambd) : ((iv < -kLambd) ? (iv + kLambd) : 0.f);
      Xr[(p0 + p) * 768 + o] = r;
      Xi[(p0 + p) * 768 + o] = iv;
    }
  }
}

// ---------------- 6. inverse row rDFT + accumulate into out ----------------
// out[b, h*64+w, c] += (1/8) * sum_kw alpha_kw (Zr cos - Zi sin)
__global__ __launch_bounds__(256) void irfft_row_add_kernel(
    const float* __restrict__ Xr, const float* __restrict__ Xi,
    float* __restrict__ out) {
  __shared__ float zr[33][256];
  __shared__ float zi[33][256];
  __shared__ float ct[64];
  __shared__ float st[64];
  const int t = threadIdx.x;
  const int bh = blockIdx.x;  // b*64 + h
  const int c0 = blockIdx.y * 256;
  const int b = bh >> 6;
  const int h = bh & 63;
  if (t < 64) {
    float ang = (float)(2.0 * M_PI / 64.0) * (float)t;
    ct[t] = cosf(ang);
    st[t] = sinf(ang);
  }
  for (int kw = 0; kw <= 32; ++kw) {
    const float a = (kw == 0 || kw == 32) ? 0.125f : 0.25f;
    const size_t off = (((size_t)b * kNKW + kw) * 64 + h) * 768 + c0 + t;
    zr[kw][t] = a * Xr[off];
    zi[kw][t] = a * Xi[off];
  }
  __syncthreads();
  float* orow = out + (size_t)bh * (64 * 768) + c0 + t;
  for (int w = 0; w < 64; ++w) {
    float s = 0.f;
    int idx = 0;
#pragma unroll
    for (int kw = 0; kw <= 32; ++kw) {
      s += zr[kw][t] * ct[idx] - zi[kw][t] * st[idx];
      idx = (idx + w) & 63;
    }
    orow[(size_t)w * 768] += s;
  }
}

}  // namespace

extern "C" void kernel_launch(void* const* d_in, const int* in_sizes, int n_in,
                              void* d_out, int out_size, void* d_ws,
                              size_t ws_size, hipStream_t stream) {
  (void)in_sizes; (void)n_in; (void)out_size;
  const float* x  = (const float*)d_in[0];
  const float* w1 = (const float*)d_in[1];
  const float* b1 = (const float*)d_in[2];
  const float* w2 = (const float*)d_in[3];
  const float* b2 = (const float*)d_in[4];
  const float* Wb = (const float*)d_in[5];
  const float* bb = (const float*)d_in[6];
  float* out = (float*)d_out;

  if (ws_size < 2 * kXFElems * sizeof(float)) return;  // ws too small -> fail loudly
  float* XFr = (float*)d_ws;
  float* XFi = XFr + kXFElems;

  // 1. bias path GEMM (writes d_out fully)
  bias_gemm_kernel<<<dim3(32768 / 128, 768 / 64), 256, 0, stream>>>(x, Wb, bb, out);
  // 2. forward row rFFT
  rfft_row_kernel<<<dim3(512, 3), 256, 0, stream>>>(x, XFr, XFi);
  // 3. forward column FFT
  fft_col_kernel<-1><<<dim3(264, 12), 256, 0, stream>>>(XFr, XFi);
  // 4. block-diagonal complex MLP
  mlp_kernel<<<dim3(2112), 256, 0, stream>>>(XFr, XFi, w1, b1, w2, b2);
  // 5. inverse column FFT
  fft_col_kernel<1><<<dim3(264, 12), 256, 0, stream>>>(XFr, XFi);
  // 6. inverse row rDFT + add bias path
  irfft_row_add_kernel<<<dim3(512, 3), 256, 0, stream>>>(XFr, XFi, out);
}

// Round 4
// 1361.890 us; speedup vs baseline: 1.3266x; 1.3266x over previous
//
#include <hip/hip_runtime.h>
#include <math.h>

#ifndef M_PI
#define M_PI 3.14159265358979323846
#endif

namespace {

constexpr int kDim = 768;
constexpr int kNKW = 33;           // W/2+1
constexpr int kB = 8;
constexpr float kLambd = 0.01f;
constexpr size_t kXFElems = (size_t)kB * kNKW * 64 * kDim;  // 12,976,128

typedef __attribute__((ext_vector_type(8))) __bf16 bf16x8;
typedef __attribute__((ext_vector_type(4))) float f32x4;

// RNE float -> bf16 (inputs are normal floats; NaN not expected)
__device__ inline unsigned short f2bf(float f) {
  unsigned int u = __float_as_uint(f);
  unsigned int r = (u + 0x7FFFu + ((u >> 16) & 1u)) >> 16;
  return (unsigned short)r;
}

__device__ inline void gload_lds16(const void* g, void* l) {
  __builtin_amdgcn_global_load_lds(
      (const __attribute__((address_space(1))) unsigned int*)g,
      (__attribute__((address_space(3))) unsigned int*)l, 16, 0, 0);
}

// ---------------- 0. fp32 -> bf16 conversion (grid-stride over groups of 4) --
__global__ __launch_bounds__(256) void cvt_f32_bf16_kernel(
    const float* __restrict__ in, unsigned short* __restrict__ out, int n4) {
  int i = blockIdx.x * 256 + threadIdx.x;
  if (i >= n4) return;
  const float4 v = reinterpret_cast<const float4*>(in)[i];
  ushort4 o;
  o.x = f2bf(v.x); o.y = f2bf(v.y); o.z = f2bf(v.z); o.w = f2bf(v.w);
  reinterpret_cast<ushort4*>(out)[i] = o;
}

// ---------------- 1. bias GEMM via MFMA ------------------------------------
// out[m,n] = sum_k xbf[m,k] * wbf[n,k] + bb[n]; M=32768, N=768, K=768.
// 128x128 tile, 4 waves (2x2), BK=32, mfma_f32_16x16x32_bf16 (m97 structure).
__global__ __launch_bounds__(256) void mfma_gemm_kernel(
    const unsigned short* __restrict__ xbf, const unsigned short* __restrict__ wbf,
    const float* __restrict__ bb, float* __restrict__ out) {
  __shared__ unsigned short As[128 * 32];  // [row][k] 8KB
  __shared__ unsigned short Bs[128 * 32];  // [n][k]   8KB
  const int t = threadIdx.x;
  const int lane = t & 63;
  const int wid = t >> 6;
  const int wm = wid >> 1;
  const int wn = wid & 1;
  const int m0 = blockIdx.x * 128;
  const int n0 = blockIdx.y * 128;

  f32x4 acc[4][4];
#pragma unroll
  for (int i = 0; i < 4; ++i)
#pragma unroll
    for (int j = 0; j < 4; ++j) acc[i][j] = (f32x4){0.f, 0.f, 0.f, 0.f};

  char* AsB = (char*)As;
  char* BsB = (char*)Bs;
  const int cl = lane & 15;
  const int kg = lane >> 4;  // 0..3

  for (int k0 = 0; k0 < 768; k0 += 32) {
#pragma unroll
    for (int i = 0; i < 2; ++i) {
      const int off = (wid * 2 + i) * 1024 + lane * 16;  // byte off in tile
      const int row = off >> 6;
      const int kb = off & 63;
      const char* gA = (const char*)xbf + ((size_t)(m0 + row) * 768 + k0) * 2 + kb;
      gload_lds16(gA, AsB + (wid * 2 + i) * 1024);
      const char* gB = (const char*)wbf + ((size_t)(n0 + row) * 768 + k0) * 2 + kb;
      gload_lds16(gB, BsB + (wid * 2 + i) * 1024);
    }
    asm volatile("s_waitcnt vmcnt(0)" ::: "memory");
    __syncthreads();

    bf16x8 av[4], bv[4];
#pragma unroll
    for (int mi = 0; mi < 4; ++mi) {
      const int r = wm * 64 + mi * 16 + cl;
      av[mi] = *reinterpret_cast<const bf16x8*>(AsB + r * 64 + kg * 16);
    }
#pragma unroll
    for (int ni = 0; ni < 4; ++ni) {
      const int r = wn * 64 + ni * 16 + cl;
      bv[ni] = *reinterpret_cast<const bf16x8*>(BsB + r * 64 + kg * 16);
    }
#pragma unroll
    for (int mi = 0; mi < 4; ++mi)
#pragma unroll
      for (int ni = 0; ni < 4; ++ni)
        acc[mi][ni] = __builtin_amdgcn_mfma_f32_16x16x32_bf16(
            av[mi], bv[ni], acc[mi][ni], 0, 0, 0);
    __syncthreads();
  }

#pragma unroll
  for (int ni = 0; ni < 4; ++ni) {
    const int n = n0 + wn * 64 + ni * 16 + cl;
    const float bias = bb[n];
#pragma unroll
    for (int mi = 0; mi < 4; ++mi) {
      const int m = m0 + wm * 64 + mi * 16 + kg * 4;
#pragma unroll
      for (int r = 0; r < 4; ++r) {
        out[(size_t)(m + r) * 768 + n] = acc[mi][ni][r] + bias;
      }
    }
  }
}

// ---------------- 2. forward row rFFT along w -----------------------------
// XFr/XFi layout: [b][kw][h][c], scale 1/8, e^{-i 2pi kw w / 64}
__global__ __launch_bounds__(256) void rfft_row_kernel(
    const float* __restrict__ x, float* __restrict__ XFr,
    float* __restrict__ XFi) {
  __shared__ float xs[64][256];
  __shared__ float ct[64];
  __shared__ float st[64];
  const int t = threadIdx.x;
  const int bh = blockIdx.x;  // b*64 + h
  const int c0 = blockIdx.y * 256;
  if (t < 64) {
    float ang = (float)(2.0 * M_PI / 64.0) * (float)t;
    ct[t] = cosf(ang);
    st[t] = sinf(ang);
  }
  const float* xrow = x + (size_t)bh * (64 * 768) + c0 + t;
#pragma unroll 4
  for (int w = 0; w < 64; ++w) xs[w][t] = xrow[(size_t)w * 768];
  __syncthreads();
  const int b = bh >> 6;
  const int h = bh & 63;
  for (int kw = 0; kw <= 32; ++kw) {
    float sr = 0.f, si = 0.f;
    int idx = 0;
#pragma unroll 8
    for (int w = 0; w < 64; ++w) {
      const float v = xs[w][t];
      sr = fmaf(v, ct[idx], sr);
      si = fmaf(v, st[idx], si);
      idx = (idx + kw) & 63;
    }
    const size_t off = (((size_t)b * kNKW + kw) * 64 + h) * 768 + c0 + t;
    XFr[off] = 0.125f * sr;
    XFi[off] = -0.125f * si;
  }
}

// ---------------- 3/5. column FFT along h (in place), SIGN=-1 fwd, +1 inv --
template <int SIGN>
__global__ __launch_bounds__(256) void fft_col_kernel(float* __restrict__ Xr,
                                                      float* __restrict__ Xi) {
  __shared__ float sr[64][64];
  __shared__ float si[64][64];
  __shared__ float ct[64];
  __shared__ float st[64];
  const int t = threadIdx.x;
  if (t < 64) {
    float ang = (float)(2.0 * M_PI / 64.0) * (float)t;
    ct[t] = cosf(ang);
    st[t] = sinf(ang);
  }
  const int c = t & 63;
  const int g = t >> 6;  // 0..3
  const size_t base = (size_t)blockIdx.x * (64 * 768) + blockIdx.y * 64 + c;
  for (int h = g; h < 64; h += 4) {
    sr[h][c] = Xr[base + (size_t)h * 768];
    si[h][c] = Xi[base + (size_t)h * 768];
  }
  __syncthreads();
  float outr[16], outi[16];
#pragma unroll
  for (int j = 0; j < 16; ++j) {
    const int kh = g + j * 4;
    float ar = 0.f, ai = 0.f;
    int idx = 0;
#pragma unroll 8
    for (int h = 0; h < 64; ++h) {
      const float xr = sr[h][c];
      const float xi = si[h][c];
      const float cv = ct[idx];
      const float sv = st[idx];
      ar += xr * cv - (float)SIGN * xi * sv;
      ai += xi * cv + (float)SIGN * xr * sv;
      idx = (idx + kh) & 63;
    }
    outr[j] = 0.125f * ar;
    outi[j] = 0.125f * ai;
  }
  __syncthreads();
#pragma unroll
  for (int j = 0; j < 16; ++j) {
    const int kh = g + j * 4;
    Xr[base + (size_t)kh * 768] = outr[j];
    Xi[base + (size_t)kh * 768] = outi[j];
  }
}

// ---------------- 4. block-diagonal complex MLP (in place) ----------------
__global__ __launch_bounds__(256) void mlp_kernel(
    float* __restrict__ Xr, float* __restrict__ Xi,
    const float* __restrict__ w1, const float* __restrict__ b1,
    const float* __restrict__ w2, const float* __restrict__ b2) {
  __shared__ float sR[8][768];
  __shared__ float sI[8][768];
  const int t = threadIdx.x;
  const size_t p0 = (size_t)blockIdx.x * 8;
  for (int p = 0; p < 8; ++p) {
    const size_t rbase = (p0 + p) * 768;
    for (int c = t; c < 768; c += 256) {
      sR[p][c] = Xr[rbase + c];
      sI[p][c] = Xi[rbase + c];
    }
  }
  __syncthreads();

  float r1v[3][8], i1v[3][8];
#pragma unroll
  for (int oo = 0; oo < 3; ++oo) {
    const int o = t + oo * 256;
    const int nb = o / 96;
    const int k = o % 96;
    const float* wr = w1 + (size_t)nb * 96 * 96 + k;
    const float* wi = w1 + (size_t)(8 + nb) * 96 * 96 + k;
    float accr[8], acci[8];
#pragma unroll
    for (int p = 0; p < 8; ++p) { accr[p] = 0.f; acci[p] = 0.f; }
    const int cb = nb * 96;
    for (int d = 0; d < 96; ++d) {
      const float wrv = wr[(size_t)d * 96];
      const float wiv = wi[(size_t)d * 96];
#pragma unroll
      for (int p = 0; p < 8; ++p) {
        const float xr = sR[p][cb + d];
        const float xi = sI[p][cb + d];
        accr[p] = fmaf(xr, wrv, fmaf(-xi, wiv, accr[p]));
        acci[p] = fmaf(xr, wiv, fmaf(xi, wrv, acci[p]));
      }
    }
    const float br = b1[nb * 96 + k];
    const float bi = b1[768 + nb * 96 + k];
#pragma unroll
    for (int p = 0; p < 8; ++p) {
      r1v[oo][p] = fmaxf(accr[p] + br, 0.f);
      i1v[oo][p] = fmaxf(acci[p] + bi, 0.f);
    }
  }
  __syncthreads();
#pragma unroll
  for (int oo = 0; oo < 3; ++oo) {
    const int o = t + oo * 256;
#pragma unroll
    for (int p = 0; p < 8; ++p) {
      sR[p][o] = r1v[oo][p];
      sI[p][o] = i1v[oo][p];
    }
  }
  __syncthreads();

#pragma unroll
  for (int oo = 0; oo < 3; ++oo) {
    const int o = t + oo * 256;
    const int nb = o / 96;
    const int k = o % 96;
    const float* wr = w2 + (size_t)nb * 96 * 96 + k;
    const float* wi = w2 + (size_t)(8 + nb) * 96 * 96 + k;
    float accr[8], acci[8];
#pragma unroll
    for (int p = 0; p < 8; ++p) { accr[p] = 0.f; acci[p] = 0.f; }
    const int cb = nb * 96;
    for (int d = 0; d < 96; ++d) {
      const float wrv = wr[(size_t)d * 96];
      const float wiv = wi[(size_t)d * 96];
#pragma unroll
      for (int p = 0; p < 8; ++p) {
        const float xr = sR[p][cb + d];
        const float xi = sI[p][cb + d];
        accr[p] = fmaf(xr, wrv, fmaf(-xi, wiv, accr[p]));
        acci[p] = fmaf(xr, wiv, fmaf(xi, wrv, acci[p]));
      }
    }
    const float br = b2[nb * 96 + k];
    const float bi = b2[768 + nb * 96 + k];
#pragma unroll
    for (int p = 0; p < 8; ++p) {
      float r = accr[p] + br;
      float iv = acci[p] + bi;
      // softshrink
      r = (r > kLambd) ? (r - kLambd) : ((r < -kLambd) ? (r + kLambd) : 0.f);
      iv = (iv > kLambd) ? (iv - kLambd) : ((iv < -kLambd) ? (iv + kLambd) : 0.f);
      Xr[(p0 + p) * 768 + o] = r;
      Xi[(p0 + p) * 768 + o] = iv;
    }
  }
}

// ---------------- 6. inverse row rDFT + accumulate into out ----------------
// out[b, h*64+w, c] += (1/8) * sum_kw alpha_kw (Zr cos - Zi sin)
__global__ __launch_bounds__(256) void irfft_row_add_kernel(
    const float* __restrict__ Xr, const float* __restrict__ Xi,
    float* __restrict__ out) {
  __shared__ float zr[33][256];
  __shared__ float zi[33][256];
  __shared__ float ct[64];
  __shared__ float st[64];
  const int t = threadIdx.x;
  const int bh = blockIdx.x;  // b*64 + h
  const int c0 = blockIdx.y * 256;
  const int b = bh >> 6;
  const int h = bh & 63;
  if (t < 64) {
    float ang = (float)(2.0 * M_PI / 64.0) * (float)t;
    ct[t] = cosf(ang);
    st[t] = sinf(ang);
  }
  for (int kw = 0; kw <= 32; ++kw) {
    const float a = (kw == 0 || kw == 32) ? 0.125f : 0.25f;
    const size_t off = (((size_t)b * kNKW + kw) * 64 + h) * 768 + c0 + t;
    zr[kw][t] = a * Xr[off];
    zi[kw][t] = a * Xi[off];
  }
  __syncthreads();
  float* orow = out + (size_t)bh * (64 * 768) + c0 + t;
  for (int w = 0; w < 64; ++w) {
    float s = 0.f;
    int idx = 0;
#pragma unroll
    for (int kw = 0; kw <= 32; ++kw) {
      s += zr[kw][t] * ct[idx] - zi[kw][t] * st[idx];
      idx = (idx + w) & 63;
    }
    orow[(size_t)w * 768] += s;
  }
}

}  // namespace

extern "C" void kernel_launch(void* const* d_in, const int* in_sizes, int n_in,
                              void* d_out, int out_size, void* d_ws,
                              size_t ws_size, hipStream_t stream) {
  (void)in_sizes; (void)n_in; (void)out_size;
  const float* x  = (const float*)d_in[0];
  const float* w1 = (const float*)d_in[1];
  const float* b1 = (const float*)d_in[2];
  const float* w2 = (const float*)d_in[3];
  const float* b2 = (const float*)d_in[4];
  const float* Wb = (const float*)d_in[5];
  const float* bb = (const float*)d_in[6];
  float* out = (float*)d_out;

  if (ws_size < 2 * kXFElems * sizeof(float)) return;  // ws too small -> fail loudly
  float* XFr = (float*)d_ws;
  float* XFi = XFr + kXFElems;

  // bf16 scratch aliases XFr/XFi regions: GEMM finishes before rFFT writes them.
  unsigned short* xbf = (unsigned short*)XFr;   // 32768*768 bf16 = 48 MB (< 51.9 MB)
  unsigned short* wbf = (unsigned short*)XFi;   // 768*768 bf16

  // 0. convert x and Wb to bf16
  cvt_f32_bf16_kernel<<<dim3((32768 * 768 / 4 + 255) / 256), 256, 0, stream>>>(
      x, xbf, 32768 * 768 / 4);
  cvt_f32_bf16_kernel<<<dim3((768 * 768 / 4 + 255) / 256), 256, 0, stream>>>(
      Wb, wbf, 768 * 768 / 4);
  // 1. bias path GEMM on matrix cores (writes d_out fully)
  mfma_gemm_kernel<<<dim3(32768 / 128, 768 / 128), 256, 0, stream>>>(xbf, wbf, bb, out);
  // 2. forward row rFFT
  rfft_row_kernel<<<dim3(512, 3), 256, 0, stream>>>(x, XFr, XFi);
  // 3. forward column FFT
  fft_col_kernel<-1><<<dim3(264, 12), 256, 0, stream>>>(XFr, XFi);
  // 4. block-diagonal complex MLP
  mlp_kernel<<<dim3(2112), 256, 0, stream>>>(XFr, XFi, w1, b1, w2, b2);
  // 5. inverse column FFT
  fft_col_kernel<1><<<dim3(264, 12), 256, 0, stream>>>(XFr, XFi);
  // 6. inverse row rDFT + add bias path
  irfft_row_add_kernel<<<dim3(512, 3), 256, 0, stream>>>(XFr, XFi, out);
}

// Round 5
// 1072.938 us; speedup vs baseline: 1.6838x; 1.2693x over previous
//
#include <hip/hip_runtime.h>
#include <math.h>

#ifndef M_PI
#define M_PI 3.14159265358979323846
#endif

namespace {

constexpr int kDim = 768;
constexpr int kNKW = 33;           // W/2+1
constexpr int kB = 8;
constexpr float kLambd = 0.01f;
constexpr size_t kXFElems = (size_t)kB * kNKW * 64 * kDim;  // 12,976,128

typedef __attribute__((ext_vector_type(8))) __bf16 bf16x8;
typedef __attribute__((ext_vector_type(8))) short short8;
typedef __attribute__((ext_vector_type(4))) float f32x4;

// RNE float -> bf16 (inputs are normal floats; NaN not expected)
__device__ inline unsigned short f2bf(float f) {
  unsigned int u = __float_as_uint(f);
  unsigned int r = (u + 0x7FFFu + ((u >> 16) & 1u)) >> 16;
  return (unsigned short)r;
}

__device__ inline bf16x8 s2b(short8 s) { return __builtin_bit_cast(bf16x8, s); }
__device__ inline bf16x8 negb(short8 s) {
  s ^= (short)0x8000;
  return __builtin_bit_cast(bf16x8, s);
}

__device__ inline void gload_lds16(const void* g, void* l) {
  __builtin_amdgcn_global_load_lds(
      (const __attribute__((address_space(1))) unsigned int*)g,
      (__attribute__((address_space(3))) unsigned int*)l, 16, 0, 0);
}

// ---------------- 0. fp32 -> bf16 conversion (grid-stride over groups of 4) --
__global__ __launch_bounds__(256) void cvt_f32_bf16_kernel(
    const float* __restrict__ in, unsigned short* __restrict__ out, int n4) {
  int i = blockIdx.x * 256 + threadIdx.x;
  if (i >= n4) return;
  const float4 v = reinterpret_cast<const float4*>(in)[i];
  ushort4 o;
  o.x = f2bf(v.x); o.y = f2bf(v.y); o.z = f2bf(v.z); o.w = f2bf(v.w);
  reinterpret_cast<ushort4*>(out)[i] = o;
}

// ---------------- 1. bias GEMM via MFMA ------------------------------------
// out[m,n] = sum_k xbf[m,k] * wbf[n,k] + bb[n]; M=32768, N=768, K=768.
__global__ __launch_bounds__(256) void mfma_gemm_kernel(
    const unsigned short* __restrict__ xbf, const unsigned short* __restrict__ wbf,
    const float* __restrict__ bb, float* __restrict__ out) {
  __shared__ unsigned short As[128 * 32];  // [row][k] 8KB
  __shared__ unsigned short Bs[128 * 32];  // [n][k]   8KB
  const int t = threadIdx.x;
  const int lane = t & 63;
  const int wid = t >> 6;
  const int wm = wid >> 1;
  const int wn = wid & 1;
  const int m0 = blockIdx.x * 128;
  const int n0 = blockIdx.y * 128;

  f32x4 acc[4][4];
#pragma unroll
  for (int i = 0; i < 4; ++i)
#pragma unroll
    for (int j = 0; j < 4; ++j) acc[i][j] = (f32x4){0.f, 0.f, 0.f, 0.f};

  char* AsB = (char*)As;
  char* BsB = (char*)Bs;
  const int cl = lane & 15;
  const int kg = lane >> 4;  // 0..3

  for (int k0 = 0; k0 < 768; k0 += 32) {
#pragma unroll
    for (int i = 0; i < 2; ++i) {
      const int off = (wid * 2 + i) * 1024 + lane * 16;  // byte off in tile
      const int row = off >> 6;
      const int kb = off & 63;
      const char* gA = (const char*)xbf + ((size_t)(m0 + row) * 768 + k0) * 2 + kb;
      gload_lds16(gA, AsB + (wid * 2 + i) * 1024);
      const char* gB = (const char*)wbf + ((size_t)(n0 + row) * 768 + k0) * 2 + kb;
      gload_lds16(gB, BsB + (wid * 2 + i) * 1024);
    }
    asm volatile("s_waitcnt vmcnt(0)" ::: "memory");
    __syncthreads();

    bf16x8 av[4], bv[4];
#pragma unroll
    for (int mi = 0; mi < 4; ++mi) {
      const int r = wm * 64 + mi * 16 + cl;
      av[mi] = *reinterpret_cast<const bf16x8*>(AsB + r * 64 + kg * 16);
    }
#pragma unroll
    for (int ni = 0; ni < 4; ++ni) {
      const int r = wn * 64 + ni * 16 + cl;
      bv[ni] = *reinterpret_cast<const bf16x8*>(BsB + r * 64 + kg * 16);
    }
#pragma unroll
    for (int mi = 0; mi < 4; ++mi)
#pragma unroll
      for (int ni = 0; ni < 4; ++ni)
        acc[mi][ni] = __builtin_amdgcn_mfma_f32_16x16x32_bf16(
            av[mi], bv[ni], acc[mi][ni], 0, 0, 0);
    __syncthreads();
  }

#pragma unroll
  for (int ni = 0; ni < 4; ++ni) {
    const int n = n0 + wn * 64 + ni * 16 + cl;
    const float bias = bb[n];
#pragma unroll
    for (int mi = 0; mi < 4; ++mi) {
      const int m = m0 + wm * 64 + mi * 16 + kg * 4;
#pragma unroll
      for (int r = 0; r < 4; ++r) {
        out[(size_t)(m + r) * 768 + n] = acc[mi][ni][r] + bias;
      }
    }
  }
}

// ---------------- 2. forward row rFFT along w -----------------------------
// XFr/XFi layout: [b][kw][h][c], scale 1/8, e^{-i 2pi kw w / 64}
__global__ __launch_bounds__(256) void rfft_row_kernel(
    const float* __restrict__ x, float* __restrict__ XFr,
    float* __restrict__ XFi) {
  __shared__ float xs[64][256];
  __shared__ float ct[64];
  __shared__ float st[64];
  const int t = threadIdx.x;
  const int bh = blockIdx.x;  // b*64 + h
  const int c0 = blockIdx.y * 256;
  if (t < 64) {
    float ang = (float)(2.0 * M_PI / 64.0) * (float)t;
    ct[t] = cosf(ang);
    st[t] = sinf(ang);
  }
  const float* xrow = x + (size_t)bh * (64 * 768) + c0 + t;
#pragma unroll 4
  for (int w = 0; w < 64; ++w) xs[w][t] = xrow[(size_t)w * 768];
  __syncthreads();
  const int b = bh >> 6;
  const int h = bh & 63;
  for (int kw = 0; kw <= 32; ++kw) {
    float sr = 0.f, si = 0.f;
    int idx = 0;
#pragma unroll 8
    for (int w = 0; w < 64; ++w) {
      const float v = xs[w][t];
      sr = fmaf(v, ct[idx], sr);
      si = fmaf(v, st[idx], si);
      idx = (idx + kw) & 63;
    }
    const size_t off = (((size_t)b * kNKW + kw) * 64 + h) * 768 + c0 + t;
    XFr[off] = 0.125f * sr;
    XFi[off] = -0.125f * si;
  }
}

// ---------------- 3/5. column FFT along h (in place), SIGN=-1 fwd, +1 inv --
template <int SIGN>
__global__ __launch_bounds__(256) void fft_col_kernel(float* __restrict__ Xr,
                                                      float* __restrict__ Xi) {
  __shared__ float sr[64][64];
  __shared__ float si[64][64];
  __shared__ float ct[64];
  __shared__ float st[64];
  const int t = threadIdx.x;
  if (t < 64) {
    float ang = (float)(2.0 * M_PI / 64.0) * (float)t;
    ct[t] = cosf(ang);
    st[t] = sinf(ang);
  }
  const int c = t & 63;
  const int g = t >> 6;  // 0..3
  const size_t base = (size_t)blockIdx.x * (64 * 768) + blockIdx.y * 64 + c;
  for (int h = g; h < 64; h += 4) {
    sr[h][c] = Xr[base + (size_t)h * 768];
    si[h][c] = Xi[base + (size_t)h * 768];
  }
  __syncthreads();
  float outr[16], outi[16];
#pragma unroll
  for (int j = 0; j < 16; ++j) {
    const int kh = g + j * 4;
    float ar = 0.f, ai = 0.f;
    int idx = 0;
#pragma unroll 8
    for (int h = 0; h < 64; ++h) {
      const float xr = sr[h][c];
      const float xi = si[h][c];
      const float cv = ct[idx];
      const float sv = st[idx];
      ar += xr * cv - (float)SIGN * xi * sv;
      ai += xi * cv + (float)SIGN * xr * sv;
      idx = (idx + kh) & 63;
    }
    outr[j] = 0.125f * ar;
    outi[j] = 0.125f * ai;
  }
  __syncthreads();
#pragma unroll
  for (int j = 0; j < 16; ++j) {
    const int kh = g + j * 4;
    Xr[base + (size_t)kh * 768] = outr[j];
    Xi[base + (size_t)kh * 768] = outi[j];
  }
}

// ---------------- 4. block-diagonal complex MLP via MFMA (in place) --------
// Per workgroup: 128 positions x one nb block (96 channels), both layers fused.
// LDS: X tiles + 4 weight matrices, all bf16, rows padded to 104 elems (208B).
__global__ __launch_bounds__(512) void mlp_mfma_kernel(
    float* __restrict__ Xr, float* __restrict__ Xi,
    const float* __restrict__ w1, const float* __restrict__ b1,
    const float* __restrict__ w2, const float* __restrict__ b2) {
  __shared__ unsigned short sXr[128 * 104];      // 26.6 KB (reused for R1)
  __shared__ unsigned short sXi[128 * 104];      // 26.6 KB (reused for I1)
  __shared__ unsigned short sW[4][96 * 104];     // 4 x 19.97 KB: w1r,w1i,w2r,w2i
  const int t = threadIdx.x;
  const int lane = t & 63;
  const int wid = t >> 6;   // 0..7
  const int wm = wid >> 1;  // 0..3: rows wm*32
  const int wn = wid & 1;   // 0..1: cols wn*48
  const int cl = lane & 15;
  const int kg = lane >> 4;
  const int nb = blockIdx.y;
  const size_t p0 = (size_t)blockIdx.x * 128;

  // ---- stage X tile: fp32 global -> bf16 LDS ----
  {
    const int row = t >> 2;
    const int q = t & 3;  // 24-float chunk
    const size_t gbase = (p0 + row) * 768 + nb * 96 + q * 24;
    unsigned short* lr = sXr + row * 104 + q * 24;
    unsigned short* li = sXi + row * 104 + q * 24;
    const float4* gr = reinterpret_cast<const float4*>(Xr + gbase);
    const float4* gi = reinterpret_cast<const float4*>(Xi + gbase);
#pragma unroll
    for (int v = 0; v < 3; ++v) {
      float4 a = gr[v * 2], b = gr[v * 2 + 1];
      short8 s;
      s[0] = (short)f2bf(a.x); s[1] = (short)f2bf(a.y);
      s[2] = (short)f2bf(a.z); s[3] = (short)f2bf(a.w);
      s[4] = (short)f2bf(b.x); s[5] = (short)f2bf(b.y);
      s[6] = (short)f2bf(b.z); s[7] = (short)f2bf(b.w);
      *reinterpret_cast<short8*>(lr + v * 8) = s;
      a = gi[v * 2]; b = gi[v * 2 + 1];
      s[0] = (short)f2bf(a.x); s[1] = (short)f2bf(a.y);
      s[2] = (short)f2bf(a.z); s[3] = (short)f2bf(a.w);
      s[4] = (short)f2bf(b.x); s[5] = (short)f2bf(b.y);
      s[6] = (short)f2bf(b.z); s[7] = (short)f2bf(b.w);
      *reinterpret_cast<short8*>(li + v * 8) = s;
    }
  }
  // ---- stage weights transposed: sW[m][n][d] = w[m..][d][n], bf16 ----
  {
    const float* srcs[4] = {w1 + (size_t)nb * 9216, w1 + (size_t)(8 + nb) * 9216,
                            w2 + (size_t)nb * 9216, w2 + (size_t)(8 + nb) * 9216};
#pragma unroll
    for (int mtx = 0; mtx < 4; ++mtx) {
      const float* src = srcs[mtx];
      unsigned short* dst = sW[mtx];
      int idx = t;
      int d = t / 96;
      int n = t - d * 96;
#pragma unroll
      for (int e = 0; e < 18; ++e) {  // 512*18 = 9216
        dst[n * 104 + d] = f2bf(src[idx]);
        idx += 512; n += 32; d += 5;
        if (n >= 96) { n -= 96; d += 1; }
      }
    }
  }
  __syncthreads();

  f32x4 aR[2][3], aI[2][3];
#pragma unroll
  for (int mf = 0; mf < 2; ++mf)
#pragma unroll
    for (int nf = 0; nf < 3; ++nf) {
      aR[mf][nf] = (f32x4){0.f, 0.f, 0.f, 0.f};
      aI[mf][nf] = (f32x4){0.f, 0.f, 0.f, 0.f};
    }

  // ---- layer 1: R1 = relu(Xr*W1r - Xi*W1i + b1r), I1 = relu(Xr*W1i + Xi*W1r + b1i)
#pragma unroll
  for (int kk = 0; kk < 3; ++kk) {
    const int ko = kk * 32 + kg * 8;  // element offset within 104-row
    short8 xr_[2], xi_[2];
#pragma unroll
    for (int mf = 0; mf < 2; ++mf) {
      const int r = wm * 32 + mf * 16 + cl;
      xr_[mf] = *reinterpret_cast<const short8*>(sXr + r * 104 + ko);
      xi_[mf] = *reinterpret_cast<const short8*>(sXi + r * 104 + ko);
    }
    short8 wr_[3], wi_[3];
#pragma unroll
    for (int nf = 0; nf < 3; ++nf) {
      const int r = wn * 48 + nf * 16 + cl;
      wr_[nf] = *reinterpret_cast<const short8*>(sW[0] + r * 104 + ko);
      wi_[nf] = *reinterpret_cast<const short8*>(sW[1] + r * 104 + ko);
    }
#pragma unroll
    for (int mf = 0; mf < 2; ++mf) {
      const bf16x8 axr = s2b(xr_[mf]);
      const bf16x8 axi = s2b(xi_[mf]);
      const bf16x8 axin = negb(xi_[mf]);
#pragma unroll
      for (int nf = 0; nf < 3; ++nf) {
        aR[mf][nf] = __builtin_amdgcn_mfma_f32_16x16x32_bf16(axr, s2b(wr_[nf]), aR[mf][nf], 0, 0, 0);
        aR[mf][nf] = __builtin_amdgcn_mfma_f32_16x16x32_bf16(axin, s2b(wi_[nf]), aR[mf][nf], 0, 0, 0);
        aI[mf][nf] = __builtin_amdgcn_mfma_f32_16x16x32_bf16(axr, s2b(wi_[nf]), aI[mf][nf], 0, 0, 0);
        aI[mf][nf] = __builtin_amdgcn_mfma_f32_16x16x32_bf16(axi, s2b(wr_[nf]), aI[mf][nf], 0, 0, 0);
      }
    }
  }
  __syncthreads();  // all layer-1 LDS reads complete before overwrite

  // epilogue L1: bias + relu -> bf16 back into sXr/sXi
#pragma unroll
  for (int nf = 0; nf < 3; ++nf) {
    const int col = wn * 48 + nf * 16 + cl;
    const float br = b1[nb * 96 + col];
    const float bi = b1[768 + nb * 96 + col];
#pragma unroll
    for (int mf = 0; mf < 2; ++mf) {
#pragma unroll
      for (int r = 0; r < 4; ++r) {
        const int m = wm * 32 + mf * 16 + kg * 4 + r;
        const float vr = fmaxf(aR[mf][nf][r] + br, 0.f);
        const float vi = fmaxf(aI[mf][nf][r] + bi, 0.f);
        sXr[m * 104 + col] = f2bf(vr);
        sXi[m * 104 + col] = f2bf(vi);
      }
    }
  }
  __syncthreads();

  // ---- layer 2: R2 = R1*W2r - I1*W2i + b2r, I2 = R1*W2i + I1*W2r + b2i ----
#pragma unroll
  for (int mf = 0; mf < 2; ++mf)
#pragma unroll
    for (int nf = 0; nf < 3; ++nf) {
      aR[mf][nf] = (f32x4){0.f, 0.f, 0.f, 0.f};
      aI[mf][nf] = (f32x4){0.f, 0.f, 0.f, 0.f};
    }
#pragma unroll
  for (int kk = 0; kk < 3; ++kk) {
    const int ko = kk * 32 + kg * 8;
    short8 xr_[2], xi_[2];
#pragma unroll
    for (int mf = 0; mf < 2; ++mf) {
      const int r = wm * 32 + mf * 16 + cl;
      xr_[mf] = *reinterpret_cast<const short8*>(sXr + r * 104 + ko);
      xi_[mf] = *reinterpret_cast<const short8*>(sXi + r * 104 + ko);
    }
    short8 wr_[3], wi_[3];
#pragma unroll
    for (int nf = 0; nf < 3; ++nf) {
      const int r = wn * 48 + nf * 16 + cl;
      wr_[nf] = *reinterpret_cast<const short8*>(sW[2] + r * 104 + ko);
      wi_[nf] = *reinterpret_cast<const short8*>(sW[3] + r * 104 + ko);
    }
#pragma unroll
    for (int mf = 0; mf < 2; ++mf) {
      const bf16x8 axr = s2b(xr_[mf]);
      const bf16x8 axi = s2b(xi_[mf]);
      const bf16x8 axin = negb(xi_[mf]);
#pragma unroll
      for (int nf = 0; nf < 3; ++nf) {
        aR[mf][nf] = __builtin_amdgcn_mfma_f32_16x16x32_bf16(axr, s2b(wr_[nf]), aR[mf][nf], 0, 0, 0);
        aR[mf][nf] = __builtin_amdgcn_mfma_f32_16x16x32_bf16(axin, s2b(wi_[nf]), aR[mf][nf], 0, 0, 0);
        aI[mf][nf] = __builtin_amdgcn_mfma_f32_16x16x32_bf16(axr, s2b(wi_[nf]), aI[mf][nf], 0, 0, 0);
        aI[mf][nf] = __builtin_amdgcn_mfma_f32_16x16x32_bf16(axi, s2b(wr_[nf]), aI[mf][nf], 0, 0, 0);
      }
    }
  }

  // epilogue L2: bias + softshrink -> fp32 global (in place)
#pragma unroll
  for (int nf = 0; nf < 3; ++nf) {
    const int col = wn * 48 + nf * 16 + cl;
    const float br = b2[nb * 96 + col];
    const float bi = b2[768 + nb * 96 + col];
    const int gc = nb * 96 + col;
#pragma unroll
    for (int mf = 0; mf < 2; ++mf) {
#pragma unroll
      for (int r = 0; r < 4; ++r) {
        const int m = wm * 32 + mf * 16 + kg * 4 + r;
        float vr = aR[mf][nf][r] + br;
        float vi = aI[mf][nf][r] + bi;
        vr = (vr > kLambd) ? (vr - kLambd) : ((vr < -kLambd) ? (vr + kLambd) : 0.f);
        vi = (vi > kLambd) ? (vi - kLambd) : ((vi < -kLambd) ? (vi + kLambd) : 0.f);
        Xr[(p0 + m) * 768 + gc] = vr;
        Xi[(p0 + m) * 768 + gc] = vi;
      }
    }
  }
}

// ---------------- 6. inverse row rDFT + accumulate into out ----------------
// out[b, h*64+w, c] += (1/8) * sum_kw alpha_kw (Zr cos - Zi sin)
__global__ __launch_bounds__(256) void irfft_row_add_kernel(
    const float* __restrict__ Xr, const float* __restrict__ Xi,
    float* __restrict__ out) {
  __shared__ float zr[33][256];
  __shared__ float zi[33][256];
  __shared__ float ct[64];
  __shared__ float st[64];
  const int t = threadIdx.x;
  const int bh = blockIdx.x;  // b*64 + h
  const int c0 = blockIdx.y * 256;
  const int b = bh >> 6;
  const int h = bh & 63;
  if (t < 64) {
    float ang = (float)(2.0 * M_PI / 64.0) * (float)t;
    ct[t] = cosf(ang);
    st[t] = sinf(ang);
  }
  for (int kw = 0; kw <= 32; ++kw) {
    const float a = (kw == 0 || kw == 32) ? 0.125f : 0.25f;
    const size_t off = (((size_t)b * kNKW + kw) * 64 + h) * 768 + c0 + t;
    zr[kw][t] = a * Xr[off];
    zi[kw][t] = a * Xi[off];
  }
  __syncthreads();
  float* orow = out + (size_t)bh * (64 * 768) + c0 + t;
  for (int w = 0; w < 64; ++w) {
    float s = 0.f;
    int idx = 0;
#pragma unroll
    for (int kw = 0; kw <= 32; ++kw) {
      s += zr[kw][t] * ct[idx] - zi[kw][t] * st[idx];
      idx = (idx + w) & 63;
    }
    orow[(size_t)w * 768] += s;
  }
}

}  // namespace

extern "C" void kernel_launch(void* const* d_in, const int* in_sizes, int n_in,
                              void* d_out, int out_size, void* d_ws,
                              size_t ws_size, hipStream_t stream) {
  (void)in_sizes; (void)n_in; (void)out_size;
  const float* x  = (const float*)d_in[0];
  const float* w1 = (const float*)d_in[1];
  const float* b1 = (const float*)d_in[2];
  const float* w2 = (const float*)d_in[3];
  const float* b2 = (const float*)d_in[4];
  const float* Wb = (const float*)d_in[5];
  const float* bb = (const float*)d_in[6];
  float* out = (float*)d_out;

  if (ws_size < 2 * kXFElems * sizeof(float)) return;  // ws too small -> fail loudly
  float* XFr = (float*)d_ws;
  float* XFi = XFr + kXFElems;

  // bf16 scratch aliases XFr/XFi regions: GEMM finishes before rFFT writes them.
  unsigned short* xbf = (unsigned short*)XFr;   // 32768*768 bf16 = 48 MB (< 51.9 MB)
  unsigned short* wbf = (unsigned short*)XFi;   // 768*768 bf16

  // 0. convert x and Wb to bf16
  cvt_f32_bf16_kernel<<<dim3((32768 * 768 / 4 + 255) / 256), 256, 0, stream>>>(
      x, xbf, 32768 * 768 / 4);
  cvt_f32_bf16_kernel<<<dim3((768 * 768 / 4 + 255) / 256), 256, 0, stream>>>(
      Wb, wbf, 768 * 768 / 4);
  // 1. bias path GEMM on matrix cores (writes d_out fully)
  mfma_gemm_kernel<<<dim3(32768 / 128, 768 / 128), 256, 0, stream>>>(xbf, wbf, bb, out);
  // 2. forward row rFFT
  rfft_row_kernel<<<dim3(512, 3), 256, 0, stream>>>(x, XFr, XFi);
  // 3. forward column FFT
  fft_col_kernel<-1><<<dim3(264, 12), 256, 0, stream>>>(XFr, XFi);
  // 4. block-diagonal complex MLP on matrix cores (in place)
  mlp_mfma_kernel<<<dim3(132, 8), 512, 0, stream>>>(XFr, XFi, w1, b1, w2, b2);
  // 5. inverse column FFT
  fft_col_kernel<1><<<dim3(264, 12), 256, 0, stream>>>(XFr, XFi);
  // 6. inverse row rDFT + add bias path
  irfft_row_add_kernel<<<dim3(512, 3), 256, 0, stream>>>(XFr, XFi, out);
}

// Round 6
// 667.292 us; speedup vs baseline: 2.7075x; 1.6079x over previous
//
#include <hip/hip_runtime.h>
#include <math.h>

#ifndef M_PI
#define M_PI 3.14159265358979323846
#endif

namespace {

constexpr int kDim = 768;
constexpr int kNKW = 33;           // W/2+1
constexpr int kB = 8;
constexpr float kLambd = 0.01f;
constexpr size_t kXFElems = (size_t)kB * kNKW * 64 * kDim;  // 12,976,128

typedef __attribute__((ext_vector_type(8))) __bf16 bf16x8;
typedef __attribute__((ext_vector_type(8))) short short8;
typedef __attribute__((ext_vector_type(4))) float f32x4;

// RNE float -> bf16 (inputs are normal floats; NaN not expected)
__device__ inline unsigned short f2bf(float f) {
  unsigned int u = __float_as_uint(f);
  unsigned int r = (u + 0x7FFFu + ((u >> 16) & 1u)) >> 16;
  return (unsigned short)r;
}

__device__ inline bf16x8 s2b(short8 s) { return __builtin_bit_cast(bf16x8, s); }
__device__ inline bf16x8 negb(short8 s) {
  s ^= (short)0x8000;
  return __builtin_bit_cast(bf16x8, s);
}

__device__ inline void gload_lds16(const void* g, void* l) {
  __builtin_amdgcn_global_load_lds(
      (const __attribute__((address_space(1))) unsigned int*)g,
      (__attribute__((address_space(3))) unsigned int*)l, 16, 0, 0);
}

// ---------------- 0. fp32 -> bf16 conversion (grid-stride over groups of 4) --
__global__ __launch_bounds__(256) void cvt_f32_bf16_kernel(
    const float* __restrict__ in, unsigned short* __restrict__ out, int n4) {
  int i = blockIdx.x * 256 + threadIdx.x;
  if (i >= n4) return;
  const float4 v = reinterpret_cast<const float4*>(in)[i];
  ushort4 o;
  o.x = f2bf(v.x); o.y = f2bf(v.y); o.z = f2bf(v.z); o.w = f2bf(v.w);
  reinterpret_cast<ushort4*>(out)[i] = o;
}

// ---------------- 1. bias GEMM via MFMA ------------------------------------
// out[m,n] = sum_k xbf[m,k] * wbf[n,k] + bb[n]; M=32768, N=768, K=768.
__global__ __launch_bounds__(256) void mfma_gemm_kernel(
    const unsigned short* __restrict__ xbf, const unsigned short* __restrict__ wbf,
    const float* __restrict__ bb, float* __restrict__ out) {
  __shared__ unsigned short As[128 * 32];  // [row][k] 8KB
  __shared__ unsigned short Bs[128 * 32];  // [n][k]   8KB
  const int t = threadIdx.x;
  const int lane = t & 63;
  const int wid = t >> 6;
  const int wm = wid >> 1;
  const int wn = wid & 1;
  const int m0 = blockIdx.x * 128;
  const int n0 = blockIdx.y * 128;

  f32x4 acc[4][4];
#pragma unroll
  for (int i = 0; i < 4; ++i)
#pragma unroll
    for (int j = 0; j < 4; ++j) acc[i][j] = (f32x4){0.f, 0.f, 0.f, 0.f};

  char* AsB = (char*)As;
  char* BsB = (char*)Bs;
  const int cl = lane & 15;
  const int kg = lane >> 4;  // 0..3

  for (int k0 = 0; k0 < 768; k0 += 32) {
#pragma unroll
    for (int i = 0; i < 2; ++i) {
      const int off = (wid * 2 + i) * 1024 + lane * 16;  // byte off in tile
      const int row = off >> 6;
      const int kb = off & 63;
      const char* gA = (const char*)xbf + ((size_t)(m0 + row) * 768 + k0) * 2 + kb;
      gload_lds16(gA, AsB + (wid * 2 + i) * 1024);
      const char* gB = (const char*)wbf + ((size_t)(n0 + row) * 768 + k0) * 2 + kb;
      gload_lds16(gB, BsB + (wid * 2 + i) * 1024);
    }
    asm volatile("s_waitcnt vmcnt(0)" ::: "memory");
    __syncthreads();

    bf16x8 av[4], bv[4];
#pragma unroll
    for (int mi = 0; mi < 4; ++mi) {
      const int r = wm * 64 + mi * 16 + cl;
      av[mi] = *reinterpret_cast<const bf16x8*>(AsB + r * 64 + kg * 16);
    }
#pragma unroll
    for (int ni = 0; ni < 4; ++ni) {
      const int r = wn * 64 + ni * 16 + cl;
      bv[ni] = *reinterpret_cast<const bf16x8*>(BsB + r * 64 + kg * 16);
    }
#pragma unroll
    for (int mi = 0; mi < 4; ++mi)
#pragma unroll
      for (int ni = 0; ni < 4; ++ni)
        acc[mi][ni] = __builtin_amdgcn_mfma_f32_16x16x32_bf16(
            av[mi], bv[ni], acc[mi][ni], 0, 0, 0);
    __syncthreads();
  }

#pragma unroll
  for (int ni = 0; ni < 4; ++ni) {
    const int n = n0 + wn * 64 + ni * 16 + cl;
    const float bias = bb[n];
#pragma unroll
    for (int mi = 0; mi < 4; ++mi) {
      const int m = m0 + wm * 64 + mi * 16 + kg * 4;
#pragma unroll
      for (int r = 0; r < 4; ++r) {
        out[(size_t)(m + r) * 768 + n] = acc[mi][ni][r] + bias;
      }
    }
  }
}

// ---------------- 2. forward row rFFT along w -----------------------------
// XFr/XFi layout: [b][kw][h][c], scale 1/8, e^{-i 2pi kw w / 64}
__global__ __launch_bounds__(256) void rfft_row_kernel(
    const float* __restrict__ x, float* __restrict__ XFr,
    float* __restrict__ XFi) {
  __shared__ float xs[64][256];
  __shared__ float ct[64];
  __shared__ float st[64];
  const int t = threadIdx.x;
  const int bh = blockIdx.x;  // b*64 + h
  const int c0 = blockIdx.y * 256;
  if (t < 64) {
    float ang = (float)(2.0 * M_PI / 64.0) * (float)t;
    ct[t] = cosf(ang);
    st[t] = sinf(ang);
  }
  const float* xrow = x + (size_t)bh * (64 * 768) + c0 + t;
#pragma unroll 4
  for (int w = 0; w < 64; ++w) xs[w][t] = xrow[(size_t)w * 768];
  __syncthreads();
  const int b = bh >> 6;
  const int h = bh & 63;
  for (int kw = 0; kw <= 32; ++kw) {
    float sr = 0.f, si = 0.f;
    int idx = 0;
#pragma unroll 8
    for (int w = 0; w < 64; ++w) {
      const float v = xs[w][t];
      sr = fmaf(v, ct[idx], sr);
      si = fmaf(v, st[idx], si);
      idx = (idx + kw) & 63;
    }
    const size_t off = (((size_t)b * kNKW + kw) * 64 + h) * 768 + c0 + t;
    XFr[off] = 0.125f * sr;
    XFi[off] = -0.125f * si;
  }
}

// ---------------- 3/5. column FFT along h via MFMA (in place) --------------
// Per (b,kw) position: Out[kh][c] = sum_h T[kh][h] X[h][c], T = 0.125 e^{i SIGN theta}.
// A (twiddles) staged bf16 in LDS; B (data) built in registers from coalesced
// global loads (lane (cl,kg) reads X[h=kg*8+j][c], 16-lane groups = 64B lines).
// Each wave owns 16 c-columns exclusively -> in-place safe, no barriers needed
// after the twiddle fill.
template <int SIGN>
__global__ __launch_bounds__(256) void fft_col_mfma_kernel(
    float* __restrict__ Xr, float* __restrict__ Xi) {
  __shared__ alignas(16) unsigned short Cs[64 * 64];  // 0.125*cos  [kh][h] 8KB
  __shared__ alignas(16) unsigned short Ss[64 * 64];  // 0.125*SIGN*sin      8KB
  const int t = threadIdx.x;
  for (int e = t; e < 4096; e += 256) {
    const int kh = e >> 6;
    const int h = e & 63;
    const float ang = (float)(2.0 * M_PI / 64.0) * (float)((kh * h) & 63);
    float s_, c_;
    __sincosf(ang, &s_, &c_);
    Cs[e] = f2bf(0.125f * c_);
    Ss[e] = f2bf(0.125f * (float)SIGN * s_);
  }
  __syncthreads();

  const int lane = t & 63;
  const int wv = t >> 6;       // wave id 0..3 -> c-strip
  const int cl = lane & 15;
  const int kg = lane >> 4;    // 0..3
  // this lane's column
  const size_t cbase =
      (size_t)blockIdx.x * (64 * 768) + blockIdx.y * 64 + wv * 16 + cl;

  f32x4 aR[4], aI[4];
#pragma unroll
  for (int mi = 0; mi < 4; ++mi) {
    aR[mi] = (f32x4){0.f, 0.f, 0.f, 0.f};
    aI[mi] = (f32x4){0.f, 0.f, 0.f, 0.f};
  }

#pragma unroll
  for (int kf = 0; kf < 2; ++kf) {
    const int h0 = kf * 32 + kg * 8;
    float xr[8], xi[8];
#pragma unroll
    for (int j = 0; j < 8; ++j) {
      xr[j] = Xr[cbase + (size_t)(h0 + j) * 768];
      xi[j] = Xi[cbase + (size_t)(h0 + j) * 768];
    }
    short8 brf, bif;
#pragma unroll
    for (int j = 0; j < 8; ++j) {
      brf[j] = (short)f2bf(xr[j]);
      bif[j] = (short)f2bf(xi[j]);
    }
    const bf16x8 bxr = s2b(brf);
    const bf16x8 bxi = s2b(bif);
    const bf16x8 bxin = negb(bif);
#pragma unroll
    for (int mi = 0; mi < 4; ++mi) {
      const int arow = mi * 16 + cl;
      const bf16x8 ac =
          *reinterpret_cast<const bf16x8*>(Cs + arow * 64 + kf * 32 + kg * 8);
      const bf16x8 as =
          *reinterpret_cast<const bf16x8*>(Ss + arow * 64 + kf * 32 + kg * 8);
      aR[mi] = __builtin_amdgcn_mfma_f32_16x16x32_bf16(ac, bxr, aR[mi], 0, 0, 0);
      aR[mi] = __builtin_amdgcn_mfma_f32_16x16x32_bf16(as, bxin, aR[mi], 0, 0, 0);
      aI[mi] = __builtin_amdgcn_mfma_f32_16x16x32_bf16(ac, bxi, aI[mi], 0, 0, 0);
      aI[mi] = __builtin_amdgcn_mfma_f32_16x16x32_bf16(as, bxr, aI[mi], 0, 0, 0);
    }
  }

  // write back in place (this lane's column only)
#pragma unroll
  for (int mi = 0; mi < 4; ++mi) {
#pragma unroll
    for (int r = 0; r < 4; ++r) {
      const int kh = mi * 16 + kg * 4 + r;
      Xr[cbase + (size_t)kh * 768] = aR[mi][r];
      Xi[cbase + (size_t)kh * 768] = aI[mi][r];
    }
  }
}

// ---------------- 4. block-diagonal complex MLP via MFMA (in place) --------
// Per workgroup: 128 positions x one nb block (96 channels), both layers fused.
// LDS: X tiles + 4 weight matrices, all bf16, rows padded to 104 elems (208B).
__global__ __launch_bounds__(512) void mlp_mfma_kernel(
    float* __restrict__ Xr, float* __restrict__ Xi,
    const float* __restrict__ w1, const float* __restrict__ b1,
    const float* __restrict__ w2, const float* __restrict__ b2) {
  __shared__ unsigned short sXr[128 * 104];      // 26.6 KB (reused for R1)
  __shared__ unsigned short sXi[128 * 104];      // 26.6 KB (reused for I1)
  __shared__ unsigned short sW[4][96 * 104];     // 4 x 19.97 KB: w1r,w1i,w2r,w2i
  const int t = threadIdx.x;
  const int lane = t & 63;
  const int wid = t >> 6;   // 0..7
  const int wm = wid >> 1;  // 0..3: rows wm*32
  const int wn = wid & 1;   // 0..1: cols wn*48
  const int cl = lane & 15;
  const int kg = lane >> 4;
  const int nb = blockIdx.y;
  const size_t p0 = (size_t)blockIdx.x * 128;

  // ---- stage X tile: fp32 global -> bf16 LDS ----
  {
    const int row = t >> 2;
    const int q = t & 3;  // 24-float chunk
    const size_t gbase = (p0 + row) * 768 + nb * 96 + q * 24;
    unsigned short* lr = sXr + row * 104 + q * 24;
    unsigned short* li = sXi + row * 104 + q * 24;
    const float4* gr = reinterpret_cast<const float4*>(Xr + gbase);
    const float4* gi = reinterpret_cast<const float4*>(Xi + gbase);
#pragma unroll
    for (int v = 0; v < 3; ++v) {
      float4 a = gr[v * 2], b = gr[v * 2 + 1];
      short8 s;
      s[0] = (short)f2bf(a.x); s[1] = (short)f2bf(a.y);
      s[2] = (short)f2bf(a.z); s[3] = (short)f2bf(a.w);
      s[4] = (short)f2bf(b.x); s[5] = (short)f2bf(b.y);
      s[6] = (short)f2bf(b.z); s[7] = (short)f2bf(b.w);
      *reinterpret_cast<short8*>(lr + v * 8) = s;
      a = gi[v * 2]; b = gi[v * 2 + 1];
      s[0] = (short)f2bf(a.x); s[1] = (short)f2bf(a.y);
      s[2] = (short)f2bf(a.z); s[3] = (short)f2bf(a.w);
      s[4] = (short)f2bf(b.x); s[5] = (short)f2bf(b.y);
      s[6] = (short)f2bf(b.z); s[7] = (short)f2bf(b.w);
      *reinterpret_cast<short8*>(li + v * 8) = s;
    }
  }
  // ---- stage weights transposed: sW[m][n][d] = w[m..][d][n], bf16 ----
  {
    const float* srcs[4] = {w1 + (size_t)nb * 9216, w1 + (size_t)(8 + nb) * 9216,
                            w2 + (size_t)nb * 9216, w2 + (size_t)(8 + nb) * 9216};
#pragma unroll
    for (int mtx = 0; mtx < 4; ++mtx) {
      const float* src = srcs[mtx];
      unsigned short* dst = sW[mtx];
      int idx = t;
      int d = t / 96;
      int n = t - d * 96;
#pragma unroll
      for (int e = 0; e < 18; ++e) {  // 512*18 = 9216
        dst[n * 104 + d] = f2bf(src[idx]);
        idx += 512; n += 32; d += 5;
        if (n >= 96) { n -= 96; d += 1; }
      }
    }
  }
  __syncthreads();

  f32x4 aR[2][3], aI[2][3];
#pragma unroll
  for (int mf = 0; mf < 2; ++mf)
#pragma unroll
    for (int nf = 0; nf < 3; ++nf) {
      aR[mf][nf] = (f32x4){0.f, 0.f, 0.f, 0.f};
      aI[mf][nf] = (f32x4){0.f, 0.f, 0.f, 0.f};
    }

  // ---- layer 1: R1 = relu(Xr*W1r - Xi*W1i + b1r), I1 = relu(Xr*W1i + Xi*W1r + b1i)
#pragma unroll
  for (int kk = 0; kk < 3; ++kk) {
    const int ko = kk * 32 + kg * 8;  // element offset within 104-row
    short8 xr_[2], xi_[2];
#pragma unroll
    for (int mf = 0; mf < 2; ++mf) {
      const int r = wm * 32 + mf * 16 + cl;
      xr_[mf] = *reinterpret_cast<const short8*>(sXr + r * 104 + ko);
      xi_[mf] = *reinterpret_cast<const short8*>(sXi + r * 104 + ko);
    }
    short8 wr_[3], wi_[3];
#pragma unroll
    for (int nf = 0; nf < 3; ++nf) {
      const int r = wn * 48 + nf * 16 + cl;
      wr_[nf] = *reinterpret_cast<const short8*>(sW[0] + r * 104 + ko);
      wi_[nf] = *reinterpret_cast<const short8*>(sW[1] + r * 104 + ko);
    }
#pragma unroll
    for (int mf = 0; mf < 2; ++mf) {
      const bf16x8 axr = s2b(xr_[mf]);
      const bf16x8 axi = s2b(xi_[mf]);
      const bf16x8 axin = negb(xi_[mf]);
#pragma unroll
      for (int nf = 0; nf < 3; ++nf) {
        aR[mf][nf] = __builtin_amdgcn_mfma_f32_16x16x32_bf16(axr, s2b(wr_[nf]), aR[mf][nf], 0, 0, 0);
        aR[mf][nf] = __builtin_amdgcn_mfma_f32_16x16x32_bf16(axin, s2b(wi_[nf]), aR[mf][nf], 0, 0, 0);
        aI[mf][nf] = __builtin_amdgcn_mfma_f32_16x16x32_bf16(axr, s2b(wi_[nf]), aI[mf][nf], 0, 0, 0);
        aI[mf][nf] = __builtin_amdgcn_mfma_f32_16x16x32_bf16(axi, s2b(wr_[nf]), aI[mf][nf], 0, 0, 0);
      }
    }
  }
  __syncthreads();  // all layer-1 LDS reads complete before overwrite

  // epilogue L1: bias + relu -> bf16 back into sXr/sXi
#pragma unroll
  for (int nf = 0; nf < 3; ++nf) {
    const int col = wn * 48 + nf * 16 + cl;
    const float br = b1[nb * 96 + col];
    const float bi = b1[768 + nb * 96 + col];
#pragma unroll
    for (int mf = 0; mf < 2; ++mf) {
#pragma unroll
      for (int r = 0; r < 4; ++r) {
        const int m = wm * 32 + mf * 16 + kg * 4 + r;
        const float vr = fmaxf(aR[mf][nf][r] + br, 0.f);
        const float vi = fmaxf(aI[mf][nf][r] + bi, 0.f);
        sXr[m * 104 + col] = f2bf(vr);
        sXi[m * 104 + col] = f2bf(vi);
      }
    }
  }
  __syncthreads();

  // ---- layer 2: R2 = R1*W2r - I1*W2i + b2r, I2 = R1*W2i + I1*W2r + b2i ----
#pragma unroll
  for (int mf = 0; mf < 2; ++mf)
#pragma unroll
    for (int nf = 0; nf < 3; ++nf) {
      aR[mf][nf] = (f32x4){0.f, 0.f, 0.f, 0.f};
      aI[mf][nf] = (f32x4){0.f, 0.f, 0.f, 0.f};
    }
#pragma unroll
  for (int kk = 0; kk < 3; ++kk) {
    const int ko = kk * 32 + kg * 8;
    short8 xr_[2], xi_[2];
#pragma unroll
    for (int mf = 0; mf < 2; ++mf) {
      const int r = wm * 32 + mf * 16 + cl;
      xr_[mf] = *reinterpret_cast<const short8*>(sXr + r * 104 + ko);
      xi_[mf] = *reinterpret_cast<const short8*>(sXi + r * 104 + ko);
    }
    short8 wr_[3], wi_[3];
#pragma unroll
    for (int nf = 0; nf < 3; ++nf) {
      const int r = wn * 48 + nf * 16 + cl;
      wr_[nf] = *reinterpret_cast<const short8*>(sW[2] + r * 104 + ko);
      wi_[nf] = *reinterpret_cast<const short8*>(sW[3] + r * 104 + ko);
    }
#pragma unroll
    for (int mf = 0; mf < 2; ++mf) {
      const bf16x8 axr = s2b(xr_[mf]);
      const bf16x8 axi = s2b(xi_[mf]);
      const bf16x8 axin = negb(xi_[mf]);
#pragma unroll
      for (int nf = 0; nf < 3; ++nf) {
        aR[mf][nf] = __builtin_amdgcn_mfma_f32_16x16x32_bf16(axr, s2b(wr_[nf]), aR[mf][nf], 0, 0, 0);
        aR[mf][nf] = __builtin_amdgcn_mfma_f32_16x16x32_bf16(axin, s2b(wi_[nf]), aR[mf][nf], 0, 0, 0);
        aI[mf][nf] = __builtin_amdgcn_mfma_f32_16x16x32_bf16(axr, s2b(wi_[nf]), aI[mf][nf], 0, 0, 0);
        aI[mf][nf] = __builtin_amdgcn_mfma_f32_16x16x32_bf16(axi, s2b(wr_[nf]), aI[mf][nf], 0, 0, 0);
      }
    }
  }

  // epilogue L2: bias + softshrink -> fp32 global (in place)
#pragma unroll
  for (int nf = 0; nf < 3; ++nf) {
    const int col = wn * 48 + nf * 16 + cl;
    const float br = b2[nb * 96 + col];
    const float bi = b2[768 + nb * 96 + col];
    const int gc = nb * 96 + col;
#pragma unroll
    for (int mf = 0; mf < 2; ++mf) {
#pragma unroll
      for (int r = 0; r < 4; ++r) {
        const int m = wm * 32 + mf * 16 + kg * 4 + r;
        float vr = aR[mf][nf][r] + br;
        float vi = aI[mf][nf][r] + bi;
        vr = (vr > kLambd) ? (vr - kLambd) : ((vr < -kLambd) ? (vr + kLambd) : 0.f);
        vi = (vi > kLambd) ? (vi - kLambd) : ((vi < -kLambd) ? (vi + kLambd) : 0.f);
        Xr[(p0 + m) * 768 + gc] = vr;
        Xi[(p0 + m) * 768 + gc] = vi;
      }
    }
  }
}

// ---------------- 6. inverse row rDFT + accumulate into out ----------------
// out[b, h*64+w, c] += (1/8) * sum_kw alpha_kw (Zr cos - Zi sin)
__global__ __launch_bounds__(256) void irfft_row_add_kernel(
    const float* __restrict__ Xr, const float* __restrict__ Xi,
    float* __restrict__ out) {
  __shared__ float zr[33][256];
  __shared__ float zi[33][256];
  __shared__ float ct[64];
  __shared__ float st[64];
  const int t = threadIdx.x;
  const int bh = blockIdx.x;  // b*64 + h
  const int c0 = blockIdx.y * 256;
  const int b = bh >> 6;
  const int h = bh & 63;
  if (t < 64) {
    float ang = (float)(2.0 * M_PI / 64.0) * (float)t;
    ct[t] = cosf(ang);
    st[t] = sinf(ang);
  }
  for (int kw = 0; kw <= 32; ++kw) {
    const float a = (kw == 0 || kw == 32) ? 0.125f : 0.25f;
    const size_t off = (((size_t)b * kNKW + kw) * 64 + h) * 768 + c0 + t;
    zr[kw][t] = a * Xr[off];
    zi[kw][t] = a * Xi[off];
  }
  __syncthreads();
  float* orow = out + (size_t)bh * (64 * 768) + c0 + t;
  for (int w = 0; w < 64; ++w) {
    float s = 0.f;
    int idx = 0;
#pragma unroll
    for (int kw = 0; kw <= 32; ++kw) {
      s += zr[kw][t] * ct[idx] - zi[kw][t] * st[idx];
      idx = (idx + w) & 63;
    }
    orow[(size_t)w * 768] += s;
  }
}

}  // namespace

extern "C" void kernel_launch(void* const* d_in, const int* in_sizes, int n_in,
                              void* d_out, int out_size, void* d_ws,
                              size_t ws_size, hipStream_t stream) {
  (void)in_sizes; (void)n_in; (void)out_size;
  const float* x  = (const float*)d_in[0];
  const float* w1 = (const float*)d_in[1];
  const float* b1 = (const float*)d_in[2];
  const float* w2 = (const float*)d_in[3];
  const float* b2 = (const float*)d_in[4];
  const float* Wb = (const float*)d_in[5];
  const float* bb = (const float*)d_in[6];
  float* out = (float*)d_out;

  if (ws_size < 2 * kXFElems * sizeof(float)) return;  // ws too small -> fail loudly
  float* XFr = (float*)d_ws;
  float* XFi = XFr + kXFElems;

  // bf16 scratch aliases XFr/XFi regions: GEMM finishes before rFFT writes them.
  unsigned short* xbf = (unsigned short*)XFr;   // 32768*768 bf16 = 48 MB (< 51.9 MB)
  unsigned short* wbf = (unsigned short*)XFi;   // 768*768 bf16

  // 0. convert x and Wb to bf16
  cvt_f32_bf16_kernel<<<dim3((32768 * 768 / 4 + 255) / 256), 256, 0, stream>>>(
      x, xbf, 32768 * 768 / 4);
  cvt_f32_bf16_kernel<<<dim3((768 * 768 / 4 + 255) / 256), 256, 0, stream>>>(
      Wb, wbf, 768 * 768 / 4);
  // 1. bias path GEMM on matrix cores (writes d_out fully)
  mfma_gemm_kernel<<<dim3(32768 / 128, 768 / 128), 256, 0, stream>>>(xbf, wbf, bb, out);
  // 2. forward row rFFT
  rfft_row_kernel<<<dim3(512, 3), 256, 0, stream>>>(x, XFr, XFi);
  // 3. forward column FFT on matrix cores (in place)
  fft_col_mfma_kernel<-1><<<dim3(264, 12), 256, 0, stream>>>(XFr, XFi);
  // 4. block-diagonal complex MLP on matrix cores (in place)
  mlp_mfma_kernel<<<dim3(132, 8), 512, 0, stream>>>(XFr, XFi, w1, b1, w2, b2);
  // 5. inverse column FFT on matrix cores (in place)
  fft_col_mfma_kernel<1><<<dim3(264, 12), 256, 0, stream>>>(XFr, XFi);
  // 6. inverse row rDFT + add bias path
  irfft_row_add_kernel<<<dim3(512, 3), 256, 0, stream>>>(XFr, XFi, out);
}

// Round 7
// 340.940 us; speedup vs baseline: 5.2991x; 1.9572x over previous
//
#include <hip/hip_runtime.h>
#include <math.h>

#ifndef M_PI
#define M_PI 3.14159265358979323846
#endif

namespace {

constexpr int kDim = 768;
constexpr int kNKW = 33;           // W/2+1
constexpr int kB = 8;
constexpr float kLambd = 0.01f;
constexpr size_t kXFElems = (size_t)kB * kNKW * 64 * kDim;  // 12,976,128

typedef __attribute__((ext_vector_type(8))) __bf16 bf16x8;
typedef __attribute__((ext_vector_type(8))) short short8;
typedef __attribute__((ext_vector_type(4))) float f32x4;

// RNE float -> bf16 (inputs are normal floats; NaN not expected)
__device__ inline unsigned short f2bf(float f) {
  unsigned int u = __float_as_uint(f);
  unsigned int r = (u + 0x7FFFu + ((u >> 16) & 1u)) >> 16;
  return (unsigned short)r;
}

__device__ inline bf16x8 s2b(short8 s) { return __builtin_bit_cast(bf16x8, s); }
__device__ inline bf16x8 negb(short8 s) {
  s ^= (short)0x8000;
  return __builtin_bit_cast(bf16x8, s);
}

__device__ inline void gload_lds16(const void* g, void* l) {
  __builtin_amdgcn_global_load_lds(
      (const __attribute__((address_space(1))) unsigned int*)g,
      (__attribute__((address_space(3))) unsigned int*)l, 16, 0, 0);
}

// ---------------- 0. fp32 -> bf16 conversion (grid-stride over groups of 4) --
__global__ __launch_bounds__(256) void cvt_f32_bf16_kernel(
    const float* __restrict__ in, unsigned short* __restrict__ out, int n4) {
  int i = blockIdx.x * 256 + threadIdx.x;
  if (i >= n4) return;
  const float4 v = reinterpret_cast<const float4*>(in)[i];
  ushort4 o;
  o.x = f2bf(v.x); o.y = f2bf(v.y); o.z = f2bf(v.z); o.w = f2bf(v.w);
  reinterpret_cast<ushort4*>(out)[i] = o;
}

// ---------------- 1. bias GEMM via MFMA ------------------------------------
// out[m,n] = sum_k xbf[m,k] * wbf[n,k] + bb[n]; M=32768, N=768, K=768.
__global__ __launch_bounds__(256) void mfma_gemm_kernel(
    const unsigned short* __restrict__ xbf, const unsigned short* __restrict__ wbf,
    const float* __restrict__ bb, float* __restrict__ out) {
  __shared__ unsigned short As[128 * 32];  // [row][k] 8KB
  __shared__ unsigned short Bs[128 * 32];  // [n][k]   8KB
  const int t = threadIdx.x;
  const int lane = t & 63;
  const int wid = t >> 6;
  const int wm = wid >> 1;
  const int wn = wid & 1;
  const int m0 = blockIdx.x * 128;
  const int n0 = blockIdx.y * 128;

  f32x4 acc[4][4];
#pragma unroll
  for (int i = 0; i < 4; ++i)
#pragma unroll
    for (int j = 0; j < 4; ++j) acc[i][j] = (f32x4){0.f, 0.f, 0.f, 0.f};

  char* AsB = (char*)As;
  char* BsB = (char*)Bs;
  const int cl = lane & 15;
  const int kg = lane >> 4;  // 0..3

  for (int k0 = 0; k0 < 768; k0 += 32) {
#pragma unroll
    for (int i = 0; i < 2; ++i) {
      const int off = (wid * 2 + i) * 1024 + lane * 16;  // byte off in tile
      const int row = off >> 6;
      const int kb = off & 63;
      const char* gA = (const char*)xbf + ((size_t)(m0 + row) * 768 + k0) * 2 + kb;
      gload_lds16(gA, AsB + (wid * 2 + i) * 1024);
      const char* gB = (const char*)wbf + ((size_t)(n0 + row) * 768 + k0) * 2 + kb;
      gload_lds16(gB, BsB + (wid * 2 + i) * 1024);
    }
    asm volatile("s_waitcnt vmcnt(0)" ::: "memory");
    __syncthreads();

    bf16x8 av[4], bv[4];
#pragma unroll
    for (int mi = 0; mi < 4; ++mi) {
      const int r = wm * 64 + mi * 16 + cl;
      av[mi] = *reinterpret_cast<const bf16x8*>(AsB + r * 64 + kg * 16);
    }
#pragma unroll
    for (int ni = 0; ni < 4; ++ni) {
      const int r = wn * 64 + ni * 16 + cl;
      bv[ni] = *reinterpret_cast<const bf16x8*>(BsB + r * 64 + kg * 16);
    }
#pragma unroll
    for (int mi = 0; mi < 4; ++mi)
#pragma unroll
      for (int ni = 0; ni < 4; ++ni)
        acc[mi][ni] = __builtin_amdgcn_mfma_f32_16x16x32_bf16(
            av[mi], bv[ni], acc[mi][ni], 0, 0, 0);
    __syncthreads();
  }

#pragma unroll
  for (int ni = 0; ni < 4; ++ni) {
    const int n = n0 + wn * 64 + ni * 16 + cl;
    const float bias = bb[n];
#pragma unroll
    for (int mi = 0; mi < 4; ++mi) {
      const int m = m0 + wm * 64 + mi * 16 + kg * 4;
#pragma unroll
      for (int r = 0; r < 4; ++r) {
        out[(size_t)(m + r) * 768 + n] = acc[mi][ni][r] + bias;
      }
    }
  }
}

// ---------------- 2. forward row rFFT via MFMA ------------------------------
// Out[kh][c] = sum_w T[kh][w] x[w][c]; T = 0.125 e^{-i 2pi kh w/64}; real input.
// XFr/XFi layout: [b][kw][h][c]. M=48 rows computed, kh<=32 written.
__global__ __launch_bounds__(256) void rfft_row_mfma_kernel(
    const float* __restrict__ x, float* __restrict__ XFr,
    float* __restrict__ XFi) {
  __shared__ alignas(16) unsigned short Cs[48 * 64];  //  0.125*cos [kh][w] 6KB
  __shared__ alignas(16) unsigned short Ss[48 * 64];  // -0.125*sin        6KB
  const int t = threadIdx.x;
  for (int e = t; e < 48 * 64; e += 256) {
    const int kh = e >> 6;
    const int w = e & 63;
    const float ang = (float)(2.0 * M_PI / 64.0) * (float)((kh * w) & 63);
    float s_, c_;
    __sincosf(ang, &s_, &c_);
    Cs[e] = f2bf(0.125f * c_);
    Ss[e] = f2bf(-0.125f * s_);
  }
  __syncthreads();

  const int lane = t & 63;
  const int wv = t >> 6;       // wave -> c-strip
  const int cl = lane & 15;
  const int kg = lane >> 4;    // 0..3
  const int bh = blockIdx.x;   // b*64 + h
  const int b = bh >> 6;
  const int h = bh & 63;
  const int c = blockIdx.y * 64 + wv * 16 + cl;
  const float* xcol = x + ((size_t)bh * 64) * 768 + c;

  f32x4 aR[3], aI[3];
#pragma unroll
  for (int mi = 0; mi < 3; ++mi) {
    aR[mi] = (f32x4){0.f, 0.f, 0.f, 0.f};
    aI[mi] = (f32x4){0.f, 0.f, 0.f, 0.f};
  }

#pragma unroll
  for (int kf = 0; kf < 2; ++kf) {
    const int w0 = kf * 32 + kg * 8;
    float xv[8];
#pragma unroll
    for (int j = 0; j < 8; ++j) xv[j] = xcol[(size_t)(w0 + j) * 768];
    short8 bs;
#pragma unroll
    for (int j = 0; j < 8; ++j) bs[j] = (short)f2bf(xv[j]);
    const bf16x8 bx = s2b(bs);
#pragma unroll
    for (int mi = 0; mi < 3; ++mi) {
      const int arow = mi * 16 + cl;
      const bf16x8 ac =
          *reinterpret_cast<const bf16x8*>(Cs + arow * 64 + kf * 32 + kg * 8);
      const bf16x8 as =
          *reinterpret_cast<const bf16x8*>(Ss + arow * 64 + kf * 32 + kg * 8);
      aR[mi] = __builtin_amdgcn_mfma_f32_16x16x32_bf16(ac, bx, aR[mi], 0, 0, 0);
      aI[mi] = __builtin_amdgcn_mfma_f32_16x16x32_bf16(as, bx, aI[mi], 0, 0, 0);
    }
  }

#pragma unroll
  for (int mi = 0; mi < 3; ++mi) {
#pragma unroll
    for (int r = 0; r < 4; ++r) {
      const int kh = mi * 16 + kg * 4 + r;
      if (kh <= 32) {
        const size_t off = (((size_t)b * kNKW + kh) * 64 + h) * 768 + c;
        XFr[off] = aR[mi][r];
        XFi[off] = aI[mi][r];
      }
    }
  }
}

// ---------------- 3/5. column FFT along h via MFMA (in place) --------------
template <int SIGN>
__global__ __launch_bounds__(256) void fft_col_mfma_kernel(
    float* __restrict__ Xr, float* __restrict__ Xi) {
  __shared__ alignas(16) unsigned short Cs[64 * 64];  // 0.125*cos  [kh][h] 8KB
  __shared__ alignas(16) unsigned short Ss[64 * 64];  // 0.125*SIGN*sin      8KB
  const int t = threadIdx.x;
  for (int e = t; e < 4096; e += 256) {
    const int kh = e >> 6;
    const int h = e & 63;
    const float ang = (float)(2.0 * M_PI / 64.0) * (float)((kh * h) & 63);
    float s_, c_;
    __sincosf(ang, &s_, &c_);
    Cs[e] = f2bf(0.125f * c_);
    Ss[e] = f2bf(0.125f * (float)SIGN * s_);
  }
  __syncthreads();

  const int lane = t & 63;
  const int wv = t >> 6;       // wave id 0..3 -> c-strip
  const int cl = lane & 15;
  const int kg = lane >> 4;    // 0..3
  const size_t cbase =
      (size_t)blockIdx.x * (64 * 768) + blockIdx.y * 64 + wv * 16 + cl;

  f32x4 aR[4], aI[4];
#pragma unroll
  for (int mi = 0; mi < 4; ++mi) {
    aR[mi] = (f32x4){0.f, 0.f, 0.f, 0.f};
    aI[mi] = (f32x4){0.f, 0.f, 0.f, 0.f};
  }

#pragma unroll
  for (int kf = 0; kf < 2; ++kf) {
    const int h0 = kf * 32 + kg * 8;
    float xr[8], xi[8];
#pragma unroll
    for (int j = 0; j < 8; ++j) {
      xr[j] = Xr[cbase + (size_t)(h0 + j) * 768];
      xi[j] = Xi[cbase + (size_t)(h0 + j) * 768];
    }
    short8 brf, bif;
#pragma unroll
    for (int j = 0; j < 8; ++j) {
      brf[j] = (short)f2bf(xr[j]);
      bif[j] = (short)f2bf(xi[j]);
    }
    const bf16x8 bxr = s2b(brf);
    const bf16x8 bxi = s2b(bif);
    const bf16x8 bxin = negb(bif);
#pragma unroll
    for (int mi = 0; mi < 4; ++mi) {
      const int arow = mi * 16 + cl;
      const bf16x8 ac =
          *reinterpret_cast<const bf16x8*>(Cs + arow * 64 + kf * 32 + kg * 8);
      const bf16x8 as =
          *reinterpret_cast<const bf16x8*>(Ss + arow * 64 + kf * 32 + kg * 8);
      aR[mi] = __builtin_amdgcn_mfma_f32_16x16x32_bf16(ac, bxr, aR[mi], 0, 0, 0);
      aR[mi] = __builtin_amdgcn_mfma_f32_16x16x32_bf16(as, bxin, aR[mi], 0, 0, 0);
      aI[mi] = __builtin_amdgcn_mfma_f32_16x16x32_bf16(ac, bxi, aI[mi], 0, 0, 0);
      aI[mi] = __builtin_amdgcn_mfma_f32_16x16x32_bf16(as, bxr, aI[mi], 0, 0, 0);
    }
  }

#pragma unroll
  for (int mi = 0; mi < 4; ++mi) {
#pragma unroll
    for (int r = 0; r < 4; ++r) {
      const int kh = mi * 16 + kg * 4 + r;
      Xr[cbase + (size_t)kh * 768] = aR[mi][r];
      Xi[cbase + (size_t)kh * 768] = aI[mi][r];
    }
  }
}

// ---------------- 4. block-diagonal complex MLP via MFMA (in place) --------
__global__ __launch_bounds__(512) void mlp_mfma_kernel(
    float* __restrict__ Xr, float* __restrict__ Xi,
    const float* __restrict__ w1, const float* __restrict__ b1,
    const float* __restrict__ w2, const float* __restrict__ b2) {
  __shared__ unsigned short sXr[128 * 104];      // 26.6 KB (reused for R1)
  __shared__ unsigned short sXi[128 * 104];      // 26.6 KB (reused for I1)
  __shared__ unsigned short sW[4][96 * 104];     // 4 x 19.97 KB: w1r,w1i,w2r,w2i
  const int t = threadIdx.x;
  const int lane = t & 63;
  const int wid = t >> 6;   // 0..7
  const int wm = wid >> 1;  // 0..3: rows wm*32
  const int wn = wid & 1;   // 0..1: cols wn*48
  const int cl = lane & 15;
  const int kg = lane >> 4;
  const int nb = blockIdx.y;
  const size_t p0 = (size_t)blockIdx.x * 128;

  // ---- stage X tile: fp32 global -> bf16 LDS ----
  {
    const int row = t >> 2;
    const int q = t & 3;  // 24-float chunk
    const size_t gbase = (p0 + row) * 768 + nb * 96 + q * 24;
    unsigned short* lr = sXr + row * 104 + q * 24;
    unsigned short* li = sXi + row * 104 + q * 24;
    const float4* gr = reinterpret_cast<const float4*>(Xr + gbase);
    const float4* gi = reinterpret_cast<const float4*>(Xi + gbase);
#pragma unroll
    for (int v = 0; v < 3; ++v) {
      float4 a = gr[v * 2], b = gr[v * 2 + 1];
      short8 s;
      s[0] = (short)f2bf(a.x); s[1] = (short)f2bf(a.y);
      s[2] = (short)f2bf(a.z); s[3] = (short)f2bf(a.w);
      s[4] = (short)f2bf(b.x); s[5] = (short)f2bf(b.y);
      s[6] = (short)f2bf(b.z); s[7] = (short)f2bf(b.w);
      *reinterpret_cast<short8*>(lr + v * 8) = s;
      a = gi[v * 2]; b = gi[v * 2 + 1];
      s[0] = (short)f2bf(a.x); s[1] = (short)f2bf(a.y);
      s[2] = (short)f2bf(a.z); s[3] = (short)f2bf(a.w);
      s[4] = (short)f2bf(b.x); s[5] = (short)f2bf(b.y);
      s[6] = (short)f2bf(b.z); s[7] = (short)f2bf(b.w);
      *reinterpret_cast<short8*>(li + v * 8) = s;
    }
  }
  // ---- stage weights transposed: sW[m][n][d] = w[m..][d][n], bf16 ----
  {
    const float* srcs[4] = {w1 + (size_t)nb * 9216, w1 + (size_t)(8 + nb) * 9216,
                            w2 + (size_t)nb * 9216, w2 + (size_t)(8 + nb) * 9216};
#pragma unroll
    for (int mtx = 0; mtx < 4; ++mtx) {
      const float* src = srcs[mtx];
      unsigned short* dst = sW[mtx];
      int idx = t;
      int d = t / 96;
      int n = t - d * 96;
#pragma unroll
      for (int e = 0; e < 18; ++e) {  // 512*18 = 9216
        dst[n * 104 + d] = f2bf(src[idx]);
        idx += 512; n += 32; d += 5;
        if (n >= 96) { n -= 96; d += 1; }
      }
    }
  }
  __syncthreads();

  f32x4 aR[2][3], aI[2][3];
#pragma unroll
  for (int mf = 0; mf < 2; ++mf)
#pragma unroll
    for (int nf = 0; nf < 3; ++nf) {
      aR[mf][nf] = (f32x4){0.f, 0.f, 0.f, 0.f};
      aI[mf][nf] = (f32x4){0.f, 0.f, 0.f, 0.f};
    }

  // ---- layer 1 ----
#pragma unroll
  for (int kk = 0; kk < 3; ++kk) {
    const int ko = kk * 32 + kg * 8;
    short8 xr_[2], xi_[2];
#pragma unroll
    for (int mf = 0; mf < 2; ++mf) {
      const int r = wm * 32 + mf * 16 + cl;
      xr_[mf] = *reinterpret_cast<const short8*>(sXr + r * 104 + ko);
      xi_[mf] = *reinterpret_cast<const short8*>(sXi + r * 104 + ko);
    }
    short8 wr_[3], wi_[3];
#pragma unroll
    for (int nf = 0; nf < 3; ++nf) {
      const int r = wn * 48 + nf * 16 + cl;
      wr_[nf] = *reinterpret_cast<const short8*>(sW[0] + r * 104 + ko);
      wi_[nf] = *reinterpret_cast<const short8*>(sW[1] + r * 104 + ko);
    }
#pragma unroll
    for (int mf = 0; mf < 2; ++mf) {
      const bf16x8 axr = s2b(xr_[mf]);
      const bf16x8 axi = s2b(xi_[mf]);
      const bf16x8 axin = negb(xi_[mf]);
#pragma unroll
      for (int nf = 0; nf < 3; ++nf) {
        aR[mf][nf] = __builtin_amdgcn_mfma_f32_16x16x32_bf16(axr, s2b(wr_[nf]), aR[mf][nf], 0, 0, 0);
        aR[mf][nf] = __builtin_amdgcn_mfma_f32_16x16x32_bf16(axin, s2b(wi_[nf]), aR[mf][nf], 0, 0, 0);
        aI[mf][nf] = __builtin_amdgcn_mfma_f32_16x16x32_bf16(axr, s2b(wi_[nf]), aI[mf][nf], 0, 0, 0);
        aI[mf][nf] = __builtin_amdgcn_mfma_f32_16x16x32_bf16(axi, s2b(wr_[nf]), aI[mf][nf], 0, 0, 0);
      }
    }
  }
  __syncthreads();

  // epilogue L1: bias + relu -> bf16 back into sXr/sXi
#pragma unroll
  for (int nf = 0; nf < 3; ++nf) {
    const int col = wn * 48 + nf * 16 + cl;
    const float br = b1[nb * 96 + col];
    const float bi = b1[768 + nb * 96 + col];
#pragma unroll
    for (int mf = 0; mf < 2; ++mf) {
#pragma unroll
      for (int r = 0; r < 4; ++r) {
        const int m = wm * 32 + mf * 16 + kg * 4 + r;
        const float vr = fmaxf(aR[mf][nf][r] + br, 0.f);
        const float vi = fmaxf(aI[mf][nf][r] + bi, 0.f);
        sXr[m * 104 + col] = f2bf(vr);
        sXi[m * 104 + col] = f2bf(vi);
      }
    }
  }
  __syncthreads();

  // ---- layer 2 ----
#pragma unroll
  for (int mf = 0; mf < 2; ++mf)
#pragma unroll
    for (int nf = 0; nf < 3; ++nf) {
      aR[mf][nf] = (f32x4){0.f, 0.f, 0.f, 0.f};
      aI[mf][nf] = (f32x4){0.f, 0.f, 0.f, 0.f};
    }
#pragma unroll
  for (int kk = 0; kk < 3; ++kk) {
    const int ko = kk * 32 + kg * 8;
    short8 xr_[2], xi_[2];
#pragma unroll
    for (int mf = 0; mf < 2; ++mf) {
      const int r = wm * 32 + mf * 16 + cl;
      xr_[mf] = *reinterpret_cast<const short8*>(sXr + r * 104 + ko);
      xi_[mf] = *reinterpret_cast<const short8*>(sXi + r * 104 + ko);
    }
    short8 wr_[3], wi_[3];
#pragma unroll
    for (int nf = 0; nf < 3; ++nf) {
      const int r = wn * 48 + nf * 16 + cl;
      wr_[nf] = *reinterpret_cast<const short8*>(sW[2] + r * 104 + ko);
      wi_[nf] = *reinterpret_cast<const short8*>(sW[3] + r * 104 + ko);
    }
#pragma unroll
    for (int mf = 0; mf < 2; ++mf) {
      const bf16x8 axr = s2b(xr_[mf]);
      const bf16x8 axi = s2b(xi_[mf]);
      const bf16x8 axin = negb(xi_[mf]);
#pragma unroll
      for (int nf = 0; nf < 3; ++nf) {
        aR[mf][nf] = __builtin_amdgcn_mfma_f32_16x16x32_bf16(axr, s2b(wr_[nf]), aR[mf][nf], 0, 0, 0);
        aR[mf][nf] = __builtin_amdgcn_mfma_f32_16x16x32_bf16(axin, s2b(wi_[nf]), aR[mf][nf], 0, 0, 0);
        aI[mf][nf] = __builtin_amdgcn_mfma_f32_16x16x32_bf16(axr, s2b(wi_[nf]), aI[mf][nf], 0, 0, 0);
        aI[mf][nf] = __builtin_amdgcn_mfma_f32_16x16x32_bf16(axi, s2b(wr_[nf]), aI[mf][nf], 0, 0, 0);
      }
    }
  }

  // epilogue L2: bias + softshrink -> fp32 global (in place)
#pragma unroll
  for (int nf = 0; nf < 3; ++nf) {
    const int col = wn * 48 + nf * 16 + cl;
    const float br = b2[nb * 96 + col];
    const float bi = b2[768 + nb * 96 + col];
    const int gc = nb * 96 + col;
#pragma unroll
    for (int mf = 0; mf < 2; ++mf) {
#pragma unroll
      for (int r = 0; r < 4; ++r) {
        const int m = wm * 32 + mf * 16 + kg * 4 + r;
        float vr = aR[mf][nf][r] + br;
        float vi = aI[mf][nf][r] + bi;
        vr = (vr > kLambd) ? (vr - kLambd) : ((vr < -kLambd) ? (vr + kLambd) : 0.f);
        vi = (vi > kLambd) ? (vi - kLambd) : ((vi < -kLambd) ? (vi + kLambd) : 0.f);
        Xr[(p0 + m) * 768 + gc] = vr;
        Xi[(p0 + m) * 768 + gc] = vi;
      }
    }
  }
}

// ---------------- 6. inverse row rDFT + accumulate via MFMA ----------------
// out[w][c] += sum_kw Ac[w][kw] Zr[kw][c] + As[w][kw] Zi[kw][c]
// Ac = alpha_kw cos, As = -alpha_kw sin; K padded 33->64 with zero columns.
// Accumulator preloaded with existing out values (bias path).
__global__ __launch_bounds__(256) void irfft_row_add_mfma_kernel(
    const float* __restrict__ Zr, const float* __restrict__ Zi,
    float* __restrict__ out) {
  __shared__ alignas(16) unsigned short Ac[64 * 64];   // [w][kw] 8KB
  __shared__ alignas(16) unsigned short Asn[64 * 64];  // [w][kw] 8KB
  const int t = threadIdx.x;
  for (int e = t; e < 4096; e += 256) {
    const int w = e >> 6;
    const int kw = e & 63;
    if (kw < 33) {
      const float a = (kw == 0 || kw == 32) ? 0.125f : 0.25f;
      const float ang = (float)(2.0 * M_PI / 64.0) * (float)((kw * w) & 63);
      float s_, c_;
      __sincosf(ang, &s_, &c_);
      Ac[e] = f2bf(a * c_);
      Asn[e] = f2bf(-a * s_);
    } else {
      Ac[e] = 0;
      Asn[e] = 0;
    }
  }
  __syncthreads();

  const int lane = t & 63;
  const int wv = t >> 6;
  const int cl = lane & 15;
  const int kg = lane >> 4;
  const int bh = blockIdx.x;  // b*64 + h
  const int b = bh >> 6;
  const int h = bh & 63;
  const int c = blockIdx.y * 64 + wv * 16 + cl;
  const size_t zbase = (((size_t)b * kNKW) * 64 + h) * 768 + c;  // + kw*64*768
  float* ocol = out + ((size_t)bh * 64) * 768 + c;

  // preload accumulator with bias-path values
  f32x4 aO[4];
#pragma unroll
  for (int mi = 0; mi < 4; ++mi) {
#pragma unroll
    for (int r = 0; r < 4; ++r) {
      const int w = mi * 16 + kg * 4 + r;
      aO[mi][r] = ocol[(size_t)w * 768];
    }
  }

#pragma unroll
  for (int kf = 0; kf < 2; ++kf) {
    short8 bzr = {0, 0, 0, 0, 0, 0, 0, 0};
    short8 bzi = {0, 0, 0, 0, 0, 0, 0, 0};
#pragma unroll
    for (int j = 0; j < 8; ++j) {
      const int kw = kf * 32 + kg * 8 + j;
      if (kw < 33) {
        bzr[j] = (short)f2bf(Zr[zbase + (size_t)kw * (64 * 768)]);
        bzi[j] = (short)f2bf(Zi[zbase + (size_t)kw * (64 * 768)]);
      }
    }
    const bf16x8 br = s2b(bzr);
    const bf16x8 bi = s2b(bzi);
#pragma unroll
    for (int mi = 0; mi < 4; ++mi) {
      const int arow = mi * 16 + cl;
      const bf16x8 acf =
          *reinterpret_cast<const bf16x8*>(Ac + arow * 64 + kf * 32 + kg * 8);
      const bf16x8 asf =
          *reinterpret_cast<const bf16x8*>(Asn + arow * 64 + kf * 32 + kg * 8);
      aO[mi] = __builtin_amdgcn_mfma_f32_16x16x32_bf16(acf, br, aO[mi], 0, 0, 0);
      aO[mi] = __builtin_amdgcn_mfma_f32_16x16x32_bf16(asf, bi, aO[mi], 0, 0, 0);
    }
  }

#pragma unroll
  for (int mi = 0; mi < 4; ++mi) {
#pragma unroll
    for (int r = 0; r < 4; ++r) {
      const int w = mi * 16 + kg * 4 + r;
      ocol[(size_t)w * 768] = aO[mi][r];
    }
  }
}

}  // namespace

extern "C" void kernel_launch(void* const* d_in, const int* in_sizes, int n_in,
                              void* d_out, int out_size, void* d_ws,
                              size_t ws_size, hipStream_t stream) {
  (void)in_sizes; (void)n_in; (void)out_size;
  const float* x  = (const float*)d_in[0];
  const float* w1 = (const float*)d_in[1];
  const float* b1 = (const float*)d_in[2];
  const float* w2 = (const float*)d_in[3];
  const float* b2 = (const float*)d_in[4];
  const float* Wb = (const float*)d_in[5];
  const float* bb = (const float*)d_in[6];
  float* out = (float*)d_out;

  if (ws_size < 2 * kXFElems * sizeof(float)) return;  // ws too small -> fail loudly
  float* XFr = (float*)d_ws;
  float* XFi = XFr + kXFElems;

  // bf16 scratch aliases XFr/XFi regions: GEMM finishes before rFFT writes them.
  unsigned short* xbf = (unsigned short*)XFr;   // 32768*768 bf16 = 48 MB (< 51.9 MB)
  unsigned short* wbf = (unsigned short*)XFi;   // 768*768 bf16

  // 0. convert x and Wb to bf16
  cvt_f32_bf16_kernel<<<dim3((32768 * 768 / 4 + 255) / 256), 256, 0, stream>>>(
      x, xbf, 32768 * 768 / 4);
  cvt_f32_bf16_kernel<<<dim3((768 * 768 / 4 + 255) / 256), 256, 0, stream>>>(
      Wb, wbf, 768 * 768 / 4);
  // 1. bias path GEMM on matrix cores (writes d_out fully)
  mfma_gemm_kernel<<<dim3(32768 / 128, 768 / 128), 256, 0, stream>>>(xbf, wbf, bb, out);
  // 2. forward row rFFT on matrix cores
  rfft_row_mfma_kernel<<<dim3(512, 12), 256, 0, stream>>>(x, XFr, XFi);
  // 3. forward column FFT on matrix cores (in place)
  fft_col_mfma_kernel<-1><<<dim3(264, 12), 256, 0, stream>>>(XFr, XFi);
  // 4. block-diagonal complex MLP on matrix cores (in place)
  mlp_mfma_kernel<<<dim3(132, 8), 512, 0, stream>>>(XFr, XFi, w1, b1, w2, b2);
  // 5. inverse column FFT on matrix cores (in place)
  fft_col_mfma_kernel<1><<<dim3(264, 12), 256, 0, stream>>>(XFr, XFi);
  // 6. inverse row rDFT + add bias path on matrix cores
  irfft_row_add_mfma_kernel<<<dim3(512, 12), 256, 0, stream>>>(XFr, XFi, out);
}

// Round 9
// 331.499 us; speedup vs baseline: 5.4500x; 1.0285x over previous
//
#include <hip/hip_runtime.h>
#include <math.h>

#ifndef M_PI
#define M_PI 3.14159265358979323846
#endif

namespace {

constexpr int kDim = 768;
constexpr int kNKW = 33;           // W/2+1
constexpr int kB = 8;
constexpr float kLambd = 0.01f;
constexpr size_t kXFElems = (size_t)kB * kNKW * 64 * kDim;  // 12,976,128

typedef __attribute__((ext_vector_type(8))) __bf16 bf16x8;
typedef __attribute__((ext_vector_type(8))) short short8;
typedef __attribute__((ext_vector_type(4))) float f32x4;

// Pre-transposed bf16 MLP weights: [mtx][nb][k_out][d], mtx: w1r,w1i,w2r,w2i
alignas(16) __device__ unsigned short g_wT[4 * 8 * 96 * 96];

// RNE float -> bf16 (inputs are normal floats; NaN not expected)
__device__ inline unsigned short f2bf(float f) {
  unsigned int u = __float_as_uint(f);
  unsigned int r = (u + 0x7FFFu + ((u >> 16) & 1u)) >> 16;
  return (unsigned short)r;
}

__device__ inline bf16x8 s2b(short8 s) { return __builtin_bit_cast(bf16x8, s); }
__device__ inline bf16x8 negb(short8 s) {
  s ^= (short)0x8000;
  return __builtin_bit_cast(bf16x8, s);
}

__device__ inline void gload_lds16(const void* g, void* l) {
  __builtin_amdgcn_global_load_lds(
      (const __attribute__((address_space(1))) unsigned int*)g,
      (__attribute__((address_space(3))) unsigned int*)l, 16, 0, 0);
}

// ---------------- 0a. fp32 -> bf16 conversion ------------------------------
__global__ __launch_bounds__(256) void cvt_f32_bf16_kernel(
    const float* __restrict__ in, unsigned short* __restrict__ out, int n4) {
  int i = blockIdx.x * 256 + threadIdx.x;
  if (i >= n4) return;
  const float4 v = reinterpret_cast<const float4*>(in)[i];
  ushort4 o;
  o.x = f2bf(v.x); o.y = f2bf(v.y); o.z = f2bf(v.z); o.w = f2bf(v.w);
  reinterpret_cast<ushort4*>(out)[i] = o;
}

// ---------------- 0b. MLP weight transpose+convert (once per launch) -------
// g_wT[mtx][nb][k][d] = src[mtx][nb][d][k]
__global__ __launch_bounds__(256) void cvt_w_kernel(
    const float* __restrict__ w1, const float* __restrict__ w2) {
  const int e = blockIdx.x * 256 + threadIdx.x;
  if (e >= 4 * 8 * 96 * 96) return;
  const int k = e % 96;
  const int d = (e / 96) % 96;
  const int nbm = e / 9216;  // mtx*8+nb
  const int mtx = nbm >> 3;
  const int nb = nbm & 7;
  const float* src =
      (mtx < 2 ? w1 : w2) + ((size_t)(mtx & 1) * 8 + nb) * 9216;
  g_wT[((size_t)nbm * 96 + k) * 96 + d] = f2bf(src[d * 96 + k]);
}

// ---------------- 1. bias GEMM via MFMA ------------------------------------
// out[m,n] = sum_k xbf[m,k] * wbf[n,k] + bb[n]; M=32768, N=768, K=768.
__global__ __launch_bounds__(256) void mfma_gemm_kernel(
    const unsigned short* __restrict__ xbf, const unsigned short* __restrict__ wbf,
    const float* __restrict__ bb, float* __restrict__ out) {
  __shared__ unsigned short As[128 * 32];  // [row][k] 8KB
  __shared__ unsigned short Bs[128 * 32];  // [n][k]   8KB
  const int t = threadIdx.x;
  const int lane = t & 63;
  const int wid = t >> 6;
  const int wm = wid >> 1;
  const int wn = wid & 1;
  const int m0 = blockIdx.x * 128;
  const int n0 = blockIdx.y * 128;

  f32x4 acc[4][4];
#pragma unroll
  for (int i = 0; i < 4; ++i)
#pragma unroll
    for (int j = 0; j < 4; ++j) acc[i][j] = (f32x4){0.f, 0.f, 0.f, 0.f};

  char* AsB = (char*)As;
  char* BsB = (char*)Bs;
  const int cl = lane & 15;
  const int kg = lane >> 4;  // 0..3

  for (int k0 = 0; k0 < 768; k0 += 32) {
#pragma unroll
    for (int i = 0; i < 2; ++i) {
      const int off = (wid * 2 + i) * 1024 + lane * 16;  // byte off in tile
      const int row = off >> 6;
      const int kb = off & 63;
      const char* gA = (const char*)xbf + ((size_t)(m0 + row) * 768 + k0) * 2 + kb;
      gload_lds16(gA, AsB + (wid * 2 + i) * 1024);
      const char* gB = (const char*)wbf + ((size_t)(n0 + row) * 768 + k0) * 2 + kb;
      gload_lds16(gB, BsB + (wid * 2 + i) * 1024);
    }
    asm volatile("s_waitcnt vmcnt(0)" ::: "memory");
    __syncthreads();

    bf16x8 av[4], bv[4];
#pragma unroll
    for (int mi = 0; mi < 4; ++mi) {
      const int r = wm * 64 + mi * 16 + cl;
      av[mi] = *reinterpret_cast<const bf16x8*>(AsB + r * 64 + kg * 16);
    }
#pragma unroll
    for (int ni = 0; ni < 4; ++ni) {
      const int r = wn * 64 + ni * 16 + cl;
      bv[ni] = *reinterpret_cast<const bf16x8*>(BsB + r * 64 + kg * 16);
    }
#pragma unroll
    for (int mi = 0; mi < 4; ++mi)
#pragma unroll
      for (int ni = 0; ni < 4; ++ni)
        acc[mi][ni] = __builtin_amdgcn_mfma_f32_16x16x32_bf16(
            av[mi], bv[ni], acc[mi][ni], 0, 0, 0);
    __syncthreads();
  }

#pragma unroll
  for (int ni = 0; ni < 4; ++ni) {
    const int n = n0 + wn * 64 + ni * 16 + cl;
    const float bias = bb[n];
#pragma unroll
    for (int mi = 0; mi < 4; ++mi) {
      const int m = m0 + wm * 64 + mi * 16 + kg * 4;
#pragma unroll
      for (int r = 0; r < 4; ++r) {
        out[(size_t)(m + r) * 768 + n] = acc[mi][ni][r] + bias;
      }
    }
  }
}

// ---------------- 2. forward row rFFT via MFMA ------------------------------
__global__ __launch_bounds__(256) void rfft_row_mfma_kernel(
    const float* __restrict__ x, float* __restrict__ XFr,
    float* __restrict__ XFi) {
  __shared__ alignas(16) unsigned short Cs[48 * 64];  //  0.125*cos [kh][w] 6KB
  __shared__ alignas(16) unsigned short Ss[48 * 64];  // -0.125*sin        6KB
  const int t = threadIdx.x;
  for (int e = t; e < 48 * 64; e += 256) {
    const int kh = e >> 6;
    const int w = e & 63;
    const float ang = (float)(2.0 * M_PI / 64.0) * (float)((kh * w) & 63);
    float s_, c_;
    __sincosf(ang, &s_, &c_);
    Cs[e] = f2bf(0.125f * c_);
    Ss[e] = f2bf(-0.125f * s_);
  }
  __syncthreads();

  const int lane = t & 63;
  const int wv = t >> 6;       // wave -> c-strip
  const int cl = lane & 15;
  const int kg = lane >> 4;    // 0..3
  const int bh = blockIdx.x;   // b*64 + h
  const int b = bh >> 6;
  const int h = bh & 63;
  const int c = blockIdx.y * 64 + wv * 16 + cl;
  const float* xcol = x + ((size_t)bh * 64) * 768 + c;

  f32x4 aR[3], aI[3];
#pragma unroll
  for (int mi = 0; mi < 3; ++mi) {
    aR[mi] = (f32x4){0.f, 0.f, 0.f, 0.f};
    aI[mi] = (f32x4){0.f, 0.f, 0.f, 0.f};
  }

#pragma unroll
  for (int kf = 0; kf < 2; ++kf) {
    const int w0 = kf * 32 + kg * 8;
    float xv[8];
#pragma unroll
    for (int j = 0; j < 8; ++j) xv[j] = xcol[(size_t)(w0 + j) * 768];
    short8 bs;
#pragma unroll
    for (int j = 0; j < 8; ++j) bs[j] = (short)f2bf(xv[j]);
    const bf16x8 bx = s2b(bs);
#pragma unroll
    for (int mi = 0; mi < 3; ++mi) {
      const int arow = mi * 16 + cl;
      const bf16x8 ac =
          *reinterpret_cast<const bf16x8*>(Cs + arow * 64 + kf * 32 + kg * 8);
      const bf16x8 as =
          *reinterpret_cast<const bf16x8*>(Ss + arow * 64 + kf * 32 + kg * 8);
      aR[mi] = __builtin_amdgcn_mfma_f32_16x16x32_bf16(ac, bx, aR[mi], 0, 0, 0);
      aI[mi] = __builtin_amdgcn_mfma_f32_16x16x32_bf16(as, bx, aI[mi], 0, 0, 0);
    }
  }

#pragma unroll
  for (int mi = 0; mi < 3; ++mi) {
#pragma unroll
    for (int r = 0; r < 4; ++r) {
      const int kh = mi * 16 + kg * 4 + r;
      if (kh <= 32) {
        const size_t off = (((size_t)b * kNKW + kh) * 64 + h) * 768 + c;
        XFr[off] = aR[mi][r];
        XFi[off] = aI[mi][r];
      }
    }
  }
}

// ---------------- 3/5. column FFT along h via MFMA (in place) --------------
template <int SIGN>
__global__ __launch_bounds__(256) void fft_col_mfma_kernel(
    float* __restrict__ Xr, float* __restrict__ Xi) {
  __shared__ alignas(16) unsigned short Cs[64 * 64];  // 0.125*cos  [kh][h] 8KB
  __shared__ alignas(16) unsigned short Ss[64 * 64];  // 0.125*SIGN*sin      8KB
  const int t = threadIdx.x;
  for (int e = t; e < 4096; e += 256) {
    const int kh = e >> 6;
    const int h = e & 63;
    const float ang = (float)(2.0 * M_PI / 64.0) * (float)((kh * h) & 63);
    float s_, c_;
    __sincosf(ang, &s_, &c_);
    Cs[e] = f2bf(0.125f * c_);
    Ss[e] = f2bf(0.125f * (float)SIGN * s_);
  }
  __syncthreads();

  const int lane = t & 63;
  const int wv = t >> 6;       // wave id 0..3 -> c-strip
  const int cl = lane & 15;
  const int kg = lane >> 4;    // 0..3
  const size_t cbase =
      (size_t)blockIdx.x * (64 * 768) + blockIdx.y * 64 + wv * 16 + cl;

  f32x4 aR[4], aI[4];
#pragma unroll
  for (int mi = 0; mi < 4; ++mi) {
    aR[mi] = (f32x4){0.f, 0.f, 0.f, 0.f};
    aI[mi] = (f32x4){0.f, 0.f, 0.f, 0.f};
  }

#pragma unroll
  for (int kf = 0; kf < 2; ++kf) {
    const int h0 = kf * 32 + kg * 8;
    float xr[8], xi[8];
#pragma unroll
    for (int j = 0; j < 8; ++j) {
      xr[j] = Xr[cbase + (size_t)(h0 + j) * 768];
      xi[j] = Xi[cbase + (size_t)(h0 + j) * 768];
    }
    short8 brf, bif;
#pragma unroll
    for (int j = 0; j < 8; ++j) {
      brf[j] = (short)f2bf(xr[j]);
      bif[j] = (short)f2bf(xi[j]);
    }
    const bf16x8 bxr = s2b(brf);
    const bf16x8 bxi = s2b(bif);
    const bf16x8 bxin = negb(bif);
#pragma unroll
    for (int mi = 0; mi < 4; ++mi) {
      const int arow = mi * 16 + cl;
      const bf16x8 ac =
          *reinterpret_cast<const bf16x8*>(Cs + arow * 64 + kf * 32 + kg * 8);
      const bf16x8 as =
          *reinterpret_cast<const bf16x8*>(Ss + arow * 64 + kf * 32 + kg * 8);
      aR[mi] = __builtin_amdgcn_mfma_f32_16x16x32_bf16(ac, bxr, aR[mi], 0, 0, 0);
      aR[mi] = __builtin_amdgcn_mfma_f32_16x16x32_bf16(as, bxin, aR[mi], 0, 0, 0);
      aI[mi] = __builtin_amdgcn_mfma_f32_16x16x32_bf16(ac, bxi, aI[mi], 0, 0, 0);
      aI[mi] = __builtin_amdgcn_mfma_f32_16x16x32_bf16(as, bxr, aI[mi], 0, 0, 0);
    }
  }

#pragma unroll
  for (int mi = 0; mi < 4; ++mi) {
#pragma unroll
    for (int r = 0; r < 4; ++r) {
      const int kh = mi * 16 + kg * 4 + r;
      Xr[cbase + (size_t)kh * 768] = aR[mi][r];
      Xi[cbase + (size_t)kh * 768] = aI[mi][r];
    }
  }
}

// ---------------- 4. block-diagonal complex MLP via MFMA (in place) --------
// Weights read as B-fragments directly from pre-transposed g_wT (L2-resident).
// LDS only stages X (53 KB) -> 3 blocks/CU.
__global__ __launch_bounds__(512) void mlp_mfma_kernel(
    float* __restrict__ Xr, float* __restrict__ Xi,
    const float* __restrict__ b1, const float* __restrict__ b2) {
  __shared__ unsigned short sXr[128 * 104];      // 26.6 KB (reused for R1)
  __shared__ unsigned short sXi[128 * 104];      // 26.6 KB (reused for I1)
  const int t = threadIdx.x;
  const int lane = t & 63;
  const int wid = t >> 6;   // 0..7
  const int wm = wid >> 1;  // 0..3: rows wm*32
  const int wn = wid & 1;   // 0..1: cols wn*48
  const int cl = lane & 15;
  const int kg = lane >> 4;
  const int nb = blockIdx.y;
  const size_t p0 = (size_t)blockIdx.x * 128;

  // ---- stage X tile: fp32 global -> bf16 LDS ----
  {
    const int row = t >> 2;
    const int q = t & 3;  // 24-float chunk
    const size_t gbase = (p0 + row) * 768 + nb * 96 + q * 24;
    unsigned short* lr = sXr + row * 104 + q * 24;
    unsigned short* li = sXi + row * 104 + q * 24;
    const float4* gr = reinterpret_cast<const float4*>(Xr + gbase);
    const float4* gi = reinterpret_cast<const float4*>(Xi + gbase);
#pragma unroll
    for (int v = 0; v < 3; ++v) {
      float4 a = gr[v * 2], b = gr[v * 2 + 1];
      short8 s;
      s[0] = (short)f2bf(a.x); s[1] = (short)f2bf(a.y);
      s[2] = (short)f2bf(a.z); s[3] = (short)f2bf(a.w);
      s[4] = (short)f2bf(b.x); s[5] = (short)f2bf(b.y);
      s[6] = (short)f2bf(b.z); s[7] = (short)f2bf(b.w);
      *reinterpret_cast<short8*>(lr + v * 8) = s;
      a = gi[v * 2]; b = gi[v * 2 + 1];
      s[0] = (short)f2bf(a.x); s[1] = (short)f2bf(a.y);
      s[2] = (short)f2bf(a.z); s[3] = (short)f2bf(a.w);
      s[4] = (short)f2bf(b.x); s[5] = (short)f2bf(b.y);
      s[6] = (short)f2bf(b.z); s[7] = (short)f2bf(b.w);
      *reinterpret_cast<short8*>(li + v * 8) = s;
    }
  }
  __syncthreads();

  const unsigned short* wt1r = g_wT + (size_t)(0 * 8 + nb) * 9216;
  const unsigned short* wt1i = g_wT + (size_t)(1 * 8 + nb) * 9216;
  const unsigned short* wt2r = g_wT + (size_t)(2 * 8 + nb) * 9216;
  const unsigned short* wt2i = g_wT + (size_t)(3 * 8 + nb) * 9216;

  f32x4 aR[2][3], aI[2][3];
#pragma unroll
  for (int mf = 0; mf < 2; ++mf)
#pragma unroll
    for (int nf = 0; nf < 3; ++nf) {
      aR[mf][nf] = (f32x4){0.f, 0.f, 0.f, 0.f};
      aI[mf][nf] = (f32x4){0.f, 0.f, 0.f, 0.f};
    }

  // ---- layer 1 ----
#pragma unroll
  for (int kk = 0; kk < 3; ++kk) {
    const int ko = kk * 32 + kg * 8;
    short8 xr_[2], xi_[2];
#pragma unroll
    for (int mf = 0; mf < 2; ++mf) {
      const int r = wm * 32 + mf * 16 + cl;
      xr_[mf] = *reinterpret_cast<const short8*>(sXr + r * 104 + ko);
      xi_[mf] = *reinterpret_cast<const short8*>(sXi + r * 104 + ko);
    }
    short8 wr_[3], wi_[3];
#pragma unroll
    for (int nf = 0; nf < 3; ++nf) {
      const int r = wn * 48 + nf * 16 + cl;
      wr_[nf] = *reinterpret_cast<const short8*>(wt1r + r * 96 + ko);
      wi_[nf] = *reinterpret_cast<const short8*>(wt1i + r * 96 + ko);
    }
#pragma unroll
    for (int mf = 0; mf < 2; ++mf) {
      const bf16x8 axr = s2b(xr_[mf]);
      const bf16x8 axi = s2b(xi_[mf]);
      const bf16x8 axin = negb(xi_[mf]);
#pragma unroll
      for (int nf = 0; nf < 3; ++nf) {
        aR[mf][nf] = __builtin_amdgcn_mfma_f32_16x16x32_bf16(axr, s2b(wr_[nf]), aR[mf][nf], 0, 0, 0);
        aR[mf][nf] = __builtin_amdgcn_mfma_f32_16x16x32_bf16(axin, s2b(wi_[nf]), aR[mf][nf], 0, 0, 0);
        aI[mf][nf] = __builtin_amdgcn_mfma_f32_16x16x32_bf16(axr, s2b(wi_[nf]), aI[mf][nf], 0, 0, 0);
        aI[mf][nf] = __builtin_amdgcn_mfma_f32_16x16x32_bf16(axi, s2b(wr_[nf]), aI[mf][nf], 0, 0, 0);
      }
    }
  }
  __syncthreads();  // all layer-1 LDS reads complete before overwrite

  // epilogue L1: bias + relu -> bf16 back into sXr/sXi
#pragma unroll
  for (int nf = 0; nf < 3; ++nf) {
    const int col = wn * 48 + nf * 16 + cl;
    const float br = b1[nb * 96 + col];
    const float bi = b1[768 + nb * 96 + col];
#pragma unroll
    for (int mf = 0; mf < 2; ++mf) {
#pragma unroll
      for (int r = 0; r < 4; ++r) {
        const int m = wm * 32 + mf * 16 + kg * 4 + r;
        const float vr = fmaxf(aR[mf][nf][r] + br, 0.f);
        const float vi = fmaxf(aI[mf][nf][r] + bi, 0.f);
        sXr[m * 104 + col] = f2bf(vr);
        sXi[m * 104 + col] = f2bf(vi);
      }
    }
  }
  __syncthreads();

  // ---- layer 2 ----
#pragma unroll
  for (int mf = 0; mf < 2; ++mf)
#pragma unroll
    for (int nf = 0; nf < 3; ++nf) {
      aR[mf][nf] = (f32x4){0.f, 0.f, 0.f, 0.f};
      aI[mf][nf] = (f32x4){0.f, 0.f, 0.f, 0.f};
    }
#pragma unroll
  for (int kk = 0; kk < 3; ++kk) {
    const int ko = kk * 32 + kg * 8;
    short8 xr_[2], xi_[2];
#pragma unroll
    for (int mf = 0; mf < 2; ++mf) {
      const int r = wm * 32 + mf * 16 + cl;
      xr_[mf] = *reinterpret_cast<const short8*>(sXr + r * 104 + ko);
      xi_[mf] = *reinterpret_cast<const short8*>(sXi + r * 104 + ko);
    }
    short8 wr_[3], wi_[3];
#pragma unroll
    for (int nf = 0; nf < 3; ++nf) {
      const int r = wn * 48 + nf * 16 + cl;
      wr_[nf] = *reinterpret_cast<const short8*>(wt2r + r * 96 + ko);
      wi_[nf] = *reinterpret_cast<const short8*>(wt2i + r * 96 + ko);
    }
#pragma unroll
    for (int mf = 0; mf < 2; ++mf) {
      const bf16x8 axr = s2b(xr_[mf]);
      const bf16x8 axi = s2b(xi_[mf]);
      const bf16x8 axin = negb(xi_[mf]);
#pragma unroll
      for (int nf = 0; nf < 3; ++nf) {
        aR[mf][nf] = __builtin_amdgcn_mfma_f32_16x16x32_bf16(axr, s2b(wr_[nf]), aR[mf][nf], 0, 0, 0);
        aR[mf][nf] = __builtin_amdgcn_mfma_f32_16x16x32_bf16(axin, s2b(wi_[nf]), aR[mf][nf], 0, 0, 0);
        aI[mf][nf] = __builtin_amdgcn_mfma_f32_16x16x32_bf16(axr, s2b(wi_[nf]), aI[mf][nf], 0, 0, 0);
        aI[mf][nf] = __builtin_amdgcn_mfma_f32_16x16x32_bf16(axi, s2b(wr_[nf]), aI[mf][nf], 0, 0, 0);
      }
    }
  }

  // epilogue L2: bias + softshrink -> fp32 global (in place)
#pragma unroll
  for (int nf = 0; nf < 3; ++nf) {
    const int col = wn * 48 + nf * 16 + cl;
    const float br = b2[nb * 96 + col];
    const float bi = b2[768 + nb * 96 + col];
    const int gc = nb * 96 + col;
#pragma unroll
    for (int mf = 0; mf < 2; ++mf) {
#pragma unroll
      for (int r = 0; r < 4; ++r) {
        const int m = wm * 32 + mf * 16 + kg * 4 + r;
        float vr = aR[mf][nf][r] + br;
        float vi = aI[mf][nf][r] + bi;
        vr = (vr > kLambd) ? (vr - kLambd) : ((vr < -kLambd) ? (vr + kLambd) : 0.f);
        vi = (vi > kLambd) ? (vi - kLambd) : ((vi < -kLambd) ? (vi + kLambd) : 0.f);
        Xr[(p0 + m) * 768 + gc] = vr;
        Xi[(p0 + m) * 768 + gc] = vi;
      }
    }
  }
}

// ---------------- 6. inverse row rDFT + accumulate via MFMA ----------------
__global__ __launch_bounds__(256) void irfft_row_add_mfma_kernel(
    const float* __restrict__ Zr, const float* __restrict__ Zi,
    float* __restrict__ out) {
  __shared__ alignas(16) unsigned short Ac[64 * 64];   // [w][kw] 8KB
  __shared__ alignas(16) unsigned short Asn[64 * 64];  // [w][kw] 8KB
  const int t = threadIdx.x;
  for (int e = t; e < 4096; e += 256) {
    const int w = e >> 6;
    const int kw = e & 63;
    if (kw < 33) {
      const float a = (kw == 0 || kw == 32) ? 0.125f : 0.25f;
      const float ang = (float)(2.0 * M_PI / 64.0) * (float)((kw * w) & 63);
      float s_, c_;
      __sincosf(ang, &s_, &c_);
      Ac[e] = f2bf(a * c_);
      Asn[e] = f2bf(-a * s_);
    } else {
      Ac[e] = 0;
      Asn[e] = 0;
    }
  }
  __syncthreads();

  const int lane = t & 63;
  const int wv = t >> 6;
  const int cl = lane & 15;
  const int kg = lane >> 4;
  const int bh = blockIdx.x;  // b*64 + h
  const int b = bh >> 6;
  const int h = bh & 63;
  const int c = blockIdx.y * 64 + wv * 16 + cl;
  const size_t zbase = (((size_t)b * kNKW) * 64 + h) * 768 + c;  // + kw*64*768
  float* ocol = out + ((size_t)bh * 64) * 768 + c;

  // preload accumulator with bias-path values
  f32x4 aO[4];
#pragma unroll
  for (int mi = 0; mi < 4; ++mi) {
#pragma unroll
    for (int r = 0; r < 4; ++r) {
      const int w = mi * 16 + kg * 4 + r;
      aO[mi][r] = ocol[(size_t)w * 768];
    }
  }

#pragma unroll
  for (int kf = 0; kf < 2; ++kf) {
    short8 bzr = {0, 0, 0, 0, 0, 0, 0, 0};
    short8 bzi = {0, 0, 0, 0, 0, 0, 0, 0};
#pragma unroll
    for (int j = 0; j < 8; ++j) {
      const int kw = kf * 32 + kg * 8 + j;
      if (kw < 33) {
        bzr[j] = (short)f2bf(Zr[zbase + (size_t)kw * (64 * 768)]);
        bzi[j] = (short)f2bf(Zi[zbase + (size_t)kw * (64 * 768)]);
      }
    }
    const bf16x8 br = s2b(bzr);
    const bf16x8 bi = s2b(bzi);
#pragma unroll
    for (int mi = 0; mi < 4; ++mi) {
      const int arow = mi * 16 + cl;
      const bf16x8 acf =
          *reinterpret_cast<const bf16x8*>(Ac + arow * 64 + kf * 32 + kg * 8);
      const bf16x8 asf =
          *reinterpret_cast<const bf16x8*>(Asn + arow * 64 + kf * 32 + kg * 8);
      aO[mi] = __builtin_amdgcn_mfma_f32_16x16x32_bf16(acf, br, aO[mi], 0, 0, 0);
      aO[mi] = __builtin_amdgcn_mfma_f32_16x16x32_bf16(asf, bi, aO[mi], 0, 0, 0);
    }
  }

#pragma unroll
  for (int mi = 0; mi < 4; ++mi) {
#pragma unroll
    for (int r = 0; r < 4; ++r) {
      const int w = mi * 16 + kg * 4 + r;
      ocol[(size_t)w * 768] = aO[mi][r];
    }
  }
}

}  // namespace

extern "C" void kernel_launch(void* const* d_in, const int* in_sizes, int n_in,
                              void* d_out, int out_size, void* d_ws,
                              size_t ws_size, hipStream_t stream) {
  (void)in_sizes; (void)n_in; (void)out_size;
  const float* x  = (const float*)d_in[0];
  const float* w1 = (const float*)d_in[1];
  const float* b1 = (const float*)d_in[2];
  const float* w2 = (const float*)d_in[3];
  const float* b2 = (const float*)d_in[4];
  const float* Wb = (const float*)d_in[5];
  const float* bb = (const float*)d_in[6];
  float* out = (float*)d_out;

  if (ws_size < 2 * kXFElems * sizeof(float)) return;  // ws too small -> fail loudly
  float* XFr = (float*)d_ws;
  float* XFi = XFr + kXFElems;

  // bf16 scratch aliases XFr/XFi regions: GEMM finishes before rFFT writes them.
  unsigned short* xbf = (unsigned short*)XFr;   // 32768*768 bf16 = 48 MB (< 51.9 MB)
  unsigned short* wbf = (unsigned short*)XFi;   // 768*768 bf16

  // 0. conversions: x, Wb to bf16; MLP weights transposed to g_wT
  cvt_f32_bf16_kernel<<<dim3((32768 * 768 / 4 + 255) / 256), 256, 0, stream>>>(
      x, xbf, 32768 * 768 / 4);
  cvt_f32_bf16_kernel<<<dim3((768 * 768 / 4 + 255) / 256), 256, 0, stream>>>(
      Wb, wbf, 768 * 768 / 4);
  cvt_w_kernel<<<dim3(4 * 8 * 96 * 96 / 256), 256, 0, stream>>>(w1, w2);
  // 1. bias path GEMM on matrix cores (writes d_out fully)
  mfma_gemm_kernel<<<dim3(32768 / 128, 768 / 128), 256, 0, stream>>>(xbf, wbf, bb, out);
  // 2. forward row rFFT on matrix cores
  rfft_row_mfma_kernel<<<dim3(512, 12), 256, 0, stream>>>(x, XFr, XFi);
  // 3. forward column FFT on matrix cores (in place)
  fft_col_mfma_kernel<-1><<<dim3(264, 12), 256, 0, stream>>>(XFr, XFi);
  // 4. block-diagonal complex MLP on matrix cores (in place)
  mlp_mfma_kernel<<<dim3(132, 8), 512, 0, stream>>>(XFr, XFi, b1, b2);
  // 5. inverse column FFT on matrix cores (in place)
  fft_col_mfma_kernel<1><<<dim3(264, 12), 256, 0, stream>>>(XFr, XFi);
  // 6. inverse row rDFT + add bias path on matrix cores
  irfft_row_add_mfma_kernel<<<dim3(512, 12), 256, 0, stream>>>(XFr, XFi, out);
}

// Round 10
// 275.821 us; speedup vs baseline: 6.5501x; 1.2019x over previous
//
#include <hip/hip_runtime.h>
#include <math.h>

#ifndef M_PI
#define M_PI 3.14159265358979323846
#endif

namespace {

constexpr int kDim = 768;
constexpr int kNKW = 33;           // W/2+1
constexpr int kB = 8;
constexpr float kLambd = 0.01f;
constexpr size_t kXFElems = (size_t)kB * kNKW * 64 * kDim;  // 12,976,128

typedef __attribute__((ext_vector_type(8))) __bf16 bf16x8;
typedef __attribute__((ext_vector_type(8))) short short8;
typedef __attribute__((ext_vector_type(4))) float f32x4;

// Pre-transposed bf16 MLP weights: [mtx][nb][k_out][d], mtx: w1r,w1i,w2r,w2i
alignas(16) __device__ unsigned short g_wT[4 * 8 * 96 * 96];

// RNE float -> bf16 (inputs are normal floats; NaN not expected)
__device__ inline unsigned short f2bf(float f) {
  unsigned int u = __float_as_uint(f);
  unsigned int r = (u + 0x7FFFu + ((u >> 16) & 1u)) >> 16;
  return (unsigned short)r;
}

__device__ inline bf16x8 s2b(short8 s) { return __builtin_bit_cast(bf16x8, s); }
__device__ inline bf16x8 negb(short8 s) {
  s ^= (short)0x8000;
  return __builtin_bit_cast(bf16x8, s);
}

__device__ inline void gload_lds16(const void* g, void* l) {
  __builtin_amdgcn_global_load_lds(
      (const __attribute__((address_space(1))) unsigned int*)g,
      (__attribute__((address_space(3))) unsigned int*)l, 16, 0, 0);
}

// ---------------- 0a. fp32 -> bf16 conversion ------------------------------
__global__ __launch_bounds__(256) void cvt_f32_bf16_kernel(
    const float* __restrict__ in, unsigned short* __restrict__ out, int n4) {
  int i = blockIdx.x * 256 + threadIdx.x;
  if (i >= n4) return;
  const float4 v = reinterpret_cast<const float4*>(in)[i];
  ushort4 o;
  o.x = f2bf(v.x); o.y = f2bf(v.y); o.z = f2bf(v.z); o.w = f2bf(v.w);
  reinterpret_cast<ushort4*>(out)[i] = o;
}

// ---------------- 0b. MLP weight transpose+convert (once per launch) -------
// g_wT[mtx][nb][k][d] = src[mtx][nb][d][k]
__global__ __launch_bounds__(256) void cvt_w_kernel(
    const float* __restrict__ w1, const float* __restrict__ w2) {
  const int e = blockIdx.x * 256 + threadIdx.x;
  if (e >= 4 * 8 * 96 * 96) return;
  const int k = e % 96;
  const int d = (e / 96) % 96;
  const int nbm = e / 9216;  // mtx*8+nb
  const int mtx = nbm >> 3;
  const int nb = nbm & 7;
  const float* src =
      (mtx < 2 ? w1 : w2) + ((size_t)(mtx & 1) * 8 + nb) * 9216;
  g_wT[((size_t)nbm * 96 + k) * 96 + d] = f2bf(src[d * 96 + k]);
}

// ---------------- 1. bias GEMM via MFMA ------------------------------------
// out[m,n] = sum_k xbf[m,k] * wbf[n,k] + bb[n]; M=32768, N=768, K=768.
__global__ __launch_bounds__(256) void mfma_gemm_kernel(
    const unsigned short* __restrict__ xbf, const unsigned short* __restrict__ wbf,
    const float* __restrict__ bb, float* __restrict__ out) {
  __shared__ unsigned short As[128 * 32];  // [row][k] 8KB
  __shared__ unsigned short Bs[128 * 32];  // [n][k]   8KB
  const int t = threadIdx.x;
  const int lane = t & 63;
  const int wid = t >> 6;
  const int wm = wid >> 1;
  const int wn = wid & 1;
  const int m0 = blockIdx.x * 128;
  const int n0 = blockIdx.y * 128;

  f32x4 acc[4][4];
#pragma unroll
  for (int i = 0; i < 4; ++i)
#pragma unroll
    for (int j = 0; j < 4; ++j) acc[i][j] = (f32x4){0.f, 0.f, 0.f, 0.f};

  char* AsB = (char*)As;
  char* BsB = (char*)Bs;
  const int cl = lane & 15;
  const int kg = lane >> 4;  // 0..3

  for (int k0 = 0; k0 < 768; k0 += 32) {
#pragma unroll
    for (int i = 0; i < 2; ++i) {
      const int off = (wid * 2 + i) * 1024 + lane * 16;  // byte off in tile
      const int row = off >> 6;
      const int kb = off & 63;
      const char* gA = (const char*)xbf + ((size_t)(m0 + row) * 768 + k0) * 2 + kb;
      gload_lds16(gA, AsB + (wid * 2 + i) * 1024);
      const char* gB = (const char*)wbf + ((size_t)(n0 + row) * 768 + k0) * 2 + kb;
      gload_lds16(gB, BsB + (wid * 2 + i) * 1024);
    }
    asm volatile("s_waitcnt vmcnt(0)" ::: "memory");
    __syncthreads();

    bf16x8 av[4], bv[4];
#pragma unroll
    for (int mi = 0; mi < 4; ++mi) {
      const int r = wm * 64 + mi * 16 + cl;
      av[mi] = *reinterpret_cast<const bf16x8*>(AsB + r * 64 + kg * 16);
    }
#pragma unroll
    for (int ni = 0; ni < 4; ++ni) {
      const int r = wn * 64 + ni * 16 + cl;
      bv[ni] = *reinterpret_cast<const bf16x8*>(BsB + r * 64 + kg * 16);
    }
#pragma unroll
    for (int mi = 0; mi < 4; ++mi)
#pragma unroll
      for (int ni = 0; ni < 4; ++ni)
        acc[mi][ni] = __builtin_amdgcn_mfma_f32_16x16x32_bf16(
            av[mi], bv[ni], acc[mi][ni], 0, 0, 0);
    __syncthreads();
  }

#pragma unroll
  for (int ni = 0; ni < 4; ++ni) {
    const int n = n0 + wn * 64 + ni * 16 + cl;
    const float bias = bb[n];
#pragma unroll
    for (int mi = 0; mi < 4; ++mi) {
      const int m = m0 + wm * 64 + mi * 16 + kg * 4;
#pragma unroll
      for (int r = 0; r < 4; ++r) {
        out[(size_t)(m + r) * 768 + n] = acc[mi][ni][r] + bias;
      }
    }
  }
}

// ---------------- 2. forward row rFFT via MFMA ------------------------------
// XF bf16 layout: [b][kw][h][c]
__global__ __launch_bounds__(256) void rfft_row_mfma_kernel(
    const float* __restrict__ x, unsigned short* __restrict__ XFr,
    unsigned short* __restrict__ XFi) {
  __shared__ alignas(16) unsigned short Cs[48 * 64];  //  0.125*cos [kh][w] 6KB
  __shared__ alignas(16) unsigned short Ss[48 * 64];  // -0.125*sin        6KB
  const int t = threadIdx.x;
  for (int e = t; e < 48 * 64; e += 256) {
    const int kh = e >> 6;
    const int w = e & 63;
    const float ang = (float)(2.0 * M_PI / 64.0) * (float)((kh * w) & 63);
    float s_, c_;
    __sincosf(ang, &s_, &c_);
    Cs[e] = f2bf(0.125f * c_);
    Ss[e] = f2bf(-0.125f * s_);
  }
  __syncthreads();

  const int lane = t & 63;
  const int wv = t >> 6;       // wave -> c-strip
  const int cl = lane & 15;
  const int kg = lane >> 4;    // 0..3
  const int bh = blockIdx.x;   // b*64 + h
  const int b = bh >> 6;
  const int h = bh & 63;
  const int c = blockIdx.y * 64 + wv * 16 + cl;
  const float* xcol = x + ((size_t)bh * 64) * 768 + c;

  f32x4 aR[3], aI[3];
#pragma unroll
  for (int mi = 0; mi < 3; ++mi) {
    aR[mi] = (f32x4){0.f, 0.f, 0.f, 0.f};
    aI[mi] = (f32x4){0.f, 0.f, 0.f, 0.f};
  }

#pragma unroll
  for (int kf = 0; kf < 2; ++kf) {
    const int w0 = kf * 32 + kg * 8;
    float xv[8];
#pragma unroll
    for (int j = 0; j < 8; ++j) xv[j] = xcol[(size_t)(w0 + j) * 768];
    short8 bs;
#pragma unroll
    for (int j = 0; j < 8; ++j) bs[j] = (short)f2bf(xv[j]);
    const bf16x8 bx = s2b(bs);
#pragma unroll
    for (int mi = 0; mi < 3; ++mi) {
      const int arow = mi * 16 + cl;
      const bf16x8 ac =
          *reinterpret_cast<const bf16x8*>(Cs + arow * 64 + kf * 32 + kg * 8);
      const bf16x8 as =
          *reinterpret_cast<const bf16x8*>(Ss + arow * 64 + kf * 32 + kg * 8);
      aR[mi] = __builtin_amdgcn_mfma_f32_16x16x32_bf16(ac, bx, aR[mi], 0, 0, 0);
      aI[mi] = __builtin_amdgcn_mfma_f32_16x16x32_bf16(as, bx, aI[mi], 0, 0, 0);
    }
  }

#pragma unroll
  for (int mi = 0; mi < 3; ++mi) {
#pragma unroll
    for (int r = 0; r < 4; ++r) {
      const int kh = mi * 16 + kg * 4 + r;
      if (kh <= 32) {
        const size_t off = (((size_t)b * kNKW + kh) * 64 + h) * 768 + c;
        XFr[off] = f2bf(aR[mi][r]);
        XFi[off] = f2bf(aI[mi][r]);
      }
    }
  }
}

// ---------------- 3/5. column FFT along h via MFMA (in place, bf16) --------
template <int SIGN>
__global__ __launch_bounds__(256) void fft_col_mfma_kernel(
    unsigned short* __restrict__ Xr, unsigned short* __restrict__ Xi) {
  __shared__ alignas(16) unsigned short Cs[64 * 64];  // 0.125*cos  [kh][h] 8KB
  __shared__ alignas(16) unsigned short Ss[64 * 64];  // 0.125*SIGN*sin      8KB
  const int t = threadIdx.x;
  for (int e = t; e < 4096; e += 256) {
    const int kh = e >> 6;
    const int h = e & 63;
    const float ang = (float)(2.0 * M_PI / 64.0) * (float)((kh * h) & 63);
    float s_, c_;
    __sincosf(ang, &s_, &c_);
    Cs[e] = f2bf(0.125f * c_);
    Ss[e] = f2bf(0.125f * (float)SIGN * s_);
  }
  __syncthreads();

  const int lane = t & 63;
  const int wv = t >> 6;       // wave id 0..3 -> c-strip
  const int cl = lane & 15;
  const int kg = lane >> 4;    // 0..3
  const size_t cbase =
      (size_t)blockIdx.x * (64 * 768) + blockIdx.y * 64 + wv * 16 + cl;

  f32x4 aR[4], aI[4];
#pragma unroll
  for (int mi = 0; mi < 4; ++mi) {
    aR[mi] = (f32x4){0.f, 0.f, 0.f, 0.f};
    aI[mi] = (f32x4){0.f, 0.f, 0.f, 0.f};
  }

#pragma unroll
  for (int kf = 0; kf < 2; ++kf) {
    const int h0 = kf * 32 + kg * 8;
    short8 brf, bif;
#pragma unroll
    for (int j = 0; j < 8; ++j) {
      brf[j] = (short)Xr[cbase + (size_t)(h0 + j) * 768];
      bif[j] = (short)Xi[cbase + (size_t)(h0 + j) * 768];
    }
    const bf16x8 bxr = s2b(brf);
    const bf16x8 bxi = s2b(bif);
    const bf16x8 bxin = negb(bif);
#pragma unroll
    for (int mi = 0; mi < 4; ++mi) {
      const int arow = mi * 16 + cl;
      const bf16x8 ac =
          *reinterpret_cast<const bf16x8*>(Cs + arow * 64 + kf * 32 + kg * 8);
      const bf16x8 as =
          *reinterpret_cast<const bf16x8*>(Ss + arow * 64 + kf * 32 + kg * 8);
      aR[mi] = __builtin_amdgcn_mfma_f32_16x16x32_bf16(ac, bxr, aR[mi], 0, 0, 0);
      aR[mi] = __builtin_amdgcn_mfma_f32_16x16x32_bf16(as, bxin, aR[mi], 0, 0, 0);
      aI[mi] = __builtin_amdgcn_mfma_f32_16x16x32_bf16(ac, bxi, aI[mi], 0, 0, 0);
      aI[mi] = __builtin_amdgcn_mfma_f32_16x16x32_bf16(as, bxr, aI[mi], 0, 0, 0);
    }
  }

#pragma unroll
  for (int mi = 0; mi < 4; ++mi) {
#pragma unroll
    for (int r = 0; r < 4; ++r) {
      const int kh = mi * 16 + kg * 4 + r;
      Xr[cbase + (size_t)kh * 768] = f2bf(aR[mi][r]);
      Xi[cbase + (size_t)kh * 768] = f2bf(aI[mi][r]);
    }
  }
}

// ---------------- 4. block-diagonal complex MLP via MFMA (in place, bf16) --
// Weights read as B-fragments directly from pre-transposed g_wT (L2-resident).
__global__ __launch_bounds__(512) void mlp_mfma_kernel(
    unsigned short* __restrict__ Xr, unsigned short* __restrict__ Xi,
    const float* __restrict__ b1, const float* __restrict__ b2) {
  __shared__ unsigned short sXr[128 * 104];      // 26.6 KB (reused for R1)
  __shared__ unsigned short sXi[128 * 104];      // 26.6 KB (reused for I1)
  const int t = threadIdx.x;
  const int lane = t & 63;
  const int wid = t >> 6;   // 0..7
  const int wm = wid >> 1;  // 0..3: rows wm*32
  const int wn = wid & 1;   // 0..1: cols wn*48
  const int cl = lane & 15;
  const int kg = lane >> 4;
  const int nb = blockIdx.y;
  const size_t p0 = (size_t)blockIdx.x * 128;

  // ---- stage X tile: bf16 global -> LDS (vector copy, no convert) ----
  {
    const int row = t >> 2;
    const int q = t & 3;  // 24-elem chunk
    const size_t gbase = (p0 + row) * 768 + nb * 96 + q * 24;
    unsigned short* lr = sXr + row * 104 + q * 24;
    unsigned short* li = sXi + row * 104 + q * 24;
#pragma unroll
    for (int v = 0; v < 3; ++v) {
      *reinterpret_cast<short8*>(lr + v * 8) =
          *reinterpret_cast<const short8*>(Xr + gbase + v * 8);
      *reinterpret_cast<short8*>(li + v * 8) =
          *reinterpret_cast<const short8*>(Xi + gbase + v * 8);
    }
  }
  __syncthreads();

  const unsigned short* wt1r = g_wT + (size_t)(0 * 8 + nb) * 9216;
  const unsigned short* wt1i = g_wT + (size_t)(1 * 8 + nb) * 9216;
  const unsigned short* wt2r = g_wT + (size_t)(2 * 8 + nb) * 9216;
  const unsigned short* wt2i = g_wT + (size_t)(3 * 8 + nb) * 9216;

  f32x4 aR[2][3], aI[2][3];
#pragma unroll
  for (int mf = 0; mf < 2; ++mf)
#pragma unroll
    for (int nf = 0; nf < 3; ++nf) {
      aR[mf][nf] = (f32x4){0.f, 0.f, 0.f, 0.f};
      aI[mf][nf] = (f32x4){0.f, 0.f, 0.f, 0.f};
    }

  // ---- layer 1 ----
#pragma unroll
  for (int kk = 0; kk < 3; ++kk) {
    const int ko = kk * 32 + kg * 8;
    short8 xr_[2], xi_[2];
#pragma unroll
    for (int mf = 0; mf < 2; ++mf) {
      const int r = wm * 32 + mf * 16 + cl;
      xr_[mf] = *reinterpret_cast<const short8*>(sXr + r * 104 + ko);
      xi_[mf] = *reinterpret_cast<const short8*>(sXi + r * 104 + ko);
    }
    short8 wr_[3], wi_[3];
#pragma unroll
    for (int nf = 0; nf < 3; ++nf) {
      const int r = wn * 48 + nf * 16 + cl;
      wr_[nf] = *reinterpret_cast<const short8*>(wt1r + r * 96 + ko);
      wi_[nf] = *reinterpret_cast<const short8*>(wt1i + r * 96 + ko);
    }
#pragma unroll
    for (int mf = 0; mf < 2; ++mf) {
      const bf16x8 axr = s2b(xr_[mf]);
      const bf16x8 axi = s2b(xi_[mf]);
      const bf16x8 axin = negb(xi_[mf]);
#pragma unroll
      for (int nf = 0; nf < 3; ++nf) {
        aR[mf][nf] = __builtin_amdgcn_mfma_f32_16x16x32_bf16(axr, s2b(wr_[nf]), aR[mf][nf], 0, 0, 0);
        aR[mf][nf] = __builtin_amdgcn_mfma_f32_16x16x32_bf16(axin, s2b(wi_[nf]), aR[mf][nf], 0, 0, 0);
        aI[mf][nf] = __builtin_amdgcn_mfma_f32_16x16x32_bf16(axr, s2b(wi_[nf]), aI[mf][nf], 0, 0, 0);
        aI[mf][nf] = __builtin_amdgcn_mfma_f32_16x16x32_bf16(axi, s2b(wr_[nf]), aI[mf][nf], 0, 0, 0);
      }
    }
  }
  __syncthreads();  // all layer-1 LDS reads complete before overwrite

  // epilogue L1: bias + relu -> bf16 back into sXr/sXi
#pragma unroll
  for (int nf = 0; nf < 3; ++nf) {
    const int col = wn * 48 + nf * 16 + cl;
    const float br = b1[nb * 96 + col];
    const float bi = b1[768 + nb * 96 + col];
#pragma unroll
    for (int mf = 0; mf < 2; ++mf) {
#pragma unroll
      for (int r = 0; r < 4; ++r) {
        const int m = wm * 32 + mf * 16 + kg * 4 + r;
        const float vr = fmaxf(aR[mf][nf][r] + br, 0.f);
        const float vi = fmaxf(aI[mf][nf][r] + bi, 0.f);
        sXr[m * 104 + col] = f2bf(vr);
        sXi[m * 104 + col] = f2bf(vi);
      }
    }
  }
  __syncthreads();

  // ---- layer 2 ----
#pragma unroll
  for (int mf = 0; mf < 2; ++mf)
#pragma unroll
    for (int nf = 0; nf < 3; ++nf) {
      aR[mf][nf] = (f32x4){0.f, 0.f, 0.f, 0.f};
      aI[mf][nf] = (f32x4){0.f, 0.f, 0.f, 0.f};
    }
#pragma unroll
  for (int kk = 0; kk < 3; ++kk) {
    const int ko = kk * 32 + kg * 8;
    short8 xr_[2], xi_[2];
#pragma unroll
    for (int mf = 0; mf < 2; ++mf) {
      const int r = wm * 32 + mf * 16 + cl;
      xr_[mf] = *reinterpret_cast<const short8*>(sXr + r * 104 + ko);
      xi_[mf] = *reinterpret_cast<const short8*>(sXi + r * 104 + ko);
    }
    short8 wr_[3], wi_[3];
#pragma unroll
    for (int nf = 0; nf < 3; ++nf) {
      const int r = wn * 48 + nf * 16 + cl;
      wr_[nf] = *reinterpret_cast<const short8*>(wt2r + r * 96 + ko);
      wi_[nf] = *reinterpret_cast<const short8*>(wt2i + r * 96 + ko);
    }
#pragma unroll
    for (int mf = 0; mf < 2; ++mf) {
      const bf16x8 axr = s2b(xr_[mf]);
      const bf16x8 axi = s2b(xi_[mf]);
      const bf16x8 axin = negb(xi_[mf]);
#pragma unroll
      for (int nf = 0; nf < 3; ++nf) {
        aR[mf][nf] = __builtin_amdgcn_mfma_f32_16x16x32_bf16(axr, s2b(wr_[nf]), aR[mf][nf], 0, 0, 0);
        aR[mf][nf] = __builtin_amdgcn_mfma_f32_16x16x32_bf16(axin, s2b(wi_[nf]), aR[mf][nf], 0, 0, 0);
        aI[mf][nf] = __builtin_amdgcn_mfma_f32_16x16x32_bf16(axr, s2b(wi_[nf]), aI[mf][nf], 0, 0, 0);
        aI[mf][nf] = __builtin_amdgcn_mfma_f32_16x16x32_bf16(axi, s2b(wr_[nf]), aI[mf][nf], 0, 0, 0);
      }
    }
  }

  // epilogue L2: bias + softshrink -> bf16 global (in place)
#pragma unroll
  for (int nf = 0; nf < 3; ++nf) {
    const int col = wn * 48 + nf * 16 + cl;
    const float br = b2[nb * 96 + col];
    const float bi = b2[768 + nb * 96 + col];
    const int gc = nb * 96 + col;
#pragma unroll
    for (int mf = 0; mf < 2; ++mf) {
#pragma unroll
      for (int r = 0; r < 4; ++r) {
        const int m = wm * 32 + mf * 16 + kg * 4 + r;
        float vr = aR[mf][nf][r] + br;
        float vi = aI[mf][nf][r] + bi;
        vr = (vr > kLambd) ? (vr - kLambd) : ((vr < -kLambd) ? (vr + kLambd) : 0.f);
        vi = (vi > kLambd) ? (vi - kLambd) : ((vi < -kLambd) ? (vi + kLambd) : 0.f);
        Xr[(p0 + m) * 768 + gc] = f2bf(vr);
        Xi[(p0 + m) * 768 + gc] = f2bf(vi);
      }
    }
  }
}

// ---------------- 6. inverse row rDFT + accumulate via MFMA ----------------
__global__ __launch_bounds__(256) void irfft_row_add_mfma_kernel(
    const unsigned short* __restrict__ Zr, const unsigned short* __restrict__ Zi,
    float* __restrict__ out) {
  __shared__ alignas(16) unsigned short Ac[64 * 64];   // [w][kw] 8KB
  __shared__ alignas(16) unsigned short Asn[64 * 64];  // [w][kw] 8KB
  const int t = threadIdx.x;
  for (int e = t; e < 4096; e += 256) {
    const int w = e >> 6;
    const int kw = e & 63;
    if (kw < 33) {
      const float a = (kw == 0 || kw == 32) ? 0.125f : 0.25f;
      const float ang = (float)(2.0 * M_PI / 64.0) * (float)((kw * w) & 63);
      float s_, c_;
      __sincosf(ang, &s_, &c_);
      Ac[e] = f2bf(a * c_);
      Asn[e] = f2bf(-a * s_);
    } else {
      Ac[e] = 0;
      Asn[e] = 0;
    }
  }
  __syncthreads();

  const int lane = t & 63;
  const int wv = t >> 6;
  const int cl = lane & 15;
  const int kg = lane >> 4;
  const int bh = blockIdx.x;  // b*64 + h
  const int b = bh >> 6;
  const int h = bh & 63;
  const int c = blockIdx.y * 64 + wv * 16 + cl;
  const size_t zbase = (((size_t)b * kNKW) * 64 + h) * 768 + c;  // + kw*64*768
  float* ocol = out + ((size_t)bh * 64) * 768 + c;

  // preload accumulator with bias-path values
  f32x4 aO[4];
#pragma unroll
  for (int mi = 0; mi < 4; ++mi) {
#pragma unroll
    for (int r = 0; r < 4; ++r) {
      const int w = mi * 16 + kg * 4 + r;
      aO[mi][r] = ocol[(size_t)w * 768];
    }
  }

#pragma unroll
  for (int kf = 0; kf < 2; ++kf) {
    short8 bzr = {0, 0, 0, 0, 0, 0, 0, 0};
    short8 bzi = {0, 0, 0, 0, 0, 0, 0, 0};
#pragma unroll
    for (int j = 0; j < 8; ++j) {
      const int kw = kf * 32 + kg * 8 + j;
      if (kw < 33) {
        bzr[j] = (short)Zr[zbase + (size_t)kw * (64 * 768)];
        bzi[j] = (short)Zi[zbase + (size_t)kw * (64 * 768)];
      }
    }
    const bf16x8 br = s2b(bzr);
    const bf16x8 bi = s2b(bzi);
#pragma unroll
    for (int mi = 0; mi < 4; ++mi) {
      const int arow = mi * 16 + cl;
      const bf16x8 acf =
          *reinterpret_cast<const bf16x8*>(Ac + arow * 64 + kf * 32 + kg * 8);
      const bf16x8 asf =
          *reinterpret_cast<const bf16x8*>(Asn + arow * 64 + kf * 32 + kg * 8);
      aO[mi] = __builtin_amdgcn_mfma_f32_16x16x32_bf16(acf, br, aO[mi], 0, 0, 0);
      aO[mi] = __builtin_amdgcn_mfma_f32_16x16x32_bf16(asf, bi, aO[mi], 0, 0, 0);
    }
  }

#pragma unroll
  for (int mi = 0; mi < 4; ++mi) {
#pragma unroll
    for (int r = 0; r < 4; ++r) {
      const int w = mi * 16 + kg * 4 + r;
      ocol[(size_t)w * 768] = aO[mi][r];
    }
  }
}

}  // namespace

extern "C" void kernel_launch(void* const* d_in, const int* in_sizes, int n_in,
                              void* d_out, int out_size, void* d_ws,
                              size_t ws_size, hipStream_t stream) {
  (void)in_sizes; (void)n_in; (void)out_size;
  const float* x  = (const float*)d_in[0];
  const float* w1 = (const float*)d_in[1];
  const float* b1 = (const float*)d_in[2];
  const float* w2 = (const float*)d_in[3];
  const float* b2 = (const float*)d_in[4];
  const float* Wb = (const float*)d_in[5];
  const float* bb = (const float*)d_in[6];
  float* out = (float*)d_out;

  // ws layout (all bf16): xbf 48MB | wbf 1.2MB | XFr 26MB | XFi 26MB = 103.4MB
  if (ws_size < 2 * kXFElems * sizeof(float)) return;  // fits in required 103.8MB
  unsigned short* xbf = (unsigned short*)d_ws;      // 32768*768
  unsigned short* wbf = xbf + (size_t)32768 * 768;  // 768*768
  unsigned short* XFr = wbf + (size_t)768 * 768;    // kXFElems
  unsigned short* XFi = XFr + kXFElems;             // kXFElems

  // 0. conversions: x, Wb to bf16; MLP weights transposed to g_wT
  cvt_f32_bf16_kernel<<<dim3((32768 * 768 / 4 + 255) / 256), 256, 0, stream>>>(
      x, xbf, 32768 * 768 / 4);
  cvt_f32_bf16_kernel<<<dim3((768 * 768 / 4 + 255) / 256), 256, 0, stream>>>(
      Wb, wbf, 768 * 768 / 4);
  cvt_w_kernel<<<dim3(4 * 8 * 96 * 96 / 256), 256, 0, stream>>>(w1, w2);
  // 1. bias path GEMM on matrix cores (writes d_out fully)
  mfma_gemm_kernel<<<dim3(32768 / 128, 768 / 128), 256, 0, stream>>>(xbf, wbf, bb, out);
  // 2. forward row rFFT on matrix cores (bf16 out)
  rfft_row_mfma_kernel<<<dim3(512, 12), 256, 0, stream>>>(x, XFr, XFi);
  // 3. forward column FFT on matrix cores (in place, bf16)
  fft_col_mfma_kernel<-1><<<dim3(264, 12), 256, 0, stream>>>(XFr, XFi);
  // 4. block-diagonal complex MLP on matrix cores (in place, bf16)
  mlp_mfma_kernel<<<dim3(132, 8), 512, 0, stream>>>(XFr, XFi, b1, b2);
  // 5. inverse column FFT on matrix cores (in place, bf16)
  fft_col_mfma_kernel<1><<<dim3(264, 12), 256, 0, stream>>>(XFr, XFi);
  // 6. inverse row rDFT + add bias path on matrix cores
  irfft_row_add_mfma_kernel<<<dim3(512, 12), 256, 0, stream>>>(XFr, XFi, out);
}

// Round 11
// 261.611 us; speedup vs baseline: 6.9059x; 1.0543x over previous
//
#include <hip/hip_runtime.h>
#include <math.h>

#ifndef M_PI
#define M_PI 3.14159265358979323846
#endif

namespace {

constexpr int kDim = 768;
constexpr int kNKW = 33;           // W/2+1
constexpr int kB = 8;
constexpr float kLambd = 0.01f;
constexpr size_t kXFElems = (size_t)kB * kNKW * 64 * kDim;  // 12,976,128

typedef __attribute__((ext_vector_type(8))) __bf16 bf16x8;
typedef __attribute__((ext_vector_type(8))) short short8;
typedef __attribute__((ext_vector_type(4))) float f32x4;

// Pre-transposed bf16 MLP weights: [mtx][nb][k_out][d], mtx: w1r,w1i,w2r,w2i
alignas(16) __device__ unsigned short g_wT[4 * 8 * 96 * 96];

// RNE float -> bf16 (inputs are normal floats; NaN not expected)
__device__ inline unsigned short f2bf(float f) {
  unsigned int u = __float_as_uint(f);
  unsigned int r = (u + 0x7FFFu + ((u >> 16) & 1u)) >> 16;
  return (unsigned short)r;
}

__device__ inline bf16x8 s2b(short8 s) { return __builtin_bit_cast(bf16x8, s); }
__device__ inline bf16x8 negb(short8 s) {
  s ^= (short)0x8000;
  return __builtin_bit_cast(bf16x8, s);
}

__device__ inline void gload_lds16(const void* g, void* l) {
  __builtin_amdgcn_global_load_lds(
      (const __attribute__((address_space(1))) unsigned int*)g,
      (__attribute__((address_space(3))) unsigned int*)l, 16, 0, 0);
}

// ---------------- 0a. fp32 -> bf16 conversion (Wb only now) ----------------
__global__ __launch_bounds__(256) void cvt_f32_bf16_kernel(
    const float* __restrict__ in, unsigned short* __restrict__ out, int n4) {
  int i = blockIdx.x * 256 + threadIdx.x;
  if (i >= n4) return;
  const float4 v = reinterpret_cast<const float4*>(in)[i];
  ushort4 o;
  o.x = f2bf(v.x); o.y = f2bf(v.y); o.z = f2bf(v.z); o.w = f2bf(v.w);
  reinterpret_cast<ushort4*>(out)[i] = o;
}

// ---------------- 0b. MLP weight transpose+convert (once per launch) -------
// g_wT[mtx][nb][k][d] = src[mtx][nb][d][k]
__global__ __launch_bounds__(256) void cvt_w_kernel(
    const float* __restrict__ w1, const float* __restrict__ w2) {
  const int e = blockIdx.x * 256 + threadIdx.x;
  if (e >= 4 * 8 * 96 * 96) return;
  const int k = e % 96;
  const int d = (e / 96) % 96;
  const int nbm = e / 9216;  // mtx*8+nb
  const int mtx = nbm >> 3;
  const int nb = nbm & 7;
  const float* src =
      (mtx < 2 ? w1 : w2) + ((size_t)(mtx & 1) * 8 + nb) * 9216;
  g_wT[((size_t)nbm * 96 + k) * 96 + d] = f2bf(src[d * 96 + k]);
}

// ---------------- 1. bias GEMM via MFMA ------------------------------------
// out[m,n] = sum_k xbf[m,k] * wbf[n,k] + bb[n]; M=32768, N=768, K=768.
// 1-D grid, nb-fast ordering + bijective XCD chunk swizzle (nwg=1536, cpx=192).
__global__ __launch_bounds__(256) void mfma_gemm_kernel(
    const unsigned short* __restrict__ xbf, const unsigned short* __restrict__ wbf,
    const float* __restrict__ bb, float* __restrict__ out) {
  __shared__ unsigned short As[128 * 32];  // [row][k] 8KB
  __shared__ unsigned short Bs[128 * 32];  // [n][k]   8KB
  const int t = threadIdx.x;
  const int lane = t & 63;
  const int wid = t >> 6;
  const int wm = wid >> 1;
  const int wn = wid & 1;
  const int id = blockIdx.x;
  const int swz = (id & 7) * 192 + (id >> 3);  // XCD chunk swizzle, bijective
  const int m0 = (swz / 6) * 128;
  const int n0 = (swz % 6) * 128;

  f32x4 acc[4][4];
#pragma unroll
  for (int i = 0; i < 4; ++i)
#pragma unroll
    for (int j = 0; j < 4; ++j) acc[i][j] = (f32x4){0.f, 0.f, 0.f, 0.f};

  char* AsB = (char*)As;
  char* BsB = (char*)Bs;
  const int cl = lane & 15;
  const int kg = lane >> 4;  // 0..3

  for (int k0 = 0; k0 < 768; k0 += 32) {
#pragma unroll
    for (int i = 0; i < 2; ++i) {
      const int off = (wid * 2 + i) * 1024 + lane * 16;  // byte off in tile
      const int row = off >> 6;
      const int kb = off & 63;
      const char* gA = (const char*)xbf + ((size_t)(m0 + row) * 768 + k0) * 2 + kb;
      gload_lds16(gA, AsB + (wid * 2 + i) * 1024);
      const char* gB = (const char*)wbf + ((size_t)(n0 + row) * 768 + k0) * 2 + kb;
      gload_lds16(gB, BsB + (wid * 2 + i) * 1024);
    }
    asm volatile("s_waitcnt vmcnt(0)" ::: "memory");
    __syncthreads();

    bf16x8 av[4], bv[4];
#pragma unroll
    for (int mi = 0; mi < 4; ++mi) {
      const int r = wm * 64 + mi * 16 + cl;
      av[mi] = *reinterpret_cast<const bf16x8*>(AsB + r * 64 + kg * 16);
    }
#pragma unroll
    for (int ni = 0; ni < 4; ++ni) {
      const int r = wn * 64 + ni * 16 + cl;
      bv[ni] = *reinterpret_cast<const bf16x8*>(BsB + r * 64 + kg * 16);
    }
#pragma unroll
    for (int mi = 0; mi < 4; ++mi)
#pragma unroll
      for (int ni = 0; ni < 4; ++ni)
        acc[mi][ni] = __builtin_amdgcn_mfma_f32_16x16x32_bf16(
            av[mi], bv[ni], acc[mi][ni], 0, 0, 0);
    __syncthreads();
  }

#pragma unroll
  for (int ni = 0; ni < 4; ++ni) {
    const int n = n0 + wn * 64 + ni * 16 + cl;
    const float bias = bb[n];
#pragma unroll
    for (int mi = 0; mi < 4; ++mi) {
      const int m = m0 + wm * 64 + mi * 16 + kg * 4;
#pragma unroll
      for (int r = 0; r < 4; ++r) {
        out[(size_t)(m + r) * 768 + n] = acc[mi][ni][r] + bias;
      }
    }
  }
}

// ---------------- 2. forward row rFFT via MFMA + fused x->bf16 -------------
// XF bf16 layout: [b][kw][h][c]. Also writes xbf (bit-identical to old cvt).
__global__ __launch_bounds__(256) void rfft_row_mfma_kernel(
    const float* __restrict__ x, unsigned short* __restrict__ xbf,
    unsigned short* __restrict__ XFr, unsigned short* __restrict__ XFi) {
  __shared__ alignas(16) unsigned short Cs[48 * 64];  //  0.125*cos [kh][w] 6KB
  __shared__ alignas(16) unsigned short Ss[48 * 64];  // -0.125*sin        6KB
  const int t = threadIdx.x;
  for (int e = t; e < 48 * 64; e += 256) {
    const int kh = e >> 6;
    const int w = e & 63;
    const float ang = (float)(2.0 * M_PI / 64.0) * (float)((kh * w) & 63);
    float s_, c_;
    __sincosf(ang, &s_, &c_);
    Cs[e] = f2bf(0.125f * c_);
    Ss[e] = f2bf(-0.125f * s_);
  }
  __syncthreads();

  const int lane = t & 63;
  const int wv = t >> 6;       // wave -> c-strip
  const int cl = lane & 15;
  const int kg = lane >> 4;    // 0..3
  const int bh = blockIdx.x;   // b*64 + h
  const int b = bh >> 6;
  const int h = bh & 63;
  const int c = blockIdx.y * 64 + wv * 16 + cl;
  const float* xcol = x + ((size_t)bh * 64) * 768 + c;

  f32x4 aR[3], aI[3];
#pragma unroll
  for (int mi = 0; mi < 3; ++mi) {
    aR[mi] = (f32x4){0.f, 0.f, 0.f, 0.f};
    aI[mi] = (f32x4){0.f, 0.f, 0.f, 0.f};
  }

#pragma unroll
  for (int kf = 0; kf < 2; ++kf) {
    const int w0 = kf * 32 + kg * 8;
    float xv[8];
#pragma unroll
    for (int j = 0; j < 8; ++j) xv[j] = xcol[(size_t)(w0 + j) * 768];
    short8 bs;
#pragma unroll
    for (int j = 0; j < 8; ++j) bs[j] = (short)f2bf(xv[j]);
    // fused x -> bf16 side output for the bias GEMM
#pragma unroll
    for (int j = 0; j < 8; ++j) {
      xbf[(size_t)(bh * 64 + w0 + j) * 768 + c] = (unsigned short)bs[j];
    }
    const bf16x8 bx = s2b(bs);
#pragma unroll
    for (int mi = 0; mi < 3; ++mi) {
      const int arow = mi * 16 + cl;
      const bf16x8 ac =
          *reinterpret_cast<const bf16x8*>(Cs + arow * 64 + kf * 32 + kg * 8);
      const bf16x8 as =
          *reinterpret_cast<const bf16x8*>(Ss + arow * 64 + kf * 32 + kg * 8);
      aR[mi] = __builtin_amdgcn_mfma_f32_16x16x32_bf16(ac, bx, aR[mi], 0, 0, 0);
      aI[mi] = __builtin_amdgcn_mfma_f32_16x16x32_bf16(as, bx, aI[mi], 0, 0, 0);
    }
  }

#pragma unroll
  for (int mi = 0; mi < 3; ++mi) {
#pragma unroll
    for (int r = 0; r < 4; ++r) {
      const int kh = mi * 16 + kg * 4 + r;
      if (kh <= 32) {
        const size_t off = (((size_t)b * kNKW + kh) * 64 + h) * 768 + c;
        XFr[off] = f2bf(aR[mi][r]);
        XFi[off] = f2bf(aI[mi][r]);
      }
    }
  }
}

// ---------------- 3/5. column FFT along h via MFMA (in place, bf16) --------
template <int SIGN>
__global__ __launch_bounds__(256) void fft_col_mfma_kernel(
    unsigned short* __restrict__ Xr, unsigned short* __restrict__ Xi) {
  __shared__ alignas(16) unsigned short Cs[64 * 64];  // 0.125*cos  [kh][h] 8KB
  __shared__ alignas(16) unsigned short Ss[64 * 64];  // 0.125*SIGN*sin      8KB
  const int t = threadIdx.x;
  for (int e = t; e < 4096; e += 256) {
    const int kh = e >> 6;
    const int h = e & 63;
    const float ang = (float)(2.0 * M_PI / 64.0) * (float)((kh * h) & 63);
    float s_, c_;
    __sincosf(ang, &s_, &c_);
    Cs[e] = f2bf(0.125f * c_);
    Ss[e] = f2bf(0.125f * (float)SIGN * s_);
  }
  __syncthreads();

  const int lane = t & 63;
  const int wv = t >> 6;       // wave id 0..3 -> c-strip
  const int cl = lane & 15;
  const int kg = lane >> 4;    // 0..3
  const size_t cbase =
      (size_t)blockIdx.x * (64 * 768) + blockIdx.y * 64 + wv * 16 + cl;

  f32x4 aR[4], aI[4];
#pragma unroll
  for (int mi = 0; mi < 4; ++mi) {
    aR[mi] = (f32x4){0.f, 0.f, 0.f, 0.f};
    aI[mi] = (f32x4){0.f, 0.f, 0.f, 0.f};
  }

#pragma unroll
  for (int kf = 0; kf < 2; ++kf) {
    const int h0 = kf * 32 + kg * 8;
    short8 brf, bif;
#pragma unroll
    for (int j = 0; j < 8; ++j) {
      brf[j] = (short)Xr[cbase + (size_t)(h0 + j) * 768];
      bif[j] = (short)Xi[cbase + (size_t)(h0 + j) * 768];
    }
    const bf16x8 bxr = s2b(brf);
    const bf16x8 bxi = s2b(bif);
    const bf16x8 bxin = negb(bif);
#pragma unroll
    for (int mi = 0; mi < 4; ++mi) {
      const int arow = mi * 16 + cl;
      const bf16x8 ac =
          *reinterpret_cast<const bf16x8*>(Cs + arow * 64 + kf * 32 + kg * 8);
      const bf16x8 as =
          *reinterpret_cast<const bf16x8*>(Ss + arow * 64 + kf * 32 + kg * 8);
      aR[mi] = __builtin_amdgcn_mfma_f32_16x16x32_bf16(ac, bxr, aR[mi], 0, 0, 0);
      aR[mi] = __builtin_amdgcn_mfma_f32_16x16x32_bf16(as, bxin, aR[mi], 0, 0, 0);
      aI[mi] = __builtin_amdgcn_mfma_f32_16x16x32_bf16(ac, bxi, aI[mi], 0, 0, 0);
      aI[mi] = __builtin_amdgcn_mfma_f32_16x16x32_bf16(as, bxr, aI[mi], 0, 0, 0);
    }
  }

#pragma unroll
  for (int mi = 0; mi < 4; ++mi) {
#pragma unroll
    for (int r = 0; r < 4; ++r) {
      const int kh = mi * 16 + kg * 4 + r;
      Xr[cbase + (size_t)kh * 768] = f2bf(aR[mi][r]);
      Xi[cbase + (size_t)kh * 768] = f2bf(aI[mi][r]);
    }
  }
}

// ---------------- 4. block-diagonal complex MLP via MFMA (in place, bf16) --
// Weights read as B-fragments directly from pre-transposed g_wT (L2-resident).
__global__ __launch_bounds__(512) void mlp_mfma_kernel(
    unsigned short* __restrict__ Xr, unsigned short* __restrict__ Xi,
    const float* __restrict__ b1, const float* __restrict__ b2) {
  __shared__ unsigned short sXr[128 * 104];      // 26.6 KB (reused for R1)
  __shared__ unsigned short sXi[128 * 104];      // 26.6 KB (reused for I1)
  const int t = threadIdx.x;
  const int lane = t & 63;
  const int wid = t >> 6;   // 0..7
  const int wm = wid >> 1;  // 0..3: rows wm*32
  const int wn = wid & 1;   // 0..1: cols wn*48
  const int cl = lane & 15;
  const int kg = lane >> 4;
  const int nb = blockIdx.y;
  const size_t p0 = (size_t)blockIdx.x * 128;

  // ---- stage X tile: bf16 global -> LDS (vector copy, no convert) ----
  {
    const int row = t >> 2;
    const int q = t & 3;  // 24-elem chunk
    const size_t gbase = (p0 + row) * 768 + nb * 96 + q * 24;
    unsigned short* lr = sXr + row * 104 + q * 24;
    unsigned short* li = sXi + row * 104 + q * 24;
#pragma unroll
    for (int v = 0; v < 3; ++v) {
      *reinterpret_cast<short8*>(lr + v * 8) =
          *reinterpret_cast<const short8*>(Xr + gbase + v * 8);
      *reinterpret_cast<short8*>(li + v * 8) =
          *reinterpret_cast<const short8*>(Xi + gbase + v * 8);
    }
  }
  __syncthreads();

  const unsigned short* wt1r = g_wT + (size_t)(0 * 8 + nb) * 9216;
  const unsigned short* wt1i = g_wT + (size_t)(1 * 8 + nb) * 9216;
  const unsigned short* wt2r = g_wT + (size_t)(2 * 8 + nb) * 9216;
  const unsigned short* wt2i = g_wT + (size_t)(3 * 8 + nb) * 9216;

  f32x4 aR[2][3], aI[2][3];
#pragma unroll
  for (int mf = 0; mf < 2; ++mf)
#pragma unroll
    for (int nf = 0; nf < 3; ++nf) {
      aR[mf][nf] = (f32x4){0.f, 0.f, 0.f, 0.f};
      aI[mf][nf] = (f32x4){0.f, 0.f, 0.f, 0.f};
    }

  // ---- layer 1 ----
#pragma unroll
  for (int kk = 0; kk < 3; ++kk) {
    const int ko = kk * 32 + kg * 8;
    short8 xr_[2], xi_[2];
#pragma unroll
    for (int mf = 0; mf < 2; ++mf) {
      const int r = wm * 32 + mf * 16 + cl;
      xr_[mf] = *reinterpret_cast<const short8*>(sXr + r * 104 + ko);
      xi_[mf] = *reinterpret_cast<const short8*>(sXi + r * 104 + ko);
    }
    short8 wr_[3], wi_[3];
#pragma unroll
    for (int nf = 0; nf < 3; ++nf) {
      const int r = wn * 48 + nf * 16 + cl;
      wr_[nf] = *reinterpret_cast<const short8*>(wt1r + r * 96 + ko);
      wi_[nf] = *reinterpret_cast<const short8*>(wt1i + r * 96 + ko);
    }
#pragma unroll
    for (int mf = 0; mf < 2; ++mf) {
      const bf16x8 axr = s2b(xr_[mf]);
      const bf16x8 axi = s2b(xi_[mf]);
      const bf16x8 axin = negb(xi_[mf]);
#pragma unroll
      for (int nf = 0; nf < 3; ++nf) {
        aR[mf][nf] = __builtin_amdgcn_mfma_f32_16x16x32_bf16(axr, s2b(wr_[nf]), aR[mf][nf], 0, 0, 0);
        aR[mf][nf] = __builtin_amdgcn_mfma_f32_16x16x32_bf16(axin, s2b(wi_[nf]), aR[mf][nf], 0, 0, 0);
        aI[mf][nf] = __builtin_amdgcn_mfma_f32_16x16x32_bf16(axr, s2b(wi_[nf]), aI[mf][nf], 0, 0, 0);
        aI[mf][nf] = __builtin_amdgcn_mfma_f32_16x16x32_bf16(axi, s2b(wr_[nf]), aI[mf][nf], 0, 0, 0);
      }
    }
  }
  __syncthreads();  // all layer-1 LDS reads complete before overwrite

  // epilogue L1: bias + relu -> bf16 back into sXr/sXi
#pragma unroll
  for (int nf = 0; nf < 3; ++nf) {
    const int col = wn * 48 + nf * 16 + cl;
    const float br = b1[nb * 96 + col];
    const float bi = b1[768 + nb * 96 + col];
#pragma unroll
    for (int mf = 0; mf < 2; ++mf) {
#pragma unroll
      for (int r = 0; r < 4; ++r) {
        const int m = wm * 32 + mf * 16 + kg * 4 + r;
        const float vr = fmaxf(aR[mf][nf][r] + br, 0.f);
        const float vi = fmaxf(aI[mf][nf][r] + bi, 0.f);
        sXr[m * 104 + col] = f2bf(vr);
        sXi[m * 104 + col] = f2bf(vi);
      }
    }
  }
  __syncthreads();

  // ---- layer 2 ----
#pragma unroll
  for (int mf = 0; mf < 2; ++mf)
#pragma unroll
    for (int nf = 0; nf < 3; ++nf) {
      aR[mf][nf] = (f32x4){0.f, 0.f, 0.f, 0.f};
      aI[mf][nf] = (f32x4){0.f, 0.f, 0.f, 0.f};
    }
#pragma unroll
  for (int kk = 0; kk < 3; ++kk) {
    const int ko = kk * 32 + kg * 8;
    short8 xr_[2], xi_[2];
#pragma unroll
    for (int mf = 0; mf < 2; ++mf) {
      const int r = wm * 32 + mf * 16 + cl;
      xr_[mf] = *reinterpret_cast<const short8*>(sXr + r * 104 + ko);
      xi_[mf] = *reinterpret_cast<const short8*>(sXi + r * 104 + ko);
    }
    short8 wr_[3], wi_[3];
#pragma unroll
    for (int nf = 0; nf < 3; ++nf) {
      const int r = wn * 48 + nf * 16 + cl;
      wr_[nf] = *reinterpret_cast<const short8*>(wt2r + r * 96 + ko);
      wi_[nf] = *reinterpret_cast<const short8*>(wt2i + r * 96 + ko);
    }
#pragma unroll
    for (int mf = 0; mf < 2; ++mf) {
      const bf16x8 axr = s2b(xr_[mf]);
      const bf16x8 axi = s2b(xi_[mf]);
      const bf16x8 axin = negb(xi_[mf]);
#pragma unroll
      for (int nf = 0; nf < 3; ++nf) {
        aR[mf][nf] = __builtin_amdgcn_mfma_f32_16x16x32_bf16(axr, s2b(wr_[nf]), aR[mf][nf], 0, 0, 0);
        aR[mf][nf] = __builtin_amdgcn_mfma_f32_16x16x32_bf16(axin, s2b(wi_[nf]), aR[mf][nf], 0, 0, 0);
        aI[mf][nf] = __builtin_amdgcn_mfma_f32_16x16x32_bf16(axr, s2b(wi_[nf]), aI[mf][nf], 0, 0, 0);
        aI[mf][nf] = __builtin_amdgcn_mfma_f32_16x16x32_bf16(axi, s2b(wr_[nf]), aI[mf][nf], 0, 0, 0);
      }
    }
  }

  // epilogue L2: bias + softshrink -> bf16 global (in place)
#pragma unroll
  for (int nf = 0; nf < 3; ++nf) {
    const int col = wn * 48 + nf * 16 + cl;
    const float br = b2[nb * 96 + col];
    const float bi = b2[768 + nb * 96 + col];
    const int gc = nb * 96 + col;
#pragma unroll
    for (int mf = 0; mf < 2; ++mf) {
#pragma unroll
      for (int r = 0; r < 4; ++r) {
        const int m = wm * 32 + mf * 16 + kg * 4 + r;
        float vr = aR[mf][nf][r] + br;
        float vi = aI[mf][nf][r] + bi;
        vr = (vr > kLambd) ? (vr - kLambd) : ((vr < -kLambd) ? (vr + kLambd) : 0.f);
        vi = (vi > kLambd) ? (vi - kLambd) : ((vi < -kLambd) ? (vi + kLambd) : 0.f);
        Xr[(p0 + m) * 768 + gc] = f2bf(vr);
        Xi[(p0 + m) * 768 + gc] = f2bf(vi);
      }
    }
  }
}

// ---------------- 6. inverse row rDFT + accumulate via MFMA ----------------
__global__ __launch_bounds__(256) void irfft_row_add_mfma_kernel(
    const unsigned short* __restrict__ Zr, const unsigned short* __restrict__ Zi,
    float* __restrict__ out) {
  __shared__ alignas(16) unsigned short Ac[64 * 64];   // [w][kw] 8KB
  __shared__ alignas(16) unsigned short Asn[64 * 64];  // [w][kw] 8KB
  const int t = threadIdx.x;
  for (int e = t; e < 4096; e += 256) {
    const int w = e >> 6;
    const int kw = e & 63;
    if (kw < 33) {
      const float a = (kw == 0 || kw == 32) ? 0.125f : 0.25f;
      const float ang = (float)(2.0 * M_PI / 64.0) * (float)((kw * w) & 63);
      float s_, c_;
      __sincosf(ang, &s_, &c_);
      Ac[e] = f2bf(a * c_);
      Asn[e] = f2bf(-a * s_);
    } else {
      Ac[e] = 0;
      Asn[e] = 0;
    }
  }
  __syncthreads();

  const int lane = t & 63;
  const int wv = t >> 6;
  const int cl = lane & 15;
  const int kg = lane >> 4;
  const int bh = blockIdx.x;  // b*64 + h
  const int b = bh >> 6;
  const int h = bh & 63;
  const int c = blockIdx.y * 64 + wv * 16 + cl;
  const size_t zbase = (((size_t)b * kNKW) * 64 + h) * 768 + c;  // + kw*64*768
  float* ocol = out + ((size_t)bh * 64) * 768 + c;

  // preload accumulator with bias-path values
  f32x4 aO[4];
#pragma unroll
  for (int mi = 0; mi < 4; ++mi) {
#pragma unroll
    for (int r = 0; r < 4; ++r) {
      const int w = mi * 16 + kg * 4 + r;
      aO[mi][r] = ocol[(size_t)w * 768];
    }
  }

#pragma unroll
  for (int kf = 0; kf < 2; ++kf) {
    short8 bzr = {0, 0, 0, 0, 0, 0, 0, 0};
    short8 bzi = {0, 0, 0, 0, 0, 0, 0, 0};
#pragma unroll
    for (int j = 0; j < 8; ++j) {
      const int kw = kf * 32 + kg * 8 + j;
      if (kw < 33) {
        bzr[j] = (short)Zr[zbase + (size_t)kw * (64 * 768)];
        bzi[j] = (short)Zi[zbase + (size_t)kw * (64 * 768)];
      }
    }
    const bf16x8 br = s2b(bzr);
    const bf16x8 bi = s2b(bzi);
#pragma unroll
    for (int mi = 0; mi < 4; ++mi) {
      const int arow = mi * 16 + cl;
      const bf16x8 acf =
          *reinterpret_cast<const bf16x8*>(Ac + arow * 64 + kf * 32 + kg * 8);
      const bf16x8 asf =
          *reinterpret_cast<const bf16x8*>(Asn + arow * 64 + kf * 32 + kg * 8);
      aO[mi] = __builtin_amdgcn_mfma_f32_16x16x32_bf16(acf, br, aO[mi], 0, 0, 0);
      aO[mi] = __builtin_amdgcn_mfma_f32_16x16x32_bf16(asf, bi, aO[mi], 0, 0, 0);
    }
  }

#pragma unroll
  for (int mi = 0; mi < 4; ++mi) {
#pragma unroll
    for (int r = 0; r < 4; ++r) {
      const int w = mi * 16 + kg * 4 + r;
      ocol[(size_t)w * 768] = aO[mi][r];
    }
  }
}

}  // namespace

extern "C" void kernel_launch(void* const* d_in, const int* in_sizes, int n_in,
                              void* d_out, int out_size, void* d_ws,
                              size_t ws_size, hipStream_t stream) {
  (void)in_sizes; (void)n_in; (void)out_size;
  const float* x  = (const float*)d_in[0];
  const float* w1 = (const float*)d_in[1];
  const float* b1 = (const float*)d_in[2];
  const float* w2 = (const float*)d_in[3];
  const float* b2 = (const float*)d_in[4];
  const float* Wb = (const float*)d_in[5];
  const float* bb = (const float*)d_in[6];
  float* out = (float*)d_out;

  // ws layout (all bf16): xbf 48MB | wbf 1.2MB | XFr 26MB | XFi 26MB = 103.4MB
  if (ws_size < 2 * kXFElems * sizeof(float)) return;  // fits in required 103.8MB
  unsigned short* xbf = (unsigned short*)d_ws;      // 32768*768
  unsigned short* wbf = xbf + (size_t)32768 * 768;  // 768*768
  unsigned short* XFr = wbf + (size_t)768 * 768;    // kXFElems
  unsigned short* XFi = XFr + kXFElems;             // kXFElems

  // 0. conversions: Wb to bf16; MLP weights transposed to g_wT
  cvt_f32_bf16_kernel<<<dim3((768 * 768 / 4 + 255) / 256), 256, 0, stream>>>(
      Wb, wbf, 768 * 768 / 4);
  cvt_w_kernel<<<dim3(4 * 8 * 96 * 96 / 256), 256, 0, stream>>>(w1, w2);
  // 2. forward row rFFT on matrix cores (bf16 out) + fused x->bf16 for GEMM
  rfft_row_mfma_kernel<<<dim3(512, 12), 256, 0, stream>>>(x, xbf, XFr, XFi);
  // 1. bias path GEMM on matrix cores (writes d_out fully)
  mfma_gemm_kernel<<<dim3(1536), 256, 0, stream>>>(xbf, wbf, bb, out);
  // 3. forward column FFT on matrix cores (in place, bf16)
  fft_col_mfma_kernel<-1><<<dim3(264, 12), 256, 0, stream>>>(XFr, XFi);
  // 4. block-diagonal complex MLP on matrix cores (in place, bf16)
  mlp_mfma_kernel<<<dim3(132, 8), 512, 0, stream>>>(XFr, XFi, b1, b2);
  // 5. inverse column FFT on matrix cores (in place, bf16)
  fft_col_mfma_kernel<1><<<dim3(264, 12), 256, 0, stream>>>(XFr, XFi);
  // 6. inverse row rDFT + add bias path on matrix cores
  irfft_row_add_mfma_kernel<<<dim3(512, 12), 256, 0, stream>>>(XFr, XFi, out);
}

// Round 12
// 249.589 us; speedup vs baseline: 7.2385x; 1.0482x over previous
//
#include <hip/hip_runtime.h>
#include <math.h>

#ifndef M_PI
#define M_PI 3.14159265358979323846
#endif

namespace {

constexpr int kDim = 768;
constexpr int kNKW = 33;           // W/2+1
constexpr int kB = 8;
constexpr float kLambd = 0.01f;
constexpr size_t kXFElems = (size_t)kB * kNKW * 64 * kDim;  // 12,976,128

typedef __attribute__((ext_vector_type(8))) __bf16 bf16x8;
typedef __attribute__((ext_vector_type(8))) short short8;
typedef __attribute__((ext_vector_type(4))) float f32x4;

// Pre-transposed bf16 MLP weights: [mtx][nb][k_out][d], mtx: w1r,w1i,w2r,w2i
alignas(16) __device__ unsigned short g_wT[4 * 8 * 96 * 96];

// RNE float -> bf16 (inputs are normal floats; NaN not expected)
__device__ inline unsigned short f2bf(float f) {
  unsigned int u = __float_as_uint(f);
  unsigned int r = (u + 0x7FFFu + ((u >> 16) & 1u)) >> 16;
  return (unsigned short)r;
}

__device__ inline bf16x8 s2b(short8 s) { return __builtin_bit_cast(bf16x8, s); }
__device__ inline bf16x8 negb(short8 s) {
  s ^= (short)0x8000;
  return __builtin_bit_cast(bf16x8, s);
}

__device__ inline void gload_lds16(const void* g, void* l) {
  __builtin_amdgcn_global_load_lds(
      (const __attribute__((address_space(1))) unsigned int*)g,
      (__attribute__((address_space(3))) unsigned int*)l, 16, 0, 0);
}

// ---------------- 0a. fp32 -> bf16 conversion (Wb only) --------------------
__global__ __launch_bounds__(256) void cvt_f32_bf16_kernel(
    const float* __restrict__ in, unsigned short* __restrict__ out, int n4) {
  int i = blockIdx.x * 256 + threadIdx.x;
  if (i >= n4) return;
  const float4 v = reinterpret_cast<const float4*>(in)[i];
  ushort4 o;
  o.x = f2bf(v.x); o.y = f2bf(v.y); o.z = f2bf(v.z); o.w = f2bf(v.w);
  reinterpret_cast<ushort4*>(out)[i] = o;
}

// ---------------- 0b. MLP weight transpose+convert (once per launch) -------
__global__ __launch_bounds__(256) void cvt_w_kernel(
    const float* __restrict__ w1, const float* __restrict__ w2) {
  const int e = blockIdx.x * 256 + threadIdx.x;
  if (e >= 4 * 8 * 96 * 96) return;
  const int k = e % 96;
  const int d = (e / 96) % 96;
  const int nbm = e / 9216;  // mtx*8+nb
  const int mtx = nbm >> 3;
  const int nb = nbm & 7;
  const float* src =
      (mtx < 2 ? w1 : w2) + ((size_t)(mtx & 1) * 8 + nb) * 9216;
  g_wT[((size_t)nbm * 96 + k) * 96 + d] = f2bf(src[d * 96 + k]);
}

// ---------------- 1. bias GEMM via MFMA ------------------------------------
// out[m,n] = sum_k xbf[m,k] * wbf[n,k] + bb[n]; M=32768, N=768, K=768.
__global__ __launch_bounds__(256) void mfma_gemm_kernel(
    const unsigned short* __restrict__ xbf, const unsigned short* __restrict__ wbf,
    const float* __restrict__ bb, float* __restrict__ out) {
  __shared__ unsigned short As[128 * 32];  // [row][k] 8KB
  __shared__ unsigned short Bs[128 * 32];  // [n][k]   8KB
  const int t = threadIdx.x;
  const int lane = t & 63;
  const int wid = t >> 6;
  const int wm = wid >> 1;
  const int wn = wid & 1;
  const int id = blockIdx.x;
  const int swz = (id & 7) * 192 + (id >> 3);  // XCD chunk swizzle, bijective
  const int m0 = (swz / 6) * 128;
  const int n0 = (swz % 6) * 128;

  f32x4 acc[4][4];
#pragma unroll
  for (int i = 0; i < 4; ++i)
#pragma unroll
    for (int j = 0; j < 4; ++j) acc[i][j] = (f32x4){0.f, 0.f, 0.f, 0.f};

  char* AsB = (char*)As;
  char* BsB = (char*)Bs;
  const int cl = lane & 15;
  const int kg = lane >> 4;  // 0..3

  for (int k0 = 0; k0 < 768; k0 += 32) {
#pragma unroll
    for (int i = 0; i < 2; ++i) {
      const int off = (wid * 2 + i) * 1024 + lane * 16;  // byte off in tile
      const int row = off >> 6;
      const int kb = off & 63;
      const char* gA = (const char*)xbf + ((size_t)(m0 + row) * 768 + k0) * 2 + kb;
      gload_lds16(gA, AsB + (wid * 2 + i) * 1024);
      const char* gB = (const char*)wbf + ((size_t)(n0 + row) * 768 + k0) * 2 + kb;
      gload_lds16(gB, BsB + (wid * 2 + i) * 1024);
    }
    asm volatile("s_waitcnt vmcnt(0)" ::: "memory");
    __syncthreads();

    bf16x8 av[4], bv[4];
#pragma unroll
    for (int mi = 0; mi < 4; ++mi) {
      const int r = wm * 64 + mi * 16 + cl;
      av[mi] = *reinterpret_cast<const bf16x8*>(AsB + r * 64 + kg * 16);
    }
#pragma unroll
    for (int ni = 0; ni < 4; ++ni) {
      const int r = wn * 64 + ni * 16 + cl;
      bv[ni] = *reinterpret_cast<const bf16x8*>(BsB + r * 64 + kg * 16);
    }
#pragma unroll
    for (int mi = 0; mi < 4; ++mi)
#pragma unroll
      for (int ni = 0; ni < 4; ++ni)
        acc[mi][ni] = __builtin_amdgcn_mfma_f32_16x16x32_bf16(
            av[mi], bv[ni], acc[mi][ni], 0, 0, 0);
    __syncthreads();
  }

#pragma unroll
  for (int ni = 0; ni < 4; ++ni) {
    const int n = n0 + wn * 64 + ni * 16 + cl;
    const float bias = bb[n];
#pragma unroll
    for (int mi = 0; mi < 4; ++mi) {
      const int m = m0 + wm * 64 + mi * 16 + kg * 4;
#pragma unroll
      for (int r = 0; r < 4; ++r) {
        out[(size_t)(m + r) * 768 + n] = acc[mi][ni][r] + bias;
      }
    }
  }
}

// ---------------- 2. forward row rFFT via MFMA + fused x->bf16 -------------
// LDS-staged: coalesced x loads (256B/instr), coalesced xbf stores
// (128B/instr), bf16 transpose tile xsT[c][w] (pad 80) for 16B-aligned
// ds_read_b128 fragments. Twiddles padded 64->80 (16-way -> 4-way conflicts).
__global__ __launch_bounds__(256) void rfft_row_mfma_kernel(
    const float* __restrict__ x, unsigned short* __restrict__ xbf,
    unsigned short* __restrict__ XFr, unsigned short* __restrict__ XFi) {
  __shared__ alignas(16) unsigned short Cs[48 * 80];   //  0.125*cos [kh][w]
  __shared__ alignas(16) unsigned short Ss[48 * 80];   // -0.125*sin
  __shared__ alignas(16) unsigned short xsT[64 * 80];  // [c_local][w] bf16
  const int t = threadIdx.x;
  for (int e = t; e < 48 * 64; e += 256) {
    const int kh = e >> 6;
    const int w = e & 63;
    const float ang = (float)(2.0 * M_PI / 64.0) * (float)((kh * w) & 63);
    float s_, c_;
    __sincosf(ang, &s_, &c_);
    Cs[kh * 80 + w] = f2bf(0.125f * c_);
    Ss[kh * 80 + w] = f2bf(-0.125f * s_);
  }

  const int lane = t & 63;
  const int wv = t >> 6;       // wave id
  const int cl = lane & 15;
  const int kg = lane >> 4;    // 0..3
  const int bh = blockIdx.x;   // b*64 + h
  const int b = bh >> 6;
  const int h = bh & 63;
  const int c0 = blockIdx.y * 64;

  // ---- stage: wave wv loads rows w = wv*16..wv*16+15, lane = channel ----
  {
    const float* xrow = x + (size_t)bh * (64 * 768) + c0;
    unsigned short* xbrow = xbf + (size_t)bh * (64 * 768) + c0;
#pragma unroll 4
    for (int it = 0; it < 16; ++it) {
      const int w = wv * 16 + it;
      const float v = xrow[(size_t)w * 768 + lane];
      const unsigned short bv = f2bf(v);
      xbrow[(size_t)w * 768 + lane] = bv;
      xsT[lane * 80 + w] = bv;
    }
  }
  __syncthreads();

  const int c = c0 + wv * 16 + cl;
  const int cloc = wv * 16 + cl;

  f32x4 aR[3], aI[3];
#pragma unroll
  for (int mi = 0; mi < 3; ++mi) {
    aR[mi] = (f32x4){0.f, 0.f, 0.f, 0.f};
    aI[mi] = (f32x4){0.f, 0.f, 0.f, 0.f};
  }

#pragma unroll
  for (int kf = 0; kf < 2; ++kf) {
    const int w0 = kf * 32 + kg * 8;
    const bf16x8 bx =
        *reinterpret_cast<const bf16x8*>(xsT + cloc * 80 + w0);
#pragma unroll
    for (int mi = 0; mi < 3; ++mi) {
      const int arow = mi * 16 + cl;
      const bf16x8 ac = *reinterpret_cast<const bf16x8*>(Cs + arow * 80 + w0);
      const bf16x8 as = *reinterpret_cast<const bf16x8*>(Ss + arow * 80 + w0);
      aR[mi] = __builtin_amdgcn_mfma_f32_16x16x32_bf16(ac, bx, aR[mi], 0, 0, 0);
      aI[mi] = __builtin_amdgcn_mfma_f32_16x16x32_bf16(as, bx, aI[mi], 0, 0, 0);
    }
  }

#pragma unroll
  for (int mi = 0; mi < 3; ++mi) {
#pragma unroll
    for (int r = 0; r < 4; ++r) {
      const int kh = mi * 16 + kg * 4 + r;
      if (kh <= 32) {
        const size_t off = (((size_t)b * kNKW + kh) * 64 + h) * 768 + c;
        XFr[off] = f2bf(aR[mi][r]);
        XFi[off] = f2bf(aI[mi][r]);
      }
    }
  }
}

// ---------------- 3/5. column FFT along h via MFMA (in place, bf16) --------
template <int SIGN>
__global__ __launch_bounds__(256) void fft_col_mfma_kernel(
    unsigned short* __restrict__ Xr, unsigned short* __restrict__ Xi) {
  __shared__ alignas(16) unsigned short Cs[64 * 80];  // 0.125*cos  [kh][h]
  __shared__ alignas(16) unsigned short Ss[64 * 80];  // 0.125*SIGN*sin
  const int t = threadIdx.x;
  for (int e = t; e < 4096; e += 256) {
    const int kh = e >> 6;
    const int h = e & 63;
    const float ang = (float)(2.0 * M_PI / 64.0) * (float)((kh * h) & 63);
    float s_, c_;
    __sincosf(ang, &s_, &c_);
    Cs[kh * 80 + h] = f2bf(0.125f * c_);
    Ss[kh * 80 + h] = f2bf(0.125f * (float)SIGN * s_);
  }
  __syncthreads();

  const int lane = t & 63;
  const int wv = t >> 6;       // wave id 0..3 -> c-strip
  const int cl = lane & 15;
  const int kg = lane >> 4;    // 0..3
  const size_t cbase =
      (size_t)blockIdx.x * (64 * 768) + blockIdx.y * 64 + wv * 16 + cl;

  f32x4 aR[4], aI[4];
#pragma unroll
  for (int mi = 0; mi < 4; ++mi) {
    aR[mi] = (f32x4){0.f, 0.f, 0.f, 0.f};
    aI[mi] = (f32x4){0.f, 0.f, 0.f, 0.f};
  }

#pragma unroll
  for (int kf = 0; kf < 2; ++kf) {
    const int h0 = kf * 32 + kg * 8;
    short8 brf, bif;
#pragma unroll
    for (int j = 0; j < 8; ++j) {
      brf[j] = (short)Xr[cbase + (size_t)(h0 + j) * 768];
      bif[j] = (short)Xi[cbase + (size_t)(h0 + j) * 768];
    }
    const bf16x8 bxr = s2b(brf);
    const bf16x8 bxi = s2b(bif);
    const bf16x8 bxin = negb(bif);
#pragma unroll
    for (int mi = 0; mi < 4; ++mi) {
      const int arow = mi * 16 + cl;
      const bf16x8 ac =
          *reinterpret_cast<const bf16x8*>(Cs + arow * 80 + h0);
      const bf16x8 as =
          *reinterpret_cast<const bf16x8*>(Ss + arow * 80 + h0);
      aR[mi] = __builtin_amdgcn_mfma_f32_16x16x32_bf16(ac, bxr, aR[mi], 0, 0, 0);
      aR[mi] = __builtin_amdgcn_mfma_f32_16x16x32_bf16(as, bxin, aR[mi], 0, 0, 0);
      aI[mi] = __builtin_amdgcn_mfma_f32_16x16x32_bf16(ac, bxi, aI[mi], 0, 0, 0);
      aI[mi] = __builtin_amdgcn_mfma_f32_16x16x32_bf16(as, bxr, aI[mi], 0, 0, 0);
    }
  }

#pragma unroll
  for (int mi = 0; mi < 4; ++mi) {
#pragma unroll
    for (int r = 0; r < 4; ++r) {
      const int kh = mi * 16 + kg * 4 + r;
      Xr[cbase + (size_t)kh * 768] = f2bf(aR[mi][r]);
      Xi[cbase + (size_t)kh * 768] = f2bf(aI[mi][r]);
    }
  }
}

// ---------------- 4. block-diagonal complex MLP via MFMA (in place, bf16) --
__global__ __launch_bounds__(512) void mlp_mfma_kernel(
    unsigned short* __restrict__ Xr, unsigned short* __restrict__ Xi,
    const float* __restrict__ b1, const float* __restrict__ b2) {
  __shared__ unsigned short sXr[128 * 104];      // 26.6 KB (reused for R1)
  __shared__ unsigned short sXi[128 * 104];      // 26.6 KB (reused for I1)
  const int t = threadIdx.x;
  const int lane = t & 63;
  const int wid = t >> 6;   // 0..7
  const int wm = wid >> 1;  // 0..3: rows wm*32
  const int wn = wid & 1;   // 0..1: cols wn*48
  const int cl = lane & 15;
  const int kg = lane >> 4;
  const int nb = blockIdx.y;
  const size_t p0 = (size_t)blockIdx.x * 128;

  // ---- stage X tile: bf16 global -> LDS (vector copy, no convert) ----
  {
    const int row = t >> 2;
    const int q = t & 3;  // 24-elem chunk
    const size_t gbase = (p0 + row) * 768 + nb * 96 + q * 24;
    unsigned short* lr = sXr + row * 104 + q * 24;
    unsigned short* li = sXi + row * 104 + q * 24;
#pragma unroll
    for (int v = 0; v < 3; ++v) {
      *reinterpret_cast<short8*>(lr + v * 8) =
          *reinterpret_cast<const short8*>(Xr + gbase + v * 8);
      *reinterpret_cast<short8*>(li + v * 8) =
          *reinterpret_cast<const short8*>(Xi + gbase + v * 8);
    }
  }
  __syncthreads();

  const unsigned short* wt1r = g_wT + (size_t)(0 * 8 + nb) * 9216;
  const unsigned short* wt1i = g_wT + (size_t)(1 * 8 + nb) * 9216;
  const unsigned short* wt2r = g_wT + (size_t)(2 * 8 + nb) * 9216;
  const unsigned short* wt2i = g_wT + (size_t)(3 * 8 + nb) * 9216;

  f32x4 aR[2][3], aI[2][3];
#pragma unroll
  for (int mf = 0; mf < 2; ++mf)
#pragma unroll
    for (int nf = 0; nf < 3; ++nf) {
      aR[mf][nf] = (f32x4){0.f, 0.f, 0.f, 0.f};
      aI[mf][nf] = (f32x4){0.f, 0.f, 0.f, 0.f};
    }

  // ---- layer 1 ----
#pragma unroll
  for (int kk = 0; kk < 3; ++kk) {
    const int ko = kk * 32 + kg * 8;
    short8 xr_[2], xi_[2];
#pragma unroll
    for (int mf = 0; mf < 2; ++mf) {
      const int r = wm * 32 + mf * 16 + cl;
      xr_[mf] = *reinterpret_cast<const short8*>(sXr + r * 104 + ko);
      xi_[mf] = *reinterpret_cast<const short8*>(sXi + r * 104 + ko);
    }
    short8 wr_[3], wi_[3];
#pragma unroll
    for (int nf = 0; nf < 3; ++nf) {
      const int r = wn * 48 + nf * 16 + cl;
      wr_[nf] = *reinterpret_cast<const short8*>(wt1r + r * 96 + ko);
      wi_[nf] = *reinterpret_cast<const short8*>(wt1i + r * 96 + ko);
    }
#pragma unroll
    for (int mf = 0; mf < 2; ++mf) {
      const bf16x8 axr = s2b(xr_[mf]);
      const bf16x8 axi = s2b(xi_[mf]);
      const bf16x8 axin = negb(xi_[mf]);
#pragma unroll
      for (int nf = 0; nf < 3; ++nf) {
        aR[mf][nf] = __builtin_amdgcn_mfma_f32_16x16x32_bf16(axr, s2b(wr_[nf]), aR[mf][nf], 0, 0, 0);
        aR[mf][nf] = __builtin_amdgcn_mfma_f32_16x16x32_bf16(axin, s2b(wi_[nf]), aR[mf][nf], 0, 0, 0);
        aI[mf][nf] = __builtin_amdgcn_mfma_f32_16x16x32_bf16(axr, s2b(wi_[nf]), aI[mf][nf], 0, 0, 0);
        aI[mf][nf] = __builtin_amdgcn_mfma_f32_16x16x32_bf16(axi, s2b(wr_[nf]), aI[mf][nf], 0, 0, 0);
      }
    }
  }
  __syncthreads();  // all layer-1 LDS reads complete before overwrite

  // epilogue L1: bias + relu -> bf16 back into sXr/sXi
#pragma unroll
  for (int nf = 0; nf < 3; ++nf) {
    const int col = wn * 48 + nf * 16 + cl;
    const float br = b1[nb * 96 + col];
    const float bi = b1[768 + nb * 96 + col];
#pragma unroll
    for (int mf = 0; mf < 2; ++mf) {
#pragma unroll
      for (int r = 0; r < 4; ++r) {
        const int m = wm * 32 + mf * 16 + kg * 4 + r;
        const float vr = fmaxf(aR[mf][nf][r] + br, 0.f);
        const float vi = fmaxf(aI[mf][nf][r] + bi, 0.f);
        sXr[m * 104 + col] = f2bf(vr);
        sXi[m * 104 + col] = f2bf(vi);
      }
    }
  }
  __syncthreads();

  // ---- layer 2 ----
#pragma unroll
  for (int mf = 0; mf < 2; ++mf)
#pragma unroll
    for (int nf = 0; nf < 3; ++nf) {
      aR[mf][nf] = (f32x4){0.f, 0.f, 0.f, 0.f};
      aI[mf][nf] = (f32x4){0.f, 0.f, 0.f, 0.f};
    }
#pragma unroll
  for (int kk = 0; kk < 3; ++kk) {
    const int ko = kk * 32 + kg * 8;
    short8 xr_[2], xi_[2];
#pragma unroll
    for (int mf = 0; mf < 2; ++mf) {
      const int r = wm * 32 + mf * 16 + cl;
      xr_[mf] = *reinterpret_cast<const short8*>(sXr + r * 104 + ko);
      xi_[mf] = *reinterpret_cast<const short8*>(sXi + r * 104 + ko);
    }
    short8 wr_[3], wi_[3];
#pragma unroll
    for (int nf = 0; nf < 3; ++nf) {
      const int r = wn * 48 + nf * 16 + cl;
      wr_[nf] = *reinterpret_cast<const short8*>(wt2r + r * 96 + ko);
      wi_[nf] = *reinterpret_cast<const short8*>(wt2i + r * 96 + ko);
    }
#pragma unroll
    for (int mf = 0; mf < 2; ++mf) {
      const bf16x8 axr = s2b(xr_[mf]);
      const bf16x8 axi = s2b(xi_[mf]);
      const bf16x8 axin = negb(xi_[mf]);
#pragma unroll
      for (int nf = 0; nf < 3; ++nf) {
        aR[mf][nf] = __builtin_amdgcn_mfma_f32_16x16x32_bf16(axr, s2b(wr_[nf]), aR[mf][nf], 0, 0, 0);
        aR[mf][nf] = __builtin_amdgcn_mfma_f32_16x16x32_bf16(axin, s2b(wi_[nf]), aR[mf][nf], 0, 0, 0);
        aI[mf][nf] = __builtin_amdgcn_mfma_f32_16x16x32_bf16(axr, s2b(wi_[nf]), aI[mf][nf], 0, 0, 0);
        aI[mf][nf] = __builtin_amdgcn_mfma_f32_16x16x32_bf16(axi, s2b(wr_[nf]), aI[mf][nf], 0, 0, 0);
      }
    }
  }

  // epilogue L2: bias + softshrink -> bf16 global (in place)
#pragma unroll
  for (int nf = 0; nf < 3; ++nf) {
    const int col = wn * 48 + nf * 16 + cl;
    const float br = b2[nb * 96 + col];
    const float bi = b2[768 + nb * 96 + col];
    const int gc = nb * 96 + col;
#pragma unroll
    for (int mf = 0; mf < 2; ++mf) {
#pragma unroll
      for (int r = 0; r < 4; ++r) {
        const int m = wm * 32 + mf * 16 + kg * 4 + r;
        float vr = aR[mf][nf][r] + br;
        float vi = aI[mf][nf][r] + bi;
        vr = (vr > kLambd) ? (vr - kLambd) : ((vr < -kLambd) ? (vr + kLambd) : 0.f);
        vi = (vi > kLambd) ? (vi - kLambd) : ((vi < -kLambd) ? (vi + kLambd) : 0.f);
        Xr[(p0 + m) * 768 + gc] = f2bf(vr);
        Xi[(p0 + m) * 768 + gc] = f2bf(vi);
      }
    }
  }
}

// ---------------- 6. inverse row rDFT + accumulate via MFMA ----------------
__global__ __launch_bounds__(256) void irfft_row_add_mfma_kernel(
    const unsigned short* __restrict__ Zr, const unsigned short* __restrict__ Zi,
    float* __restrict__ out) {
  __shared__ alignas(16) unsigned short Ac[64 * 80];   // [w][kw]
  __shared__ alignas(16) unsigned short Asn[64 * 80];  // [w][kw]
  const int t = threadIdx.x;
  for (int e = t; e < 4096; e += 256) {
    const int w = e >> 6;
    const int kw = e & 63;
    unsigned short cv = 0, sv = 0;
    if (kw < 33) {
      const float a = (kw == 0 || kw == 32) ? 0.125f : 0.25f;
      const float ang = (float)(2.0 * M_PI / 64.0) * (float)((kw * w) & 63);
      float s_, c_;
      __sincosf(ang, &s_, &c_);
      cv = f2bf(a * c_);
      sv = f2bf(-a * s_);
    }
    Ac[w * 80 + kw] = cv;
    Asn[w * 80 + kw] = sv;
  }
  __syncthreads();

  const int lane = t & 63;
  const int wv = t >> 6;
  const int cl = lane & 15;
  const int kg = lane >> 4;
  const int bh = blockIdx.x;  // b*64 + h
  const int b = bh >> 6;
  const int h = bh & 63;
  const int c = blockIdx.y * 64 + wv * 16 + cl;
  const size_t zbase = (((size_t)b * kNKW) * 64 + h) * 768 + c;  // + kw*64*768
  float* ocol = out + ((size_t)bh * 64) * 768 + c;

  // preload accumulator with bias-path values
  f32x4 aO[4];
#pragma unroll
  for (int mi = 0; mi < 4; ++mi) {
#pragma unroll
    for (int r = 0; r < 4; ++r) {
      const int w = mi * 16 + kg * 4 + r;
      aO[mi][r] = ocol[(size_t)w * 768];
    }
  }

#pragma unroll
  for (int kf = 0; kf < 2; ++kf) {
    short8 bzr = {0, 0, 0, 0, 0, 0, 0, 0};
    short8 bzi = {0, 0, 0, 0, 0, 0, 0, 0};
#pragma unroll
    for (int j = 0; j < 8; ++j) {
      const int kw = kf * 32 + kg * 8 + j;
      if (kw < 33) {
        bzr[j] = (short)Zr[zbase + (size_t)kw * (64 * 768)];
        bzi[j] = (short)Zi[zbase + (size_t)kw * (64 * 768)];
      }
    }
    const bf16x8 br = s2b(bzr);
    const bf16x8 bi = s2b(bzi);
#pragma unroll
    for (int mi = 0; mi < 4; ++mi) {
      const int arow = mi * 16 + cl;
      const bf16x8 acf =
          *reinterpret_cast<const bf16x8*>(Ac + arow * 80 + kf * 32 + kg * 8);
      const bf16x8 asf =
          *reinterpret_cast<const bf16x8*>(Asn + arow * 80 + kf * 32 + kg * 8);
      aO[mi] = __builtin_amdgcn_mfma_f32_16x16x32_bf16(acf, br, aO[mi], 0, 0, 0);
      aO[mi] = __builtin_amdgcn_mfma_f32_16x16x32_bf16(asf, bi, aO[mi], 0, 0, 0);
    }
  }

#pragma unroll
  for (int mi = 0; mi < 4; ++mi) {
#pragma unroll
    for (int r = 0; r < 4; ++r) {
      const int w = mi * 16 + kg * 4 + r;
      ocol[(size_t)w * 768] = aO[mi][r];
    }
  }
}

}  // namespace

extern "C" void kernel_launch(void* const* d_in, const int* in_sizes, int n_in,
                              void* d_out, int out_size, void* d_ws,
                              size_t ws_size, hipStream_t stream) {
  (void)in_sizes; (void)n_in; (void)out_size;
  const float* x  = (const float*)d_in[0];
  const float* w1 = (const float*)d_in[1];
  const float* b1 = (const float*)d_in[2];
  const float* w2 = (const float*)d_in[3];
  const float* b2 = (const float*)d_in[4];
  const float* Wb = (const float*)d_in[5];
  const float* bb = (const float*)d_in[6];
  float* out = (float*)d_out;

  // ws layout (all bf16): xbf 48MB | wbf 1.2MB | XFr 26MB | XFi 26MB = 103.4MB
  if (ws_size < 2 * kXFElems * sizeof(float)) return;
  unsigned short* xbf = (unsigned short*)d_ws;      // 32768*768
  unsigned short* wbf = xbf + (size_t)32768 * 768;  // 768*768
  unsigned short* XFr = wbf + (size_t)768 * 768;    // kXFElems
  unsigned short* XFi = XFr + kXFElems;             // kXFElems

  // 0. conversions: Wb to bf16; MLP weights transposed to g_wT
  cvt_f32_bf16_kernel<<<dim3((768 * 768 / 4 + 255) / 256), 256, 0, stream>>>(
      Wb, wbf, 768 * 768 / 4);
  cvt_w_kernel<<<dim3(4 * 8 * 96 * 96 / 256), 256, 0, stream>>>(w1, w2);
  // 2. forward row rFFT on matrix cores (bf16 out) + fused x->bf16 for GEMM
  rfft_row_mfma_kernel<<<dim3(512, 12), 256, 0, stream>>>(x, xbf, XFr, XFi);
  // 1. bias path GEMM on matrix cores (writes d_out fully)
  mfma_gemm_kernel<<<dim3(1536), 256, 0, stream>>>(xbf, wbf, bb, out);
  // 3. forward column FFT on matrix cores (in place, bf16)
  fft_col_mfma_kernel<-1><<<dim3(264, 12), 256, 0, stream>>>(XFr, XFi);
  // 4. block-diagonal complex MLP on matrix cores (in place, bf16)
  mlp_mfma_kernel<<<dim3(132, 8), 512, 0, stream>>>(XFr, XFi, b1, b2);
  // 5. inverse column FFT on matrix cores (in place, bf16)
  fft_col_mfma_kernel<1><<<dim3(264, 12), 256, 0, stream>>>(XFr, XFi);
  // 6. inverse row rDFT + add bias path on matrix cores
  irfft_row_add_mfma_kernel<<<dim3(512, 12), 256, 0, stream>>>(XFr, XFi, out);
}